// Round 9
// baseline (595.364 us; speedup 1.0000x reference)
//
#include <hip/hip_runtime.h>
#include <hip/hip_bf16.h>
#include <hip/hip_fp16.h>
#include <math.h>

#define NN 50000
#define EE 400000
#define ETOT (NN + EE)

// ---------- helpers ----------
__device__ __forceinline__ float gelu_f(float x) {
    return 0.5f * x * (1.f + erff(x * 0.7071067811865476f));
}
__device__ __forceinline__ float elu_f(float x) {
    return x > 0.f ? x : expm1f(x);
}
__device__ __forceinline__ float4 half8_lo_hi(uint4 raw, float4* hi) {
    __half2 h0 = *(__half2*)&raw.x, h1 = *(__half2*)&raw.y;
    __half2 h2 = *(__half2*)&raw.z, h3 = *(__half2*)&raw.w;
    float2 f0 = __half22float2(h0), f1 = __half22float2(h1);
    float2 f2 = __half22float2(h2), f3 = __half22float2(h3);
    *hi = make_float4(f2.x, f2.y, f3.x, f3.y);
    return make_float4(f0.x, f0.y, f1.x, f1.y);
}

// ---------- ea mean (sum) ----------
__global__ __launch_bounds__(256) void k_ea_reduce(const float* __restrict__ ea,
                                                   float* __restrict__ ea_sum, int E) {
    float s[8];
#pragma unroll
    for (int i = 0; i < 8; i++) s[i] = 0.f;
    for (int e = blockIdx.x * blockDim.x + threadIdx.x; e < E; e += gridDim.x * blockDim.x) {
        const float4* p = (const float4*)(ea + (size_t)e * 8);
        float4 a = p[0], b = p[1];
        s[0] += a.x; s[1] += a.y; s[2] += a.z; s[3] += a.w;
        s[4] += b.x; s[5] += b.y; s[6] += b.z; s[7] += b.w;
    }
#pragma unroll
    for (int o = 32; o; o >>= 1)
#pragma unroll
        for (int i = 0; i < 8; i++) s[i] += __shfl_xor(s[i], o, 64);
    __shared__ float sh[4][8];
    int lane = threadIdx.x & 63, w = threadIdx.x >> 6;
    if (lane == 0)
#pragma unroll
        for (int i = 0; i < 8; i++) sh[w][i] = s[i];
    __syncthreads();
    if (threadIdx.x < 8) {
        float v = sh[0][threadIdx.x] + sh[1][threadIdx.x] + sh[2][threadIdx.x] + sh[3][threadIdx.x];
        atomicAdd(ea_sum + threadIdx.x, v);
    }
}

// ---------- CSR build: count / scan / scatter ----------
__global__ __launch_bounds__(256) void k_count(const int* __restrict__ ei, int* __restrict__ counts,
                                               int E, int N) {
    int e = blockIdx.x * blockDim.x + threadIdx.x;
    if (e >= E + N) return;
    int d = (e < E) ? ei[E + e] : (e - E);
    atomicAdd(counts + d, 1);
}

__global__ __launch_bounds__(1024) void k_scan(const int* __restrict__ counts, int* __restrict__ off,
                                               int* __restrict__ cursor, int N) {
    __shared__ int buf[1024];
    int t = threadIdx.x;
    int carry = 0;
    if (t == 0) off[0] = 0;
    for (int base = 0; base < N; base += 4096) {
        int i0 = base + t * 4;
        int v0 = 0, v1 = 0, v2 = 0, v3 = 0;
        if (i0 + 3 < N) {
            int4 vv = *(const int4*)(counts + i0);
            v0 = vv.x; v1 = vv.y; v2 = vv.z; v3 = vv.w;
        } else {
            if (i0 < N)     v0 = counts[i0];
            if (i0 + 1 < N) v1 = counts[i0 + 1];
            if (i0 + 2 < N) v2 = counts[i0 + 2];
            if (i0 + 3 < N) v3 = counts[i0 + 3];
        }
        int s01 = v0 + v1, s012 = s01 + v2, tot4 = s012 + v3;
        buf[t] = tot4;
        __syncthreads();
        for (int o = 1; o < 1024; o <<= 1) {
            int add = (t >= o) ? buf[t - o] : 0;
            __syncthreads();
            buf[t] += add;
            __syncthreads();
        }
        int incl4 = buf[t] + carry;
        int excl = incl4 - tot4;
        if (i0 < N)     { off[i0 + 1] = excl + v0;   cursor[i0]     = excl; }
        if (i0 + 1 < N) { off[i0 + 2] = excl + s01;  cursor[i0 + 1] = excl + v0; }
        if (i0 + 2 < N) { off[i0 + 3] = excl + s012; cursor[i0 + 2] = excl + s01; }
        if (i0 + 3 < N) { off[i0 + 4] = excl + tot4; cursor[i0 + 3] = excl + s012; }
        int tot = buf[1023];
        __syncthreads();
        carry += tot;
    }
}

__global__ __launch_bounds__(256) void k_scatter(const int* __restrict__ ei, int* __restrict__ cursor,
                                                 int* __restrict__ csr_src, int* __restrict__ csr_eid,
                                                 int E, int N) {
    int e = blockIdx.x * blockDim.x + threadIdx.x;
    if (e >= E + N) return;
    int s, d;
    if (e < E) { s = ei[e]; d = ei[E + e]; }
    else { s = d = e - E; }
    int pos = atomicAdd(cursor + d, 1);
    csr_src[pos] = s;
    csr_eid[pos] = e;
}

// ---------- node transform 1: xl1(fp16) = x@Wl1+bl1, xr1(fp32) = x@Wr1+br1 ----------
__global__ __launch_bounds__(256) void k_ntrans1(const float* __restrict__ x,
                                                 const float* __restrict__ Wl, const float* __restrict__ bl,
                                                 const float* __restrict__ Wr, const float* __restrict__ br,
                                                 __half* __restrict__ xl1h, float* __restrict__ xr1, int N) {
    __shared__ float swl[16 * 256];
    __shared__ float swr[16 * 256];
    __shared__ float sx[32 * 16];
    int t = threadIdx.x;
#pragma unroll
    for (int k = 0; k < 16; k++) { swl[k * 256 + t] = Wl[k * 256 + t]; swr[k * 256 + t] = Wr[k * 256 + t]; }
    int n0 = blockIdx.x * 32;
    for (int i = t; i < 32 * 16; i += 256) {
        int n = n0 + (i >> 4);
        sx[i] = (n < N) ? x[(size_t)n * 16 + (i & 15)] : 0.f;
    }
    __syncthreads();
    float bL = bl[t], bR = br[t];
    for (int ni = 0; ni < 32; ni++) {
        int n = n0 + ni;
        if (n >= N) break;
        float al = bL, ar = bR;
#pragma unroll
        for (int k = 0; k < 16; k++) {
            float xv = sx[ni * 16 + k];
            al += xv * swl[k * 256 + t];
            ar += xv * swr[k * 256 + t];
        }
        xl1h[(size_t)n * 256 + t] = __float2half(al);
        xr1[(size_t)n * 256 + t] = ar;
    }
}

// ---------- fetch helpers for fused conv kernels ----------
__device__ __forceinline__ void fetch1_c1(const __half* __restrict__ xl1h, const float* __restrict__ ea,
                                          int sl, int el, int j, int cnt, int c4,
                                          float4 eam0, float4 eam1, int E,
                                          float2* row, float4* e0, float4* e1) {
    if (j < cnt) {
        int s = __shfl(sl, j, 64);
        int e = __shfl(el, j, 64);
        *row = *(const float2*)(xl1h + (size_t)s * 256 + c4);
        if (e < E) {
            *e0 = *(const float4*)(ea + (size_t)e * 8);
            *e1 = *(const float4*)(ea + (size_t)e * 8 + 4);
        } else { *e0 = eam0; *e1 = eam1; }
    } else {
        *row = make_float2(0.f, 0.f); *e0 = eam0; *e1 = eam1;
    }
}

__device__ __forceinline__ float logit_c1(float2 raw, float4 e0, float4 e1,
                                          const float4* we, float4 xr4, float4 at4,
                                          float4* xs_out) {
    const __half2* hp = (const __half2*)&raw;
    float2 lo = __half22float2(hp[0]);
    float2 hi = __half22float2(hp[1]);
    float4 xs = make_float4(lo.x, lo.y, hi.x, hi.y);
    float ev[8] = { e0.x, e0.y, e0.z, e0.w, e1.x, e1.y, e1.z, e1.w };
    float4 ee = make_float4(0.f, 0.f, 0.f, 0.f);
#pragma unroll
    for (int k = 0; k < 8; k++) {
        ee.x += ev[k] * we[k].x; ee.y += ev[k] * we[k].y;
        ee.z += ev[k] * we[k].z; ee.w += ev[k] * we[k].w;
    }
    float4 v;
    v.x = xs.x + xr4.x + ee.x; v.y = xs.y + xr4.y + ee.y;
    v.z = xs.z + xr4.z + ee.z; v.w = xs.w + xr4.w + ee.w;
    v.x = v.x > 0.f ? v.x : 0.2f * v.x;
    v.y = v.y > 0.f ? v.y : 0.2f * v.y;
    v.z = v.z > 0.f ? v.z : 0.2f * v.z;
    v.w = v.w > 0.f ? v.w : 0.2f * v.w;
    float p = v.x * at4.x + v.y * at4.y + v.z * at4.z + v.w * at4.w;
    p += __shfl_xor(p, 1, 64);
    p += __shfl_xor(p, 2, 64);
    p += __shfl_xor(p, 4, 64);
    p += __shfl_xor(p, 8, 64);
    *xs_out = xs;
    return p;
}

// ---------- fused conv1: uniform-ea, pair-merged online softmax ----------
__global__ __launch_bounds__(256) void k_fagg1(const __half* __restrict__ xl1h, const float* __restrict__ xr1,
                                               const int* __restrict__ off, const int* __restrict__ csr_src,
                                               const int* __restrict__ csr_eid,
                                               const float* __restrict__ ea, const float* __restrict__ ea_sum,
                                               const float* __restrict__ We1, const float* __restrict__ att1,
                                               const float* __restrict__ bias1,
                                               const float* __restrict__ x, const float* __restrict__ Wres,
                                               const float* __restrict__ g, const float* __restrict__ bb_,
                                               const float* __restrict__ mm_, const float* __restrict__ vv_,
                                               float* __restrict__ h1,
                                               int E, int N) {
    int t = threadIdx.x;
    int lane = t & 63, w = t >> 6;
    int node = blockIdx.x * 4 + w;
    if (node >= N) return;
    int c4 = lane * 4;
    float4 we[8];
#pragma unroll
    for (int k = 0; k < 8; k++) we[k] = *(const float4*)(We1 + k * 256 + c4);
    float4 xr4 = *(const float4*)(xr1 + (size_t)node * 256 + c4);
    float4 at4 = *(const float4*)(att1 + c4);
    float invE = 1.f / (float)E;
    float4 eam0, eam1;
    eam0.x = ea_sum[0] * invE; eam0.y = ea_sum[1] * invE;
    eam0.z = ea_sum[2] * invE; eam0.w = ea_sum[3] * invE;
    eam1.x = ea_sum[4] * invE; eam1.y = ea_sum[5] * invE;
    eam1.z = ea_sum[6] * invE; eam1.w = ea_sum[7] * invE;

    int beg = off[node], end = off[node + 1];
    float m = -1e30f, sumw = 0.f;
    float4 acc = make_float4(0.f, 0.f, 0.f, 0.f);

    int cb = beg;
    while (cb < end) {
        int cnt = end - cb; if (cnt > 64) cnt = 64;
        int sl = 0, el = 0;
        if (lane < cnt) { sl = csr_src[cb + lane]; el = csr_eid[cb + lane]; }
        float2 rA, rB, rC, rD;
        float4 a0, a1, b0, b1, c0, c1, d0, d1;
        fetch1_c1(xl1h, ea, sl, el, 0, cnt, c4, eam0, eam1, E, &rA, &a0, &a1);
        fetch1_c1(xl1h, ea, sl, el, 1, cnt, c4, eam0, eam1, E, &rB, &b0, &b1);
        for (int j = 0; j < cnt; j += 2) {
            fetch1_c1(xl1h, ea, sl, el, j + 2, cnt, c4, eam0, eam1, E, &rC, &c0, &c1);
            fetch1_c1(xl1h, ea, sl, el, j + 3, cnt, c4, eam0, eam1, E, &rD, &d0, &d1);
            float4 xsA, xsB;
            float pA = logit_c1(rA, a0, a1, we, xr4, at4, &xsA);
            if (j + 1 < cnt) {
                float pB = logit_c1(rB, b0, b1, we, xr4, at4, &xsB);
                float mn = fmaxf(m, fmaxf(pA, pB));
                float sc = expf(m - mn);
                float wa = expf(pA - mn);
                float wb = expf(pB - mn);
                acc.x = acc.x * sc + wa * xsA.x + wb * xsB.x;
                acc.y = acc.y * sc + wa * xsA.y + wb * xsB.y;
                acc.z = acc.z * sc + wa * xsA.z + wb * xsB.z;
                acc.w = acc.w * sc + wa * xsA.w + wb * xsB.w;
                sumw = sumw * sc + wa + wb;
                m = mn;
            } else {
                float mn = fmaxf(m, pA);
                float sc = expf(m - mn);
                float wa = expf(pA - mn);
                acc.x = acc.x * sc + wa * xsA.x;
                acc.y = acc.y * sc + wa * xsA.y;
                acc.z = acc.z * sc + wa * xsA.z;
                acc.w = acc.w * sc + wa * xsA.w;
                sumw = sumw * sc + wa;
                m = mn;
            }
            rA = rC; a0 = c0; a1 = c1;
            rB = rD; b0 = d0; b1 = d1;
        }
        cb += cnt;
    }
    float inv = 1.f / (sumw + 1e-16f);
    float4 r = make_float4(0.f, 0.f, 0.f, 0.f);
#pragma unroll
    for (int q = 0; q < 4; q++) {
        float4 xq = *(const float4*)(x + (size_t)node * 16 + q * 4);
        float xa[4] = { xq.x, xq.y, xq.z, xq.w };
#pragma unroll
        for (int kk = 0; kk < 4; kk++) {
            float4 wv = *(const float4*)(Wres + (size_t)(q * 4 + kk) * 256 + c4);
            r.x += xa[kk] * wv.x; r.y += xa[kk] * wv.y;
            r.z += xa[kk] * wv.z; r.w += xa[kk] * wv.w;
        }
    }
    float4 bi = *(const float4*)(bias1 + c4);
    float4 g4 = *(const float4*)(g + c4);
    float4 b4 = *(const float4*)(bb_ + c4);
    float4 m4 = *(const float4*)(mm_ + c4);
    float4 v4 = *(const float4*)(vv_ + c4);
    float4 o;
    o.x = acc.x * inv + bi.x; o.y = acc.y * inv + bi.y;
    o.z = acc.z * inv + bi.z; o.w = acc.w * inv + bi.w;
    o.x = (o.x - m4.x) * rsqrtf(v4.x + 1e-5f) * g4.x + b4.x + r.x;
    o.y = (o.y - m4.y) * rsqrtf(v4.y + 1e-5f) * g4.y + b4.y + r.y;
    o.z = (o.z - m4.z) * rsqrtf(v4.z + 1e-5f) * g4.z + b4.z + r.z;
    o.w = (o.w - m4.w) * rsqrtf(v4.w + 1e-5f) * g4.w + b4.w + r.w;
    o.x = elu_f(o.x); o.y = elu_f(o.y); o.z = elu_f(o.z); o.w = elu_f(o.w);
    *(float4*)(h1 + (size_t)node * 256 + c4) = o;
}

// ---------- xl2(fp16) = h1@Wl2+bl2, xr2(fp32) = h1@Wr2+br2 ----------
__global__ __launch_bounds__(256) void k_xlr2(const float* __restrict__ h1,
                                              const float* __restrict__ Wl2, const float* __restrict__ bl2,
                                              const float* __restrict__ Wr2, const float* __restrict__ br2,
                                              __half* __restrict__ xl2h, float* __restrict__ xr2, int N) {
    __shared__ float sh[32][32];    // [kk][node]
    __shared__ float sw[32][128];   // [kk][col]
    int t = threadIdx.x;
    int tr = t >> 5, tc = t & 31;
    int n0 = blockIdx.x * 32;
    float acc[4][4];
#pragma unroll
    for (int i = 0; i < 4; i++)
#pragma unroll
        for (int j = 0; j < 4; j++) acc[i][j] = 0.f;
    for (int k0 = 0; k0 < 256; k0 += 32) {
        {
            int n = t >> 3, kk0 = (t & 7) * 4;
            int gn = n0 + n;
            float4 hv = make_float4(0.f, 0.f, 0.f, 0.f);
            if (gn < N) hv = *(const float4*)(h1 + (size_t)gn * 256 + k0 + kk0);
            sh[kk0 + 0][n] = hv.x; sh[kk0 + 1][n] = hv.y; sh[kk0 + 2][n] = hv.z; sh[kk0 + 3][n] = hv.w;
        }
        for (int i = t; i < 32 * 128; i += 256) {
            int kk = i >> 7, c = i & 127;
            sw[kk][c] = (c < 64) ? Wl2[(size_t)(k0 + kk) * 64 + c] : Wr2[(size_t)(k0 + kk) * 64 + (c - 64)];
        }
        __syncthreads();
#pragma unroll
        for (int kk = 0; kk < 32; kk++) {
            float4 hv = *(const float4*)&sh[kk][tr * 4];
            float4 wv = *(const float4*)&sw[kk][tc * 4];
            float hh[4] = { hv.x, hv.y, hv.z, hv.w };
            float wwv[4] = { wv.x, wv.y, wv.z, wv.w };
#pragma unroll
            for (int i = 0; i < 4; i++)
#pragma unroll
                for (int j = 0; j < 4; j++) acc[i][j] += hh[i] * wwv[j];
        }
        __syncthreads();
    }
#pragma unroll
    for (int i = 0; i < 4; i++) {
        int gn = n0 + tr * 4 + i;
        if (gn >= N) continue;
#pragma unroll
        for (int j = 0; j < 4; j++) {
            int c = tc * 4 + j;
            float vv = acc[i][j];
            if (c < 64) xl2h[(size_t)gn * 64 + c] = __float2half(vv + bl2[c]);
            else        xr2[(size_t)gn * 64 + (c - 64)] = vv + br2[c - 64];
        }
    }
}

// ---------- fused conv2: uniform-ea, pair-merged online softmax ----------
__device__ __forceinline__ void fetch1_c2(const __half* __restrict__ xl2h, const float* __restrict__ ea,
                                          int sl, int el, int j, int cnt, int lane,
                                          float4 eam0, float4 eam1, int E,
                                          float* row, float4* e0, float4* e1) {
    if (j < cnt) {
        int s = __shfl(sl, j, 64);
        int e = __shfl(el, j, 64);
        *row = __half2float(xl2h[(size_t)s * 64 + lane]);
        if (e < E) {
            *e0 = *(const float4*)(ea + (size_t)e * 8);
            *e1 = *(const float4*)(ea + (size_t)e * 8 + 4);
        } else { *e0 = eam0; *e1 = eam1; }
    } else {
        *row = 0.f; *e0 = eam0; *e1 = eam1;
    }
}

__device__ __forceinline__ float logit_c2(float xs, float4 e0, float4 e1,
                                          const float* we, float xr, float at) {
    float ev[8] = { e0.x, e0.y, e0.z, e0.w, e1.x, e1.y, e1.z, e1.w };
    float v = xs + xr;
#pragma unroll
    for (int k = 0; k < 8; k++) v += ev[k] * we[k];
    v = v > 0.f ? v : 0.2f * v;
    float p = v * at;
#pragma unroll
    for (int o = 32; o; o >>= 1) p += __shfl_xor(p, o, 64);
    return p;
}

__global__ __launch_bounds__(256) void k_fagg2(const __half* __restrict__ xl2h, const float* __restrict__ xr2,
                                               const int* __restrict__ off, const int* __restrict__ csr_src,
                                               const int* __restrict__ csr_eid,
                                               const float* __restrict__ ea, const float* __restrict__ ea_sum,
                                               const float* __restrict__ We2, const float* __restrict__ att2,
                                               const float* __restrict__ bias2,
                                               const float* __restrict__ g, const float* __restrict__ bb_,
                                               const float* __restrict__ mm_, const float* __restrict__ vv_,
                                               __half* __restrict__ h2h,
                                               int E, int N) {
    int t = threadIdx.x;
    int lane = t & 63, w = t >> 6;
    int node = blockIdx.x * 4 + w;
    if (node >= N) return;
    float we[8];
#pragma unroll
    for (int k = 0; k < 8; k++) we[k] = We2[k * 64 + lane];
    float xr = xr2[(size_t)node * 64 + lane];
    float at = att2[lane];
    float invE = 1.f / (float)E;
    float4 eam0, eam1;
    eam0.x = ea_sum[0] * invE; eam0.y = ea_sum[1] * invE;
    eam0.z = ea_sum[2] * invE; eam0.w = ea_sum[3] * invE;
    eam1.x = ea_sum[4] * invE; eam1.y = ea_sum[5] * invE;
    eam1.z = ea_sum[6] * invE; eam1.w = ea_sum[7] * invE;

    int beg = off[node], end = off[node + 1];
    float m = -1e30f, sumw = 0.f, acc = 0.f;

    int cb = beg;
    while (cb < end) {
        int cnt = end - cb; if (cnt > 64) cnt = 64;
        int sl = 0, el = 0;
        if (lane < cnt) { sl = csr_src[cb + lane]; el = csr_eid[cb + lane]; }
        float rA, rB, rC, rD;
        float4 a0, a1, b0, b1, c0, c1, d0, d1;
        fetch1_c2(xl2h, ea, sl, el, 0, cnt, lane, eam0, eam1, E, &rA, &a0, &a1);
        fetch1_c2(xl2h, ea, sl, el, 1, cnt, lane, eam0, eam1, E, &rB, &b0, &b1);
        for (int j = 0; j < cnt; j += 2) {
            fetch1_c2(xl2h, ea, sl, el, j + 2, cnt, lane, eam0, eam1, E, &rC, &c0, &c1);
            fetch1_c2(xl2h, ea, sl, el, j + 3, cnt, lane, eam0, eam1, E, &rD, &d0, &d1);
            float pA = logit_c2(rA, a0, a1, we, xr, at);
            if (j + 1 < cnt) {
                float pB = logit_c2(rB, b0, b1, we, xr, at);
                float mn = fmaxf(m, fmaxf(pA, pB));
                float sc = expf(m - mn);
                float wa = expf(pA - mn);
                float wb = expf(pB - mn);
                acc = acc * sc + wa * rA + wb * rB;
                sumw = sumw * sc + wa + wb;
                m = mn;
            } else {
                float mn = fmaxf(m, pA);
                float sc = expf(m - mn);
                float wa = expf(pA - mn);
                acc = acc * sc + wa * rA;
                sumw = sumw * sc + wa;
                m = mn;
            }
            rA = rC; a0 = c0; a1 = c1;
            rB = rD; b0 = d0; b1 = d1;
        }
        cb += cnt;
    }
    float val = acc / (sumw + 1e-16f) + bias2[lane];
    val = (val - mm_[lane]) * rsqrtf(vv_[lane] + 1e-5f) * g[lane] + bb_[lane];
    h2h[(size_t)node * 64 + lane] = __float2half(elu_f(val));
}

// ---------- u = h2@Wm1[0:64], v = h2@Wm1[64:128]  (fp16 out, no bias) ----------
__global__ __launch_bounds__(256) void k_uv(const __half* __restrict__ h2h, const float* __restrict__ Wm1,
                                            __half* __restrict__ uh, __half* __restrict__ vh, int N) {
    __shared__ float sh[32][32];    // [kk][node]
    __shared__ float sw[32][128];   // [kk][col]  (u cols 0..63, v cols 64..127)
    int t = threadIdx.x;
    int tr = t >> 5, tc = t & 31;
    int n0 = blockIdx.x * 32;
    float acc[4][4];
#pragma unroll
    for (int i = 0; i < 4; i++)
#pragma unroll
        for (int j = 0; j < 4; j++) acc[i][j] = 0.f;
    for (int k0 = 0; k0 < 64; k0 += 32) {
        {
            int n = t >> 3, kk0 = (t & 7) * 4;
            int gn = n0 + n;
            float4 hv = make_float4(0.f, 0.f, 0.f, 0.f);
            if (gn < N) {
                uint2 raw = *(const uint2*)(h2h + (size_t)gn * 64 + k0 + kk0);
                __half2 a = *(__half2*)&raw.x, b = *(__half2*)&raw.y;
                float2 fa = __half22float2(a), fb = __half22float2(b);
                hv = make_float4(fa.x, fa.y, fb.x, fb.y);
            }
            sh[kk0 + 0][n] = hv.x; sh[kk0 + 1][n] = hv.y; sh[kk0 + 2][n] = hv.z; sh[kk0 + 3][n] = hv.w;
        }
        for (int i = t; i < 32 * 128; i += 256) {
            int kk = i >> 7, c = i & 127;
            sw[kk][c] = (c < 64) ? Wm1[(size_t)(k0 + kk) * 64 + c]
                                 : Wm1[(size_t)(64 + k0 + kk) * 64 + (c - 64)];
        }
        __syncthreads();
#pragma unroll
        for (int kk = 0; kk < 32; kk++) {
            float4 hv = *(const float4*)&sh[kk][tr * 4];
            float4 wv = *(const float4*)&sw[kk][tc * 4];
            float hh[4] = { hv.x, hv.y, hv.z, hv.w };
            float wwv[4] = { wv.x, wv.y, wv.z, wv.w };
#pragma unroll
            for (int i = 0; i < 4; i++)
#pragma unroll
                for (int j = 0; j < 4; j++) acc[i][j] += hh[i] * wwv[j];
        }
        __syncthreads();
    }
#pragma unroll
    for (int i = 0; i < 4; i++) {
        int gn = n0 + tr * 4 + i;
        if (gn >= N) continue;
#pragma unroll
        for (int j = 0; j < 4; j++) {
            int c = tc * 4 + j;
            if (c < 64) uh[(size_t)gn * 64 + c] = __float2half(acc[i][j]);
            else        vh[(size_t)gn * 64 + (c - 64)] = __float2half(acc[i][j]);
        }
    }
}

// ---------- weA[e] = ea[e]@Wm1[128:136] + bm1  (fp16 out, coalesced) ----------
__global__ __launch_bounds__(256) void k_wea(const float* __restrict__ ea, const float* __restrict__ Wm1,
                                             const float* __restrict__ bm1,
                                             __half* __restrict__ weAh, int E) {
    __shared__ float sW[8 * 64];
    int t = threadIdx.x;
    for (int i = t; i < 512; i += 256) sW[i] = Wm1[128 * 64 + i];
    __syncthreads();
    int i = blockIdx.x * 256 + t;
    if (i >= E * 8) return;
    int e = i >> 3, q = i & 7;
    float4 a0 = *(const float4*)(ea + (size_t)e * 8);
    float4 a1 = *(const float4*)(ea + (size_t)e * 8 + 4);
    float av[8] = { a0.x, a0.y, a0.z, a0.w, a1.x, a1.y, a1.z, a1.w };
    float o[8];
#pragma unroll
    for (int j = 0; j < 8; j++) o[j] = bm1[q * 8 + j];
#pragma unroll
    for (int k = 0; k < 8; k++) {
        float a = av[k];
#pragma unroll
        for (int j = 0; j < 8; j++) o[j] += a * sW[k * 64 + q * 8 + j];
    }
    __half2 h[4];
#pragma unroll
    for (int j = 0; j < 4; j++) h[j] = __floats2half2_rn(o[2 * j], o[2 * j + 1]);
    *(uint4*)(weAh + (size_t)e * 64 + q * 8) = *(uint4*)h;
}

// ---------- edge MLP head v2: z1 = gelu(u[r]+v[c]+weA[e]); layer2+3 fused ----------
__global__ __launch_bounds__(256) void k_mlp2(const __half* __restrict__ uh, const __half* __restrict__ vh,
                                              const __half* __restrict__ weAh, const int* __restrict__ ei,
                                              const float* __restrict__ Wm2, const float* __restrict__ bm2,
                                              const float* __restrict__ Wm3, const float* __restrict__ bm3,
                                              float* __restrict__ out, int E) {
    __shared__ float sw2[64 * 32];
    __shared__ int sre[64], sce[64];
    __shared__ float z1[64 * 68];
    int t = threadIdx.x;
    for (int i = t; i < 64 * 32; i += 256) sw2[i] = Wm2[i];
    int e0 = blockIdx.x * 64;
    if (t < 64) {
        int e = e0 + t;
        if (e < E) { sre[t] = ei[e]; sce[t] = ei[E + e]; }
        else { sre[t] = 0; sce[t] = 0; }
    }
    __syncthreads();
    for (int i = t; i < 512; i += 256) {
        int el = i >> 3, q = i & 7;
        int r = sre[el], c = sce[el];
        uint4 ru = *(const uint4*)(uh + (size_t)r * 64 + q * 8);
        uint4 rv = *(const uint4*)(vh + (size_t)c * 64 + q * 8);
        uint4 rw = *(const uint4*)(weAh + (size_t)(e0 + el) * 64 + q * 8);
        float4 uhi, vhi, whi;
        float4 ulo = half8_lo_hi(ru, &uhi);
        float4 vlo = half8_lo_hi(rv, &vhi);
        float4 wlo = half8_lo_hi(rw, &whi);
        float4 zlo, zhi;
        zlo.x = gelu_f(ulo.x + vlo.x + wlo.x);
        zlo.y = gelu_f(ulo.y + vlo.y + wlo.y);
        zlo.z = gelu_f(ulo.z + vlo.z + wlo.z);
        zlo.w = gelu_f(ulo.w + vlo.w + wlo.w);
        zhi.x = gelu_f(uhi.x + vhi.x + whi.x);
        zhi.y = gelu_f(uhi.y + vhi.y + whi.y);
        zhi.z = gelu_f(uhi.z + vhi.z + whi.z);
        zhi.w = gelu_f(uhi.w + vhi.w + whi.w);
        *(float4*)(z1 + el * 68 + q * 8)     = zlo;
        *(float4*)(z1 + el * 68 + q * 8 + 4) = zhi;
    }
    __syncthreads();
    int tr = t >> 3;
    int tc = t & 7;
    float b2[4], w3[4];
#pragma unroll
    for (int j = 0; j < 4; j++) { b2[j] = bm2[tc * 4 + j]; w3[j] = Wm3[tc * 4 + j]; }
    float b3 = bm3[0];
    float acc0[4], acc1[4];
#pragma unroll
    for (int j = 0; j < 4; j++) { acc0[j] = 0.f; acc1[j] = 0.f; }
    const float* z0p = z1 + (tr * 2 + 0) * 68;
    const float* z1p = z1 + (tr * 2 + 1) * 68;
#pragma unroll 8
    for (int k = 0; k < 64; k++) {
        float4 wv = *(const float4*)(sw2 + k * 32 + tc * 4);
        float a0 = z0p[k];
        float a1 = z1p[k];
        acc0[0] += a0 * wv.x; acc0[1] += a0 * wv.y; acc0[2] += a0 * wv.z; acc0[3] += a0 * wv.w;
        acc1[0] += a1 * wv.x; acc1[1] += a1 * wv.y; acc1[2] += a1 * wv.z; acc1[3] += a1 * wv.w;
    }
    float p0 = 0.f, p1 = 0.f;
#pragma unroll
    for (int j = 0; j < 4; j++) {
        p0 += gelu_f(acc0[j] + b2[j]) * w3[j];
        p1 += gelu_f(acc1[j] + b2[j]) * w3[j];
    }
    p0 += __shfl_xor(p0, 1, 64); p0 += __shfl_xor(p0, 2, 64); p0 += __shfl_xor(p0, 4, 64);
    p1 += __shfl_xor(p1, 1, 64); p1 += __shfl_xor(p1, 2, 64); p1 += __shfl_xor(p1, 4, 64);
    if (tc == 0) {
        int e = e0 + tr * 2;
        if (e < E)     out[e]     = 1.f / (1.f + expf(-(p0 + b3)));
        if (e + 1 < E) out[e + 1] = 1.f / (1.f + expf(-(p1 + b3)));
    }
}

extern "C" void kernel_launch(void* const* d_in, const int* in_sizes, int n_in,
                              void* d_out, int out_size, void* d_ws, size_t ws_size,
                              hipStream_t stream) {
    const float* x    = (const float*)d_in[0];
    const int*   ei   = (const int*)d_in[1];
    const float* ea   = (const float*)d_in[2];
    const float* Wl1  = (const float*)d_in[3];
    const float* bl1  = (const float*)d_in[4];
    const float* Wr1  = (const float*)d_in[5];
    const float* br1  = (const float*)d_in[6];
    const float* We1  = (const float*)d_in[7];
    const float* att1 = (const float*)d_in[8];
    const float* bias1= (const float*)d_in[9];
    const float* Wl2  = (const float*)d_in[10];
    const float* bl2  = (const float*)d_in[11];
    const float* Wr2  = (const float*)d_in[12];
    const float* br2  = (const float*)d_in[13];
    const float* We2  = (const float*)d_in[14];
    const float* att2 = (const float*)d_in[15];
    const float* bias2= (const float*)d_in[16];
    const float* bn1g = (const float*)d_in[17];
    const float* bn1b = (const float*)d_in[18];
    const float* bn1m = (const float*)d_in[19];
    const float* bn1v = (const float*)d_in[20];
    const float* bn2g = (const float*)d_in[21];
    const float* bn2b = (const float*)d_in[22];
    const float* bn2m = (const float*)d_in[23];
    const float* bn2v = (const float*)d_in[24];
    const float* Wres = (const float*)d_in[25];
    const float* Wm1  = (const float*)d_in[26];
    const float* bm1  = (const float*)d_in[27];
    const float* Wm2  = (const float*)d_in[28];
    const float* bm2  = (const float*)d_in[29];
    const float* Wm3  = (const float*)d_in[30];
    const float* bm3  = (const float*)d_in[31];
    float* out = (float*)d_out;
    float* ws = (float*)d_ws;

    const int N = NN, E = EE, Etot = ETOT;

    // workspace layout (floats)
    float* ea_sum   = ws;                                     // 16
    int*   counts   = (int*)(ws + 16);                        // N
    int*   off      = (int*)(ws + 16 + (size_t)N);            // N+16
    int*   cursor   = (int*)(ws + 32 + (size_t)2 * N);        // N
    int*   csr_src  = (int*)(ws + 32 + (size_t)3 * N);        // Etot
    int*   csr_eid  = (int*)(ws + 32 + (size_t)3 * N + Etot); // Etot
    size_t base     = 32 + (size_t)3 * N + (size_t)2 * Etot;
    __half* xl1h    = (__half*)(ws + base);                   // 256N halfs = 128N floats
    __half* xl2h    = xl1h;                                   // reuses (xl1h dead after k_fagg1)
    __half* h2h     = (__half*)(ws + base + (size_t)128 * N); // 64N halfs = 32N floats
    float* xr1      = ws + base + (size_t)160 * N;            // 256N floats
    float* h1       = xr1;                                    // in-place (row read before write)
    __half* weAh    = (__half*)xr1;                           // E*64 halfs (h1 dead after k_xlr2)
    float* xr2      = xr1 + (size_t)256 * N;                  // 64N floats
    __half* uh      = (__half*)xr2;                           // 64N halfs
    __half* vh      = uh + (size_t)64 * N;                    // 64N halfs (xr2 dead after k_fagg2)

    hipMemsetAsync(ea_sum, 0, 16 * sizeof(float), stream);
    hipMemsetAsync(counts, 0, (size_t)N * sizeof(int), stream);

    k_ea_reduce<<<256, 256, 0, stream>>>(ea, ea_sum, E);
    k_count<<<(Etot + 255) / 256, 256, 0, stream>>>(ei, counts, E, N);
    k_scan<<<1, 1024, 0, stream>>>(counts, off, cursor, N);
    k_scatter<<<(Etot + 255) / 256, 256, 0, stream>>>(ei, cursor, csr_src, csr_eid, E, N);
    k_ntrans1<<<(N + 31) / 32, 256, 0, stream>>>(x, Wl1, bl1, Wr1, br1, xl1h, xr1, N);
    k_fagg1<<<(N + 3) / 4, 256, 0, stream>>>(xl1h, xr1, off, csr_src, csr_eid, ea, ea_sum,
                                             We1, att1, bias1, x, Wres,
                                             bn1g, bn1b, bn1m, bn1v, h1, E, N);
    k_xlr2<<<(N + 31) / 32, 256, 0, stream>>>(h1, Wl2, bl2, Wr2, br2, xl2h, xr2, N);
    k_fagg2<<<(N + 3) / 4, 256, 0, stream>>>(xl2h, xr2, off, csr_src, csr_eid, ea, ea_sum,
                                             We2, att2, bias2,
                                             bn2g, bn2b, bn2m, bn2v, h2h, E, N);
    // h1 (xr1 region) now dead -> weAh overlay; xr2 now dead -> uh/vh overlay
    k_wea<<<(E * 8 + 255) / 256, 256, 0, stream>>>(ea, Wm1, bm1, weAh, E);
    k_uv<<<(N + 31) / 32, 256, 0, stream>>>(h2h, Wm1, uh, vh, N);
    k_mlp2<<<(E + 63) / 64, 256, 0, stream>>>(uh, vh, weAh, ei, Wm2, bm2, Wm3, bm3, out, E);
}

// Round 10
// 506.110 us; speedup vs baseline: 1.1764x; 1.1764x over previous
//
#include <hip/hip_runtime.h>
#include <hip/hip_bf16.h>
#include <hip/hip_fp16.h>
#include <math.h>

#define NN 50000
#define EE 400000
#define ETOT (NN + EE)

// ---------- helpers ----------
__device__ __forceinline__ float gelu_f(float x) {
    return 0.5f * x * (1.f + erff(x * 0.7071067811865476f));
}
__device__ __forceinline__ float elu_f(float x) {
    return x > 0.f ? x : expm1f(x);
}
__device__ __forceinline__ float4 half8_lo_hi(uint4 raw, float4* hi) {
    __half2 h0 = *(__half2*)&raw.x, h1 = *(__half2*)&raw.y;
    __half2 h2 = *(__half2*)&raw.z, h3 = *(__half2*)&raw.w;
    float2 f0 = __half22float2(h0), f1 = __half22float2(h1);
    float2 f2 = __half22float2(h2), f3 = __half22float2(h3);
    *hi = make_float4(f2.x, f2.y, f3.x, f3.y);
    return make_float4(f0.x, f0.y, f1.x, f1.y);
}

// ---------- combined: ea mean (sum) [blocks 0..255] + degree count [blocks 256..] ----------
__global__ __launch_bounds__(256) void k_init(const float* __restrict__ ea, float* __restrict__ ea_sum,
                                              const int* __restrict__ ei, int* __restrict__ counts,
                                              int E, int N) {
    int t = threadIdx.x;
    if (blockIdx.x < 256) {
        float s[8];
#pragma unroll
        for (int i = 0; i < 8; i++) s[i] = 0.f;
        for (int e = blockIdx.x * 256 + t; e < E; e += 256 * 256) {
            const float4* p = (const float4*)(ea + (size_t)e * 8);
            float4 a = p[0], b = p[1];
            s[0] += a.x; s[1] += a.y; s[2] += a.z; s[3] += a.w;
            s[4] += b.x; s[5] += b.y; s[6] += b.z; s[7] += b.w;
        }
#pragma unroll
        for (int o = 32; o; o >>= 1)
#pragma unroll
            for (int i = 0; i < 8; i++) s[i] += __shfl_xor(s[i], o, 64);
        __shared__ float sh[4][8];
        int lane = t & 63, w = t >> 6;
        if (lane == 0)
#pragma unroll
            for (int i = 0; i < 8; i++) sh[w][i] = s[i];
        __syncthreads();
        if (t < 8) {
            float v = sh[0][t] + sh[1][t] + sh[2][t] + sh[3][t];
            atomicAdd(ea_sum + t, v);
        }
    } else {
        int e = (blockIdx.x - 256) * 256 + t;
        if (e >= E + N) return;
        int d = (e < E) ? ei[E + e] : (e - E);
        atomicAdd(counts + d, 1);
    }
}

// ---------- scan (4 elems/thread) ----------
__global__ __launch_bounds__(1024) void k_scan(const int* __restrict__ counts, int* __restrict__ off,
                                               int* __restrict__ cursor, int N) {
    __shared__ int buf[1024];
    int t = threadIdx.x;
    int carry = 0;
    if (t == 0) off[0] = 0;
    for (int base = 0; base < N; base += 4096) {
        int i0 = base + t * 4;
        int v0 = 0, v1 = 0, v2 = 0, v3 = 0;
        if (i0 + 3 < N) {
            int4 vv = *(const int4*)(counts + i0);
            v0 = vv.x; v1 = vv.y; v2 = vv.z; v3 = vv.w;
        } else {
            if (i0 < N)     v0 = counts[i0];
            if (i0 + 1 < N) v1 = counts[i0 + 1];
            if (i0 + 2 < N) v2 = counts[i0 + 2];
            if (i0 + 3 < N) v3 = counts[i0 + 3];
        }
        int s01 = v0 + v1, s012 = s01 + v2, tot4 = s012 + v3;
        buf[t] = tot4;
        __syncthreads();
        for (int o = 1; o < 1024; o <<= 1) {
            int add = (t >= o) ? buf[t - o] : 0;
            __syncthreads();
            buf[t] += add;
            __syncthreads();
        }
        int incl4 = buf[t] + carry;
        int excl = incl4 - tot4;
        if (i0 < N)     { off[i0 + 1] = excl + v0;   cursor[i0]     = excl; }
        if (i0 + 1 < N) { off[i0 + 2] = excl + s01;  cursor[i0 + 1] = excl + v0; }
        if (i0 + 2 < N) { off[i0 + 3] = excl + s012; cursor[i0 + 2] = excl + s01; }
        if (i0 + 3 < N) { off[i0 + 4] = excl + tot4; cursor[i0 + 3] = excl + s012; }
        int tot = buf[1023];
        __syncthreads();
        carry += tot;
    }
}

// ---------- combined: scatter [blocks 0..S) + ntrans1 [blocks S..) ----------
__global__ __launch_bounds__(256) void k_scat_nt1(const int* __restrict__ ei, int* __restrict__ cursor,
                                                  int* __restrict__ csr_src, int* __restrict__ csr_eid,
                                                  const float* __restrict__ x,
                                                  const float* __restrict__ Wl, const float* __restrict__ bl,
                                                  const float* __restrict__ Wr, const float* __restrict__ br,
                                                  __half* __restrict__ xl1h, float* __restrict__ xr1,
                                                  int E, int N) {
    __shared__ float swl[16 * 256];
    __shared__ float swr[16 * 256];
    __shared__ float sx[32 * 16];
    int t = threadIdx.x;
    int S = (E + N + 255) >> 8;
    if ((int)blockIdx.x < S) {
        int e = blockIdx.x * 256 + t;
        if (e >= E + N) return;
        int s, d;
        if (e < E) { s = ei[e]; d = ei[E + e]; }
        else { s = d = e - E; }
        int pos = atomicAdd(cursor + d, 1);
        csr_src[pos] = s;
        csr_eid[pos] = e;
        return;
    }
    int bid = blockIdx.x - S;
#pragma unroll
    for (int k = 0; k < 16; k++) { swl[k * 256 + t] = Wl[k * 256 + t]; swr[k * 256 + t] = Wr[k * 256 + t]; }
    int n0 = bid * 32;
    for (int i = t; i < 32 * 16; i += 256) {
        int n = n0 + (i >> 4);
        sx[i] = (n < N) ? x[(size_t)n * 16 + (i & 15)] : 0.f;
    }
    __syncthreads();
    float bL = bl[t], bR = br[t];
    for (int ni = 0; ni < 32; ni++) {
        int n = n0 + ni;
        if (n >= N) break;
        float al = bL, ar = bR;
#pragma unroll
        for (int k = 0; k < 16; k++) {
            float xv = sx[ni * 16 + k];
            al += xv * swl[k * 256 + t];
            ar += xv * swr[k * 256 + t];
        }
        xl1h[(size_t)n * 256 + t] = __float2half(al);
        xr1[(size_t)n * 256 + t] = ar;
    }
}

// ---------- fused conv1: zero-LDS, chunked index/ea broadcast, depth-3 row prefetch (round-8 verified) ----------
__global__ __launch_bounds__(256) void k_fagg1(const __half* __restrict__ xl1h, const float* __restrict__ xr1,
                                               const int* __restrict__ off, const int* __restrict__ csr_src,
                                               const int* __restrict__ csr_eid,
                                               const float* __restrict__ ea, const float* __restrict__ ea_sum,
                                               const float* __restrict__ We1, const float* __restrict__ att1,
                                               const float* __restrict__ bias1,
                                               const float* __restrict__ x, const float* __restrict__ Wres,
                                               const float* __restrict__ g, const float* __restrict__ bb_,
                                               const float* __restrict__ mm_, const float* __restrict__ vv_,
                                               float* __restrict__ h1,
                                               int E, int N) {
    int t = threadIdx.x;
    int lane = t & 63, w = t >> 6;
    int node = blockIdx.x * 4 + w;
    if (node >= N) return;
    int c4 = lane * 4;
    float4 we[8];
#pragma unroll
    for (int k = 0; k < 8; k++) we[k] = *(const float4*)(We1 + k * 256 + c4);
    float4 xr4 = *(const float4*)(xr1 + (size_t)node * 256 + c4);
    float4 at4 = *(const float4*)(att1 + c4);
    float invE = 1.f / (float)E;
    float4 eam0, eam1;
    eam0.x = ea_sum[0] * invE; eam0.y = ea_sum[1] * invE;
    eam0.z = ea_sum[2] * invE; eam0.w = ea_sum[3] * invE;
    eam1.x = ea_sum[4] * invE; eam1.y = ea_sum[5] * invE;
    eam1.z = ea_sum[6] * invE; eam1.w = ea_sum[7] * invE;

    int beg = off[node], end = off[node + 1];
    float m = -1e30f, sumw = 0.f;
    float4 acc = make_float4(0.f, 0.f, 0.f, 0.f);

    int cb = beg;
    while (cb < end) {
        int cnt = end - cb; if (cnt > 64) cnt = 64;
        int sl = 0;
        float4 ba = eam0, bb4 = eam1;
        if (lane < cnt) {
            sl = csr_src[cb + lane];
            int el = csr_eid[cb + lane];
            if (el < E) {
                ba  = *(const float4*)(ea + (size_t)el * 8);
                bb4 = *(const float4*)(ea + (size_t)el * 8 + 4);
            }
        }
        float2 r0 = make_float2(0.f, 0.f), r1 = r0, r2 = r0;
        {
            int s0 = __shfl(sl, 0, 64);
            r0 = *(const float2*)(xl1h + (size_t)s0 * 256 + c4);
            if (cnt > 1) { int s1 = __shfl(sl, 1, 64); r1 = *(const float2*)(xl1h + (size_t)s1 * 256 + c4); }
            if (cnt > 2) { int s2 = __shfl(sl, 2, 64); r2 = *(const float2*)(xl1h + (size_t)s2 * 256 + c4); }
        }
        for (int j = 0; j < cnt; j++) {
            float2 cur = r0;
            r0 = r1; r1 = r2;
            if (j + 3 < cnt) {
                int s3 = __shfl(sl, j + 3, 64);
                r2 = *(const float2*)(xl1h + (size_t)s3 * 256 + c4);
            }
            float eav[8];
            eav[0] = __shfl(ba.x, j, 64);  eav[1] = __shfl(ba.y, j, 64);
            eav[2] = __shfl(ba.z, j, 64);  eav[3] = __shfl(ba.w, j, 64);
            eav[4] = __shfl(bb4.x, j, 64); eav[5] = __shfl(bb4.y, j, 64);
            eav[6] = __shfl(bb4.z, j, 64); eav[7] = __shfl(bb4.w, j, 64);
            const __half2* hp = (const __half2*)&cur;
            float2 lo = __half22float2(hp[0]);
            float2 hi = __half22float2(hp[1]);
            float4 xs = make_float4(lo.x, lo.y, hi.x, hi.y);
            float4 ee = make_float4(0.f, 0.f, 0.f, 0.f);
#pragma unroll
            for (int k = 0; k < 8; k++) {
                ee.x += eav[k] * we[k].x; ee.y += eav[k] * we[k].y;
                ee.z += eav[k] * we[k].z; ee.w += eav[k] * we[k].w;
            }
            float4 v;
            v.x = xs.x + xr4.x + ee.x; v.y = xs.y + xr4.y + ee.y;
            v.z = xs.z + xr4.z + ee.z; v.w = xs.w + xr4.w + ee.w;
            v.x = v.x > 0.f ? v.x : 0.2f * v.x;
            v.y = v.y > 0.f ? v.y : 0.2f * v.y;
            v.z = v.z > 0.f ? v.z : 0.2f * v.z;
            v.w = v.w > 0.f ? v.w : 0.2f * v.w;
            float p = v.x * at4.x + v.y * at4.y + v.z * at4.z + v.w * at4.w;
            p += __shfl_xor(p, 1, 64);
            p += __shfl_xor(p, 2, 64);
            p += __shfl_xor(p, 4, 64);
            p += __shfl_xor(p, 8, 64);
            float mn = fmaxf(m, p);
            float sc = expf(m - mn);
            float wgt = expf(p - mn);
            acc.x = acc.x * sc + wgt * xs.x;
            acc.y = acc.y * sc + wgt * xs.y;
            acc.z = acc.z * sc + wgt * xs.z;
            acc.w = acc.w * sc + wgt * xs.w;
            sumw = sumw * sc + wgt;
            m = mn;
        }
        cb += cnt;
    }
    float inv = 1.f / (sumw + 1e-16f);
    float4 r = make_float4(0.f, 0.f, 0.f, 0.f);
#pragma unroll
    for (int q = 0; q < 4; q++) {
        float4 xq = *(const float4*)(x + (size_t)node * 16 + q * 4);
        float xa[4] = { xq.x, xq.y, xq.z, xq.w };
#pragma unroll
        for (int kk = 0; kk < 4; kk++) {
            float4 wv = *(const float4*)(Wres + (size_t)(q * 4 + kk) * 256 + c4);
            r.x += xa[kk] * wv.x; r.y += xa[kk] * wv.y;
            r.z += xa[kk] * wv.z; r.w += xa[kk] * wv.w;
        }
    }
    float4 bi = *(const float4*)(bias1 + c4);
    float4 g4 = *(const float4*)(g + c4);
    float4 b4 = *(const float4*)(bb_ + c4);
    float4 m4 = *(const float4*)(mm_ + c4);
    float4 v4 = *(const float4*)(vv_ + c4);
    float4 o;
    o.x = acc.x * inv + bi.x; o.y = acc.y * inv + bi.y;
    o.z = acc.z * inv + bi.z; o.w = acc.w * inv + bi.w;
    o.x = (o.x - m4.x) * rsqrtf(v4.x + 1e-5f) * g4.x + b4.x + r.x;
    o.y = (o.y - m4.y) * rsqrtf(v4.y + 1e-5f) * g4.y + b4.y + r.y;
    o.z = (o.z - m4.z) * rsqrtf(v4.z + 1e-5f) * g4.z + b4.z + r.z;
    o.w = (o.w - m4.w) * rsqrtf(v4.w + 1e-5f) * g4.w + b4.w + r.w;
    o.x = elu_f(o.x); o.y = elu_f(o.y); o.z = elu_f(o.z); o.w = elu_f(o.w);
    *(float4*)(h1 + (size_t)node * 256 + c4) = o;
}

// ---------- xl2(fp16) = h1@Wl2+bl2, xr2(fp32) = h1@Wr2+br2 ----------
__global__ __launch_bounds__(256) void k_xlr2(const float* __restrict__ h1,
                                              const float* __restrict__ Wl2, const float* __restrict__ bl2,
                                              const float* __restrict__ Wr2, const float* __restrict__ br2,
                                              __half* __restrict__ xl2h, float* __restrict__ xr2, int N) {
    __shared__ float sh[32][32];    // [kk][node]
    __shared__ float sw[32][128];   // [kk][col]
    int t = threadIdx.x;
    int tr = t >> 5, tc = t & 31;
    int n0 = blockIdx.x * 32;
    float acc[4][4];
#pragma unroll
    for (int i = 0; i < 4; i++)
#pragma unroll
        for (int j = 0; j < 4; j++) acc[i][j] = 0.f;
    for (int k0 = 0; k0 < 256; k0 += 32) {
        {
            int n = t >> 3, kk0 = (t & 7) * 4;
            int gn = n0 + n;
            float4 hv = make_float4(0.f, 0.f, 0.f, 0.f);
            if (gn < N) hv = *(const float4*)(h1 + (size_t)gn * 256 + k0 + kk0);
            sh[kk0 + 0][n] = hv.x; sh[kk0 + 1][n] = hv.y; sh[kk0 + 2][n] = hv.z; sh[kk0 + 3][n] = hv.w;
        }
        for (int i = t; i < 32 * 128; i += 256) {
            int kk = i >> 7, c = i & 127;
            sw[kk][c] = (c < 64) ? Wl2[(size_t)(k0 + kk) * 64 + c] : Wr2[(size_t)(k0 + kk) * 64 + (c - 64)];
        }
        __syncthreads();
#pragma unroll
        for (int kk = 0; kk < 32; kk++) {
            float4 hv = *(const float4*)&sh[kk][tr * 4];
            float4 wv = *(const float4*)&sw[kk][tc * 4];
            float hh[4] = { hv.x, hv.y, hv.z, hv.w };
            float wwv[4] = { wv.x, wv.y, wv.z, wv.w };
#pragma unroll
            for (int i = 0; i < 4; i++)
#pragma unroll
                for (int j = 0; j < 4; j++) acc[i][j] += hh[i] * wwv[j];
        }
        __syncthreads();
    }
#pragma unroll
    for (int i = 0; i < 4; i++) {
        int gn = n0 + tr * 4 + i;
        if (gn >= N) continue;
#pragma unroll
        for (int j = 0; j < 4; j++) {
            int c = tc * 4 + j;
            float vv = acc[i][j];
            if (c < 64) xl2h[(size_t)gn * 64 + c] = __float2half(vv + bl2[c]);
            else        xr2[(size_t)gn * 64 + (c - 64)] = vv + br2[c - 64];
        }
    }
}

// ---------- fused conv2: zero-LDS, chunked broadcast, depth-3 prefetch (round-8 verified) ----------
__global__ __launch_bounds__(256) void k_fagg2(const __half* __restrict__ xl2h, const float* __restrict__ xr2,
                                               const int* __restrict__ off, const int* __restrict__ csr_src,
                                               const int* __restrict__ csr_eid,
                                               const float* __restrict__ ea, const float* __restrict__ ea_sum,
                                               const float* __restrict__ We2, const float* __restrict__ att2,
                                               const float* __restrict__ bias2,
                                               const float* __restrict__ g, const float* __restrict__ bb_,
                                               const float* __restrict__ mm_, const float* __restrict__ vv_,
                                               __half* __restrict__ h2h,
                                               int E, int N) {
    int t = threadIdx.x;
    int lane = t & 63, w = t >> 6;
    int node = blockIdx.x * 4 + w;
    if (node >= N) return;
    float we[8];
#pragma unroll
    for (int k = 0; k < 8; k++) we[k] = We2[k * 64 + lane];
    float xr = xr2[(size_t)node * 64 + lane];
    float at = att2[lane];
    float invE = 1.f / (float)E;
    float4 eam0, eam1;
    eam0.x = ea_sum[0] * invE; eam0.y = ea_sum[1] * invE;
    eam0.z = ea_sum[2] * invE; eam0.w = ea_sum[3] * invE;
    eam1.x = ea_sum[4] * invE; eam1.y = ea_sum[5] * invE;
    eam1.z = ea_sum[6] * invE; eam1.w = ea_sum[7] * invE;

    int beg = off[node], end = off[node + 1];
    float m = -1e30f, sumw = 0.f, acc = 0.f;

    int cb = beg;
    while (cb < end) {
        int cnt = end - cb; if (cnt > 64) cnt = 64;
        int sl = 0;
        float4 ba = eam0, bb4 = eam1;
        if (lane < cnt) {
            sl = csr_src[cb + lane];
            int el = csr_eid[cb + lane];
            if (el < E) {
                ba  = *(const float4*)(ea + (size_t)el * 8);
                bb4 = *(const float4*)(ea + (size_t)el * 8 + 4);
            }
        }
        float r0 = 0.f, r1 = 0.f, r2 = 0.f;
        {
            int s0 = __shfl(sl, 0, 64);
            r0 = __half2float(xl2h[(size_t)s0 * 64 + lane]);
            if (cnt > 1) { int s1 = __shfl(sl, 1, 64); r1 = __half2float(xl2h[(size_t)s1 * 64 + lane]); }
            if (cnt > 2) { int s2 = __shfl(sl, 2, 64); r2 = __half2float(xl2h[(size_t)s2 * 64 + lane]); }
        }
        for (int j = 0; j < cnt; j++) {
            float xs = r0;
            r0 = r1; r1 = r2;
            if (j + 3 < cnt) {
                int s3 = __shfl(sl, j + 3, 64);
                r2 = __half2float(xl2h[(size_t)s3 * 64 + lane]);
            }
            float eav[8];
            eav[0] = __shfl(ba.x, j, 64);  eav[1] = __shfl(ba.y, j, 64);
            eav[2] = __shfl(ba.z, j, 64);  eav[3] = __shfl(ba.w, j, 64);
            eav[4] = __shfl(bb4.x, j, 64); eav[5] = __shfl(bb4.y, j, 64);
            eav[6] = __shfl(bb4.z, j, 64); eav[7] = __shfl(bb4.w, j, 64);
            float v = xs + xr;
#pragma unroll
            for (int k = 0; k < 8; k++) v += eav[k] * we[k];
            v = v > 0.f ? v : 0.2f * v;
            float p = v * at;
#pragma unroll
            for (int o = 32; o; o >>= 1) p += __shfl_xor(p, o, 64);
            float mn = fmaxf(m, p);
            float sc = expf(m - mn);
            float wgt = expf(p - mn);
            acc = acc * sc + wgt * xs;
            sumw = sumw * sc + wgt;
            m = mn;
        }
        cb += cnt;
    }
    float val = acc / (sumw + 1e-16f) + bias2[lane];
    val = (val - mm_[lane]) * rsqrtf(vv_[lane] + 1e-5f) * g[lane] + bb_[lane];
    h2h[(size_t)node * 64 + lane] = __float2half(elu_f(val));
}

// ---------- u = h2@Wm1[0:64], v = h2@Wm1[64:128]  (fp16 out, no bias) ----------
__global__ __launch_bounds__(256) void k_uv(const __half* __restrict__ h2h, const float* __restrict__ Wm1,
                                            __half* __restrict__ uh, __half* __restrict__ vh, int N) {
    __shared__ float sh[32][32];    // [kk][node]
    __shared__ float sw[32][128];   // [kk][col]  (u cols 0..63, v cols 64..127)
    int t = threadIdx.x;
    int tr = t >> 5, tc = t & 31;
    int n0 = blockIdx.x * 32;
    float acc[4][4];
#pragma unroll
    for (int i = 0; i < 4; i++)
#pragma unroll
        for (int j = 0; j < 4; j++) acc[i][j] = 0.f;
    for (int k0 = 0; k0 < 64; k0 += 32) {
        {
            int n = t >> 3, kk0 = (t & 7) * 4;
            int gn = n0 + n;
            float4 hv = make_float4(0.f, 0.f, 0.f, 0.f);
            if (gn < N) {
                uint2 raw = *(const uint2*)(h2h + (size_t)gn * 64 + k0 + kk0);
                __half2 a = *(__half2*)&raw.x, b = *(__half2*)&raw.y;
                float2 fa = __half22float2(a), fb = __half22float2(b);
                hv = make_float4(fa.x, fa.y, fb.x, fb.y);
            }
            sh[kk0 + 0][n] = hv.x; sh[kk0 + 1][n] = hv.y; sh[kk0 + 2][n] = hv.z; sh[kk0 + 3][n] = hv.w;
        }
        for (int i = t; i < 32 * 128; i += 256) {
            int kk = i >> 7, c = i & 127;
            sw[kk][c] = (c < 64) ? Wm1[(size_t)(k0 + kk) * 64 + c]
                                 : Wm1[(size_t)(64 + k0 + kk) * 64 + (c - 64)];
        }
        __syncthreads();
#pragma unroll
        for (int kk = 0; kk < 32; kk++) {
            float4 hv = *(const float4*)&sh[kk][tr * 4];
            float4 wv = *(const float4*)&sw[kk][tc * 4];
            float hh[4] = { hv.x, hv.y, hv.z, hv.w };
            float wwv[4] = { wv.x, wv.y, wv.z, wv.w };
#pragma unroll
            for (int i = 0; i < 4; i++)
#pragma unroll
                for (int j = 0; j < 4; j++) acc[i][j] += hh[i] * wwv[j];
        }
        __syncthreads();
    }
#pragma unroll
    for (int i = 0; i < 4; i++) {
        int gn = n0 + tr * 4 + i;
        if (gn >= N) continue;
#pragma unroll
        for (int j = 0; j < 4; j++) {
            int c = tc * 4 + j;
            if (c < 64) uh[(size_t)gn * 64 + c] = __float2half(acc[i][j]);
            else        vh[(size_t)gn * 64 + (c - 64)] = __float2half(acc[i][j]);
        }
    }
}

// ---------- edge MLP head v3: inline weA = ea@Wm1[128:136]+bm1; z1 = gelu(u[r]+v[c]+weA); layer2+3 fused ----------
__global__ __launch_bounds__(256) void k_mlp2(const __half* __restrict__ uh, const __half* __restrict__ vh,
                                              const float* __restrict__ ea, const int* __restrict__ ei,
                                              const float* __restrict__ Wm1, const float* __restrict__ bm1,
                                              const float* __restrict__ Wm2, const float* __restrict__ bm2,
                                              const float* __restrict__ Wm3, const float* __restrict__ bm3,
                                              float* __restrict__ out, int E) {
    __shared__ float sw2[64 * 32];
    __shared__ float sW1e[8 * 64];
    __shared__ float sb1[64];
    __shared__ int sre[64], sce[64];
    __shared__ float z1[64 * 68];
    int t = threadIdx.x;
    for (int i = t; i < 64 * 32; i += 256) sw2[i] = Wm2[i];
    for (int i = t; i < 512; i += 256) sW1e[i] = Wm1[128 * 64 + i];
    if (t < 64) sb1[t] = bm1[t];
    int e0 = blockIdx.x * 64;
    if (t < 64) {
        int e = e0 + t;
        if (e < E) { sre[t] = ei[e]; sce[t] = ei[E + e]; }
        else { sre[t] = 0; sce[t] = 0; }
    }
    __syncthreads();
    // stage z1 = gelu(u[r] + v[c] + (ea[e]@W1e + b1)) : 64 edges x 8 q-chunks of 8 cols
    for (int i = t; i < 512; i += 256) {
        int el = i >> 3, q = i & 7;
        int r = sre[el], c = sce[el];
        uint4 ru = *(const uint4*)(uh + (size_t)r * 64 + q * 8);
        uint4 rv = *(const uint4*)(vh + (size_t)c * 64 + q * 8);
        float4 a0 = *(const float4*)(ea + (size_t)(e0 + el) * 8);
        float4 a1 = *(const float4*)(ea + (size_t)(e0 + el) * 8 + 4);
        float av[8] = { a0.x, a0.y, a0.z, a0.w, a1.x, a1.y, a1.z, a1.w };
        float wv[8];
#pragma unroll
        for (int j = 0; j < 8; j++) wv[j] = sb1[q * 8 + j];
#pragma unroll
        for (int k = 0; k < 8; k++) {
            float a = av[k];
#pragma unroll
            for (int j = 0; j < 8; j++) wv[j] += a * sW1e[k * 64 + q * 8 + j];
        }
        float4 uhi, vhi;
        float4 ulo = half8_lo_hi(ru, &uhi);
        float4 vlo = half8_lo_hi(rv, &vhi);
        float4 zlo, zhi;
        zlo.x = gelu_f(ulo.x + vlo.x + wv[0]);
        zlo.y = gelu_f(ulo.y + vlo.y + wv[1]);
        zlo.z = gelu_f(ulo.z + vlo.z + wv[2]);
        zlo.w = gelu_f(ulo.w + vlo.w + wv[3]);
        zhi.x = gelu_f(uhi.x + vhi.x + wv[4]);
        zhi.y = gelu_f(uhi.y + vhi.y + wv[5]);
        zhi.z = gelu_f(uhi.z + vhi.z + wv[6]);
        zhi.w = gelu_f(uhi.w + vhi.w + wv[7]);
        *(float4*)(z1 + el * 68 + q * 8)     = zlo;
        *(float4*)(z1 + el * 68 + q * 8 + 4) = zhi;
    }
    __syncthreads();
    // layer 2: per thread 2 edges x 4 cols; layer 3 via 8-lane shuffle reduce
    int tr = t >> 3;
    int tc = t & 7;
    float b2[4], w3[4];
#pragma unroll
    for (int j = 0; j < 4; j++) { b2[j] = bm2[tc * 4 + j]; w3[j] = Wm3[tc * 4 + j]; }
    float b3 = bm3[0];
    float acc0[4], acc1[4];
#pragma unroll
    for (int j = 0; j < 4; j++) { acc0[j] = 0.f; acc1[j] = 0.f; }
    const float* z0p = z1 + (tr * 2 + 0) * 68;
    const float* z1p = z1 + (tr * 2 + 1) * 68;
#pragma unroll 8
    for (int k = 0; k < 64; k++) {
        float4 wv = *(const float4*)(sw2 + k * 32 + tc * 4);
        float a0 = z0p[k];
        float a1 = z1p[k];
        acc0[0] += a0 * wv.x; acc0[1] += a0 * wv.y; acc0[2] += a0 * wv.z; acc0[3] += a0 * wv.w;
        acc1[0] += a1 * wv.x; acc1[1] += a1 * wv.y; acc1[2] += a1 * wv.z; acc1[3] += a1 * wv.w;
    }
    float p0 = 0.f, p1 = 0.f;
#pragma unroll
    for (int j = 0; j < 4; j++) {
        p0 += gelu_f(acc0[j] + b2[j]) * w3[j];
        p1 += gelu_f(acc1[j] + b2[j]) * w3[j];
    }
    p0 += __shfl_xor(p0, 1, 64); p0 += __shfl_xor(p0, 2, 64); p0 += __shfl_xor(p0, 4, 64);
    p1 += __shfl_xor(p1, 1, 64); p1 += __shfl_xor(p1, 2, 64); p1 += __shfl_xor(p1, 4, 64);
    if (tc == 0) {
        int e = e0 + tr * 2;
        if (e < E)     out[e]     = 1.f / (1.f + expf(-(p0 + b3)));
        if (e + 1 < E) out[e + 1] = 1.f / (1.f + expf(-(p1 + b3)));
    }
}

extern "C" void kernel_launch(void* const* d_in, const int* in_sizes, int n_in,
                              void* d_out, int out_size, void* d_ws, size_t ws_size,
                              hipStream_t stream) {
    const float* x    = (const float*)d_in[0];
    const int*   ei   = (const int*)d_in[1];
    const float* ea   = (const float*)d_in[2];
    const float* Wl1  = (const float*)d_in[3];
    const float* bl1  = (const float*)d_in[4];
    const float* Wr1  = (const float*)d_in[5];
    const float* br1  = (const float*)d_in[6];
    const float* We1  = (const float*)d_in[7];
    const float* att1 = (const float*)d_in[8];
    const float* bias1= (const float*)d_in[9];
    const float* Wl2  = (const float*)d_in[10];
    const float* bl2  = (const float*)d_in[11];
    const float* Wr2  = (const float*)d_in[12];
    const float* br2  = (const float*)d_in[13];
    const float* We2  = (const float*)d_in[14];
    const float* att2 = (const float*)d_in[15];
    const float* bias2= (const float*)d_in[16];
    const float* bn1g = (const float*)d_in[17];
    const float* bn1b = (const float*)d_in[18];
    const float* bn1m = (const float*)d_in[19];
    const float* bn1v = (const float*)d_in[20];
    const float* bn2g = (const float*)d_in[21];
    const float* bn2b = (const float*)d_in[22];
    const float* bn2m = (const float*)d_in[23];
    const float* bn2v = (const float*)d_in[24];
    const float* Wres = (const float*)d_in[25];
    const float* Wm1  = (const float*)d_in[26];
    const float* bm1  = (const float*)d_in[27];
    const float* Wm2  = (const float*)d_in[28];
    const float* bm2  = (const float*)d_in[29];
    const float* Wm3  = (const float*)d_in[30];
    const float* bm3  = (const float*)d_in[31];
    float* out = (float*)d_out;
    float* ws = (float*)d_ws;

    const int N = NN, E = EE, Etot = ETOT;

    // workspace layout (floats)
    float* ea_sum   = ws;                                     // 16
    int*   counts   = (int*)(ws + 16);                        // N
    int*   off      = (int*)(ws + 16 + (size_t)N);            // N+16
    int*   cursor   = (int*)(ws + 32 + (size_t)2 * N);        // N
    int*   csr_src  = (int*)(ws + 32 + (size_t)3 * N);        // Etot
    int*   csr_eid  = (int*)(ws + 32 + (size_t)3 * N + Etot); // Etot
    size_t base     = 32 + (size_t)3 * N + (size_t)2 * Etot;
    __half* xl1h    = (__half*)(ws + base);                   // 256N halfs = 128N floats
    __half* xl2h    = xl1h;                                   // reuses (xl1h dead after k_fagg1)
    __half* h2h     = (__half*)(ws + base + (size_t)128 * N); // 64N halfs = 32N floats
    float* xr1      = ws + base + (size_t)160 * N;            // 256N floats
    float* h1       = xr1;                                    // in-place (row read before write)
    float* xr2      = xr1 + (size_t)256 * N;                  // 64N floats
    __half* uh      = (__half*)xr2;                           // 64N halfs
    __half* vh      = uh + (size_t)64 * N;                    // 64N halfs (xr2 dead after k_fagg2)

    hipMemsetAsync(ea_sum, 0, 16 * sizeof(float), stream);
    hipMemsetAsync(counts, 0, (size_t)N * sizeof(int), stream);

    int S = (Etot + 255) / 256;
    k_init<<<256 + S, 256, 0, stream>>>(ea, ea_sum, ei, counts, E, N);
    k_scan<<<1, 1024, 0, stream>>>(counts, off, cursor, N);
    k_scat_nt1<<<S + (N + 31) / 32, 256, 0, stream>>>(ei, cursor, csr_src, csr_eid,
                                                      x, Wl1, bl1, Wr1, br1, xl1h, xr1, E, N);
    k_fagg1<<<(N + 3) / 4, 256, 0, stream>>>(xl1h, xr1, off, csr_src, csr_eid, ea, ea_sum,
                                             We1, att1, bias1, x, Wres,
                                             bn1g, bn1b, bn1m, bn1v, h1, E, N);
    k_xlr2<<<(N + 31) / 32, 256, 0, stream>>>(h1, Wl2, bl2, Wr2, br2, xl2h, xr2, N);
    k_fagg2<<<(N + 3) / 4, 256, 0, stream>>>(xl2h, xr2, off, csr_src, csr_eid, ea, ea_sum,
                                             We2, att2, bias2,
                                             bn2g, bn2b, bn2m, bn2v, h2h, E, N);
    k_uv<<<(N + 31) / 32, 256, 0, stream>>>(h2h, Wm1, uh, vh, N);
    k_mlp2<<<(E + 63) / 64, 256, 0, stream>>>(uh, vh, ea, ei, Wm1, bm1, Wm2, bm2, Wm3, bm3, out, E);
}

// Round 11
// 482.246 us; speedup vs baseline: 1.2346x; 1.0495x over previous
//
#include <hip/hip_runtime.h>
#include <hip/hip_bf16.h>
#include <hip/hip_fp16.h>
#include <math.h>

#define NN 50000
#define EE 400000
#define ETOT (NN + EE)

// ---------- helpers ----------
__device__ __forceinline__ float gelu_f(float x) {
    return 0.5f * x * (1.f + erff(x * 0.7071067811865476f));
}
__device__ __forceinline__ float elu_f(float x) {
    return x > 0.f ? x : expm1f(x);
}
__device__ __forceinline__ float4 half8_lo_hi(uint4 raw, float4* hi) {
    __half2 h0 = *(__half2*)&raw.x, h1 = *(__half2*)&raw.y;
    __half2 h2 = *(__half2*)&raw.z, h3 = *(__half2*)&raw.w;
    float2 f0 = __half22float2(h0), f1 = __half22float2(h1);
    float2 f2 = __half22float2(h2), f3 = __half22float2(h3);
    *hi = make_float4(f2.x, f2.y, f3.x, f3.y);
    return make_float4(f0.x, f0.y, f1.x, f1.y);
}

// ---------- combined: ea mean (sum) [blocks 0..255] + degree count [blocks 256..] ----------
__global__ __launch_bounds__(256) void k_init(const float* __restrict__ ea, float* __restrict__ ea_sum,
                                              const int* __restrict__ ei, int* __restrict__ counts,
                                              int E, int N) {
    int t = threadIdx.x;
    if (blockIdx.x < 256) {
        float s[8];
#pragma unroll
        for (int i = 0; i < 8; i++) s[i] = 0.f;
        for (int e = blockIdx.x * 256 + t; e < E; e += 256 * 256) {
            const float4* p = (const float4*)(ea + (size_t)e * 8);
            float4 a = p[0], b = p[1];
            s[0] += a.x; s[1] += a.y; s[2] += a.z; s[3] += a.w;
            s[4] += b.x; s[5] += b.y; s[6] += b.z; s[7] += b.w;
        }
#pragma unroll
        for (int o = 32; o; o >>= 1)
#pragma unroll
            for (int i = 0; i < 8; i++) s[i] += __shfl_xor(s[i], o, 64);
        __shared__ float sh[4][8];
        int lane = t & 63, w = t >> 6;
        if (lane == 0)
#pragma unroll
            for (int i = 0; i < 8; i++) sh[w][i] = s[i];
        __syncthreads();
        if (t < 8) {
            float v = sh[0][t] + sh[1][t] + sh[2][t] + sh[3][t];
            atomicAdd(ea_sum + t, v);
        }
    } else {
        int e = (blockIdx.x - 256) * 256 + t;
        if (e >= E + N) return;
        int d = (e < E) ? ei[E + e] : (e - E);
        atomicAdd(counts + d, 1);
    }
}

// ---------- scan (4 elems/thread) ----------
__global__ __launch_bounds__(1024) void k_scan(const int* __restrict__ counts, int* __restrict__ off,
                                               int* __restrict__ cursor, int N) {
    __shared__ int buf[1024];
    int t = threadIdx.x;
    int carry = 0;
    if (t == 0) off[0] = 0;
    for (int base = 0; base < N; base += 4096) {
        int i0 = base + t * 4;
        int v0 = 0, v1 = 0, v2 = 0, v3 = 0;
        if (i0 + 3 < N) {
            int4 vv = *(const int4*)(counts + i0);
            v0 = vv.x; v1 = vv.y; v2 = vv.z; v3 = vv.w;
        } else {
            if (i0 < N)     v0 = counts[i0];
            if (i0 + 1 < N) v1 = counts[i0 + 1];
            if (i0 + 2 < N) v2 = counts[i0 + 2];
            if (i0 + 3 < N) v3 = counts[i0 + 3];
        }
        int s01 = v0 + v1, s012 = s01 + v2, tot4 = s012 + v3;
        buf[t] = tot4;
        __syncthreads();
        for (int o = 1; o < 1024; o <<= 1) {
            int add = (t >= o) ? buf[t - o] : 0;
            __syncthreads();
            buf[t] += add;
            __syncthreads();
        }
        int incl4 = buf[t] + carry;
        int excl = incl4 - tot4;
        if (i0 < N)     { off[i0 + 1] = excl + v0;   cursor[i0]     = excl; }
        if (i0 + 1 < N) { off[i0 + 2] = excl + s01;  cursor[i0 + 1] = excl + v0; }
        if (i0 + 2 < N) { off[i0 + 3] = excl + s012; cursor[i0 + 2] = excl + s01; }
        if (i0 + 3 < N) { off[i0 + 4] = excl + tot4; cursor[i0 + 3] = excl + s012; }
        int tot = buf[1023];
        __syncthreads();
        carry += tot;
    }
}

// ---------- combined: scatter [blocks 0..S) + ntrans1 [blocks S..) ----------
__global__ __launch_bounds__(256) void k_scat_nt1(const int* __restrict__ ei, int* __restrict__ cursor,
                                                  int* __restrict__ csr_src, int* __restrict__ csr_eid,
                                                  const float* __restrict__ x,
                                                  const float* __restrict__ Wl, const float* __restrict__ bl,
                                                  const float* __restrict__ Wr, const float* __restrict__ br,
                                                  __half* __restrict__ xl1h, float* __restrict__ xr1,
                                                  int E, int N) {
    __shared__ float swl[16 * 256];
    __shared__ float swr[16 * 256];
    __shared__ float sx[32 * 16];
    int t = threadIdx.x;
    int S = (E + N + 255) >> 8;
    if ((int)blockIdx.x < S) {
        int e = blockIdx.x * 256 + t;
        if (e >= E + N) return;
        int s, d;
        if (e < E) { s = ei[e]; d = ei[E + e]; }
        else { s = d = e - E; }
        int pos = atomicAdd(cursor + d, 1);
        csr_src[pos] = s;
        csr_eid[pos] = e;
        return;
    }
    int bid = blockIdx.x - S;
#pragma unroll
    for (int k = 0; k < 16; k++) { swl[k * 256 + t] = Wl[k * 256 + t]; swr[k * 256 + t] = Wr[k * 256 + t]; }
    int n0 = bid * 32;
    for (int i = t; i < 32 * 16; i += 256) {
        int n = n0 + (i >> 4);
        sx[i] = (n < N) ? x[(size_t)n * 16 + (i & 15)] : 0.f;
    }
    __syncthreads();
    float bL = bl[t], bR = br[t];
    for (int ni = 0; ni < 32; ni++) {
        int n = n0 + ni;
        if (n >= N) break;
        float al = bL, ar = bR;
#pragma unroll
        for (int k = 0; k < 16; k++) {
            float xv = sx[ni * 16 + k];
            al += xv * swl[k * 256 + t];
            ar += xv * swr[k * 256 + t];
        }
        xl1h[(size_t)n * 256 + t] = __float2half(al);
        xr1[(size_t)n * 256 + t] = ar;
    }
}

// ---------- fused conv1: zero-LDS, chunked index/ea broadcast, depth-3 row prefetch (round-8 verified) ----------
__global__ __launch_bounds__(256) void k_fagg1(const __half* __restrict__ xl1h, const float* __restrict__ xr1,
                                               const int* __restrict__ off, const int* __restrict__ csr_src,
                                               const int* __restrict__ csr_eid,
                                               const float* __restrict__ ea, const float* __restrict__ ea_sum,
                                               const float* __restrict__ We1, const float* __restrict__ att1,
                                               const float* __restrict__ bias1,
                                               const float* __restrict__ x, const float* __restrict__ Wres,
                                               const float* __restrict__ g, const float* __restrict__ bb_,
                                               const float* __restrict__ mm_, const float* __restrict__ vv_,
                                               float* __restrict__ h1,
                                               int E, int N) {
    int t = threadIdx.x;
    int lane = t & 63, w = t >> 6;
    int node = blockIdx.x * 4 + w;
    if (node >= N) return;
    int c4 = lane * 4;
    float4 we[8];
#pragma unroll
    for (int k = 0; k < 8; k++) we[k] = *(const float4*)(We1 + k * 256 + c4);
    float4 xr4 = *(const float4*)(xr1 + (size_t)node * 256 + c4);
    float4 at4 = *(const float4*)(att1 + c4);
    float invE = 1.f / (float)E;
    float4 eam0, eam1;
    eam0.x = ea_sum[0] * invE; eam0.y = ea_sum[1] * invE;
    eam0.z = ea_sum[2] * invE; eam0.w = ea_sum[3] * invE;
    eam1.x = ea_sum[4] * invE; eam1.y = ea_sum[5] * invE;
    eam1.z = ea_sum[6] * invE; eam1.w = ea_sum[7] * invE;

    int beg = off[node], end = off[node + 1];
    float m = -1e30f, sumw = 0.f;
    float4 acc = make_float4(0.f, 0.f, 0.f, 0.f);

    int cb = beg;
    while (cb < end) {
        int cnt = end - cb; if (cnt > 64) cnt = 64;
        int sl = 0;
        float4 ba = eam0, bb4 = eam1;
        if (lane < cnt) {
            sl = csr_src[cb + lane];
            int el = csr_eid[cb + lane];
            if (el < E) {
                ba  = *(const float4*)(ea + (size_t)el * 8);
                bb4 = *(const float4*)(ea + (size_t)el * 8 + 4);
            }
        }
        float2 r0 = make_float2(0.f, 0.f), r1 = r0, r2 = r0;
        {
            int s0 = __shfl(sl, 0, 64);
            r0 = *(const float2*)(xl1h + (size_t)s0 * 256 + c4);
            if (cnt > 1) { int s1 = __shfl(sl, 1, 64); r1 = *(const float2*)(xl1h + (size_t)s1 * 256 + c4); }
            if (cnt > 2) { int s2 = __shfl(sl, 2, 64); r2 = *(const float2*)(xl1h + (size_t)s2 * 256 + c4); }
        }
        for (int j = 0; j < cnt; j++) {
            float2 cur = r0;
            r0 = r1; r1 = r2;
            if (j + 3 < cnt) {
                int s3 = __shfl(sl, j + 3, 64);
                r2 = *(const float2*)(xl1h + (size_t)s3 * 256 + c4);
            }
            float eav[8];
            eav[0] = __shfl(ba.x, j, 64);  eav[1] = __shfl(ba.y, j, 64);
            eav[2] = __shfl(ba.z, j, 64);  eav[3] = __shfl(ba.w, j, 64);
            eav[4] = __shfl(bb4.x, j, 64); eav[5] = __shfl(bb4.y, j, 64);
            eav[6] = __shfl(bb4.z, j, 64); eav[7] = __shfl(bb4.w, j, 64);
            const __half2* hp = (const __half2*)&cur;
            float2 lo = __half22float2(hp[0]);
            float2 hi = __half22float2(hp[1]);
            float4 xs = make_float4(lo.x, lo.y, hi.x, hi.y);
            float4 ee = make_float4(0.f, 0.f, 0.f, 0.f);
#pragma unroll
            for (int k = 0; k < 8; k++) {
                ee.x += eav[k] * we[k].x; ee.y += eav[k] * we[k].y;
                ee.z += eav[k] * we[k].z; ee.w += eav[k] * we[k].w;
            }
            float4 v;
            v.x = xs.x + xr4.x + ee.x; v.y = xs.y + xr4.y + ee.y;
            v.z = xs.z + xr4.z + ee.z; v.w = xs.w + xr4.w + ee.w;
            v.x = v.x > 0.f ? v.x : 0.2f * v.x;
            v.y = v.y > 0.f ? v.y : 0.2f * v.y;
            v.z = v.z > 0.f ? v.z : 0.2f * v.z;
            v.w = v.w > 0.f ? v.w : 0.2f * v.w;
            float p = v.x * at4.x + v.y * at4.y + v.z * at4.z + v.w * at4.w;
            p += __shfl_xor(p, 1, 64);
            p += __shfl_xor(p, 2, 64);
            p += __shfl_xor(p, 4, 64);
            p += __shfl_xor(p, 8, 64);
            float mn = fmaxf(m, p);
            float sc = expf(m - mn);
            float wgt = expf(p - mn);
            acc.x = acc.x * sc + wgt * xs.x;
            acc.y = acc.y * sc + wgt * xs.y;
            acc.z = acc.z * sc + wgt * xs.z;
            acc.w = acc.w * sc + wgt * xs.w;
            sumw = sumw * sc + wgt;
            m = mn;
        }
        cb += cnt;
    }
    float inv = 1.f / (sumw + 1e-16f);
    float4 r = make_float4(0.f, 0.f, 0.f, 0.f);
#pragma unroll
    for (int q = 0; q < 4; q++) {
        float4 xq = *(const float4*)(x + (size_t)node * 16 + q * 4);
        float xa[4] = { xq.x, xq.y, xq.z, xq.w };
#pragma unroll
        for (int kk = 0; kk < 4; kk++) {
            float4 wv = *(const float4*)(Wres + (size_t)(q * 4 + kk) * 256 + c4);
            r.x += xa[kk] * wv.x; r.y += xa[kk] * wv.y;
            r.z += xa[kk] * wv.z; r.w += xa[kk] * wv.w;
        }
    }
    float4 bi = *(const float4*)(bias1 + c4);
    float4 g4 = *(const float4*)(g + c4);
    float4 b4 = *(const float4*)(bb_ + c4);
    float4 m4 = *(const float4*)(mm_ + c4);
    float4 v4 = *(const float4*)(vv_ + c4);
    float4 o;
    o.x = acc.x * inv + bi.x; o.y = acc.y * inv + bi.y;
    o.z = acc.z * inv + bi.z; o.w = acc.w * inv + bi.w;
    o.x = (o.x - m4.x) * rsqrtf(v4.x + 1e-5f) * g4.x + b4.x + r.x;
    o.y = (o.y - m4.y) * rsqrtf(v4.y + 1e-5f) * g4.y + b4.y + r.y;
    o.z = (o.z - m4.z) * rsqrtf(v4.z + 1e-5f) * g4.z + b4.z + r.z;
    o.w = (o.w - m4.w) * rsqrtf(v4.w + 1e-5f) * g4.w + b4.w + r.w;
    o.x = elu_f(o.x); o.y = elu_f(o.y); o.z = elu_f(o.z); o.w = elu_f(o.w);
    *(float4*)(h1 + (size_t)node * 256 + c4) = o;
}

// ---------- xl2(fp16) = h1@Wl2+bl2, xr2(fp32) = h1@Wr2+br2 ----------
__global__ __launch_bounds__(256) void k_xlr2(const float* __restrict__ h1,
                                              const float* __restrict__ Wl2, const float* __restrict__ bl2,
                                              const float* __restrict__ Wr2, const float* __restrict__ br2,
                                              __half* __restrict__ xl2h, float* __restrict__ xr2, int N) {
    __shared__ float sh[32][32];    // [kk][node]
    __shared__ float sw[32][128];   // [kk][col]
    int t = threadIdx.x;
    int tr = t >> 5, tc = t & 31;
    int n0 = blockIdx.x * 32;
    float acc[4][4];
#pragma unroll
    for (int i = 0; i < 4; i++)
#pragma unroll
        for (int j = 0; j < 4; j++) acc[i][j] = 0.f;
    for (int k0 = 0; k0 < 256; k0 += 32) {
        {
            int n = t >> 3, kk0 = (t & 7) * 4;
            int gn = n0 + n;
            float4 hv = make_float4(0.f, 0.f, 0.f, 0.f);
            if (gn < N) hv = *(const float4*)(h1 + (size_t)gn * 256 + k0 + kk0);
            sh[kk0 + 0][n] = hv.x; sh[kk0 + 1][n] = hv.y; sh[kk0 + 2][n] = hv.z; sh[kk0 + 3][n] = hv.w;
        }
        for (int i = t; i < 32 * 128; i += 256) {
            int kk = i >> 7, c = i & 127;
            sw[kk][c] = (c < 64) ? Wl2[(size_t)(k0 + kk) * 64 + c] : Wr2[(size_t)(k0 + kk) * 64 + (c - 64)];
        }
        __syncthreads();
#pragma unroll
        for (int kk = 0; kk < 32; kk++) {
            float4 hv = *(const float4*)&sh[kk][tr * 4];
            float4 wv = *(const float4*)&sw[kk][tc * 4];
            float hh[4] = { hv.x, hv.y, hv.z, hv.w };
            float wwv[4] = { wv.x, wv.y, wv.z, wv.w };
#pragma unroll
            for (int i = 0; i < 4; i++)
#pragma unroll
                for (int j = 0; j < 4; j++) acc[i][j] += hh[i] * wwv[j];
        }
        __syncthreads();
    }
#pragma unroll
    for (int i = 0; i < 4; i++) {
        int gn = n0 + tr * 4 + i;
        if (gn >= N) continue;
#pragma unroll
        for (int j = 0; j < 4; j++) {
            int c = tc * 4 + j;
            float vv = acc[i][j];
            if (c < 64) xl2h[(size_t)gn * 64 + c] = __float2half(vv + bl2[c]);
            else        xr2[(size_t)gn * 64 + (c - 64)] = vv + br2[c - 64];
        }
    }
}

// ---------- fused conv2 v2: 4 edges per wave (16-lane segments, 4 ch/lane), merged online softmax ----------
__global__ __launch_bounds__(256) void k_fagg2(const __half* __restrict__ xl2h, const float* __restrict__ xr2,
                                               const int* __restrict__ off, const int* __restrict__ csr_src,
                                               const int* __restrict__ csr_eid,
                                               const float* __restrict__ ea, const float* __restrict__ ea_sum,
                                               const float* __restrict__ We2, const float* __restrict__ att2,
                                               const float* __restrict__ bias2,
                                               const float* __restrict__ g, const float* __restrict__ bb_,
                                               const float* __restrict__ mm_, const float* __restrict__ vv_,
                                               __half* __restrict__ h2h,
                                               int E, int N) {
    int t = threadIdx.x;
    int lane = t & 63, w = t >> 6;
    int node = blockIdx.x * 4 + w;
    if (node >= N) return;
    int seg = lane >> 4;          // edge slot 0..3
    int c4 = (lane & 15) * 4;     // 4 channels owned
    float4 we[8];
#pragma unroll
    for (int k = 0; k < 8; k++) we[k] = *(const float4*)(We2 + k * 64 + c4);
    float4 xr4 = *(const float4*)(xr2 + (size_t)node * 64 + c4);
    float4 at4 = *(const float4*)(att2 + c4);
    float invE = 1.f / (float)E;
    float4 eam0, eam1;
    eam0.x = ea_sum[0] * invE; eam0.y = ea_sum[1] * invE;
    eam0.z = ea_sum[2] * invE; eam0.w = ea_sum[3] * invE;
    eam1.x = ea_sum[4] * invE; eam1.y = ea_sum[5] * invE;
    eam1.z = ea_sum[6] * invE; eam1.w = ea_sum[7] * invE;

    int beg = off[node], end = off[node + 1];
    float m = -1e30f, sumw = 0.f;
    float4 acc = make_float4(0.f, 0.f, 0.f, 0.f);

    int cb = beg;
    while (cb < end) {
        int cnt = end - cb; if (cnt > 64) cnt = 64;
        int sl = 0;
        float4 ba = eam0, bb4 = eam1;
        if (lane < cnt) {
            sl = csr_src[cb + lane];
            int el = csr_eid[cb + lane];
            if (el < E) {
                ba  = *(const float4*)(ea + (size_t)el * 8);
                bb4 = *(const float4*)(ea + (size_t)el * 8 + 4);
            }
        }
        int nit = (cnt + 3) >> 2;
        // depth-2 rotating row prefetch (per segment)
        float2 r0, r1;
        {
            int s0 = __shfl(sl, seg, 64);
            r0 = *(const float2*)(xl2h + (size_t)s0 * 64 + c4);
            int s1 = __shfl(sl, (seg + 4) & 63, 64);
            r1 = *(const float2*)(xl2h + (size_t)s1 * 64 + c4);
        }
        for (int it = 0; it < nit; ++it) {
            int jj = it * 4 + seg;            // this segment's edge position (uniform in segment)
            float2 cur = r0;
            r0 = r1;
            {
                int sn = __shfl(sl, (jj + 8) & 63, 64);
                r1 = *(const float2*)(xl2h + (size_t)sn * 64 + c4);
            }
            float eav[8];
            eav[0] = __shfl(ba.x, jj, 64);  eav[1] = __shfl(ba.y, jj, 64);
            eav[2] = __shfl(ba.z, jj, 64);  eav[3] = __shfl(ba.w, jj, 64);
            eav[4] = __shfl(bb4.x, jj, 64); eav[5] = __shfl(bb4.y, jj, 64);
            eav[6] = __shfl(bb4.z, jj, 64); eav[7] = __shfl(bb4.w, jj, 64);
            const __half2* hp = (const __half2*)&cur;
            float2 lo = __half22float2(hp[0]);
            float2 hi = __half22float2(hp[1]);
            float4 xs = make_float4(lo.x, lo.y, hi.x, hi.y);
            float4 ee = make_float4(0.f, 0.f, 0.f, 0.f);
#pragma unroll
            for (int k = 0; k < 8; k++) {
                ee.x += eav[k] * we[k].x; ee.y += eav[k] * we[k].y;
                ee.z += eav[k] * we[k].z; ee.w += eav[k] * we[k].w;
            }
            float4 v;
            v.x = xs.x + xr4.x + ee.x; v.y = xs.y + xr4.y + ee.y;
            v.z = xs.z + xr4.z + ee.z; v.w = xs.w + xr4.w + ee.w;
            v.x = v.x > 0.f ? v.x : 0.2f * v.x;
            v.y = v.y > 0.f ? v.y : 0.2f * v.y;
            v.z = v.z > 0.f ? v.z : 0.2f * v.z;
            v.w = v.w > 0.f ? v.w : 0.2f * v.w;
            float p = v.x * at4.x + v.y * at4.y + v.z * at4.z + v.w * at4.w;
            p += __shfl_xor(p, 1, 64);
            p += __shfl_xor(p, 2, 64);
            p += __shfl_xor(p, 4, 64);
            p += __shfl_xor(p, 8, 64);        // 16-lane segment reduce
            bool valid = jj < cnt;
            float pe = valid ? p : -1e30f;
            float mn = fmaxf(m, pe);
            float sc = expf(m - mn);
            float wgt = valid ? expf(pe - mn) : 0.f;
            acc.x = acc.x * sc + wgt * xs.x;
            acc.y = acc.y * sc + wgt * xs.y;
            acc.z = acc.z * sc + wgt * xs.z;
            acc.w = acc.w * sc + wgt * xs.w;
            sumw = sumw * sc + wgt;
            m = mn;
        }
        cb += cnt;
    }
    // merge the 4 segment states (same channels per lane across segments)
#pragma unroll
    for (int d = 16; d <= 32; d <<= 1) {
        float m2 = __shfl_xor(m, d, 64);
        float s2 = __shfl_xor(sumw, d, 64);
        float ax = __shfl_xor(acc.x, d, 64);
        float ay = __shfl_xor(acc.y, d, 64);
        float az = __shfl_xor(acc.z, d, 64);
        float aw = __shfl_xor(acc.w, d, 64);
        float mn = fmaxf(m, m2);
        float e1 = expf(m - mn), e2 = expf(m2 - mn);
        acc.x = acc.x * e1 + ax * e2;
        acc.y = acc.y * e1 + ay * e2;
        acc.z = acc.z * e1 + az * e2;
        acc.w = acc.w * e1 + aw * e2;
        sumw = sumw * e1 + s2 * e2;
        m = mn;
    }
    float inv = 1.f / (sumw + 1e-16f);
    float4 bi = *(const float4*)(bias2 + c4);
    float4 g4 = *(const float4*)(g + c4);
    float4 b4 = *(const float4*)(bb_ + c4);
    float4 m4 = *(const float4*)(mm_ + c4);
    float4 v4 = *(const float4*)(vv_ + c4);
    float4 o;
    o.x = acc.x * inv + bi.x; o.y = acc.y * inv + bi.y;
    o.z = acc.z * inv + bi.z; o.w = acc.w * inv + bi.w;
    o.x = (o.x - m4.x) * rsqrtf(v4.x + 1e-5f) * g4.x + b4.x;
    o.y = (o.y - m4.y) * rsqrtf(v4.y + 1e-5f) * g4.y + b4.y;
    o.z = (o.z - m4.z) * rsqrtf(v4.z + 1e-5f) * g4.z + b4.z;
    o.w = (o.w - m4.w) * rsqrtf(v4.w + 1e-5f) * g4.w + b4.w;
    if (seg == 0) {
        __half2 h0 = __floats2half2_rn(elu_f(o.x), elu_f(o.y));
        __half2 h1 = __floats2half2_rn(elu_f(o.z), elu_f(o.w));
        uint2 pk;
        pk.x = *(unsigned*)&h0;
        pk.y = *(unsigned*)&h1;
        *(uint2*)(h2h + (size_t)node * 64 + c4) = pk;
    }
}

// ---------- u = h2@Wm1[0:64], v = h2@Wm1[64:128]  (fp16 out, no bias) ----------
__global__ __launch_bounds__(256) void k_uv(const __half* __restrict__ h2h, const float* __restrict__ Wm1,
                                            __half* __restrict__ uh, __half* __restrict__ vh, int N) {
    __shared__ float sh[32][32];    // [kk][node]
    __shared__ float sw[32][128];   // [kk][col]  (u cols 0..63, v cols 64..127)
    int t = threadIdx.x;
    int tr = t >> 5, tc = t & 31;
    int n0 = blockIdx.x * 32;
    float acc[4][4];
#pragma unroll
    for (int i = 0; i < 4; i++)
#pragma unroll
        for (int j = 0; j < 4; j++) acc[i][j] = 0.f;
    for (int k0 = 0; k0 < 64; k0 += 32) {
        {
            int n = t >> 3, kk0 = (t & 7) * 4;
            int gn = n0 + n;
            float4 hv = make_float4(0.f, 0.f, 0.f, 0.f);
            if (gn < N) {
                uint2 raw = *(const uint2*)(h2h + (size_t)gn * 64 + k0 + kk0);
                __half2 a = *(__half2*)&raw.x, b = *(__half2*)&raw.y;
                float2 fa = __half22float2(a), fb = __half22float2(b);
                hv = make_float4(fa.x, fa.y, fb.x, fb.y);
            }
            sh[kk0 + 0][n] = hv.x; sh[kk0 + 1][n] = hv.y; sh[kk0 + 2][n] = hv.z; sh[kk0 + 3][n] = hv.w;
        }
        for (int i = t; i < 32 * 128; i += 256) {
            int kk = i >> 7, c = i & 127;
            sw[kk][c] = (c < 64) ? Wm1[(size_t)(k0 + kk) * 64 + c]
                                 : Wm1[(size_t)(64 + k0 + kk) * 64 + (c - 64)];
        }
        __syncthreads();
#pragma unroll
        for (int kk = 0; kk < 32; kk++) {
            float4 hv = *(const float4*)&sh[kk][tr * 4];
            float4 wv = *(const float4*)&sw[kk][tc * 4];
            float hh[4] = { hv.x, hv.y, hv.z, hv.w };
            float wwv[4] = { wv.x, wv.y, wv.z, wv.w };
#pragma unroll
            for (int i = 0; i < 4; i++)
#pragma unroll
                for (int j = 0; j < 4; j++) acc[i][j] += hh[i] * wwv[j];
        }
        __syncthreads();
    }
#pragma unroll
    for (int i = 0; i < 4; i++) {
        int gn = n0 + tr * 4 + i;
        if (gn >= N) continue;
#pragma unroll
        for (int j = 0; j < 4; j++) {
            int c = tc * 4 + j;
            if (c < 64) uh[(size_t)gn * 64 + c] = __float2half(acc[i][j]);
            else        vh[(size_t)gn * 64 + (c - 64)] = __float2half(acc[i][j]);
        }
    }
}

// ---------- edge MLP head v3: inline weA = ea@Wm1[128:136]+bm1; z1 = gelu(u[r]+v[c]+weA); layer2+3 fused ----------
__global__ __launch_bounds__(256) void k_mlp2(const __half* __restrict__ uh, const __half* __restrict__ vh,
                                              const float* __restrict__ ea, const int* __restrict__ ei,
                                              const float* __restrict__ Wm1, const float* __restrict__ bm1,
                                              const float* __restrict__ Wm2, const float* __restrict__ bm2,
                                              const float* __restrict__ Wm3, const float* __restrict__ bm3,
                                              float* __restrict__ out, int E) {
    __shared__ float sw2[64 * 32];
    __shared__ float sW1e[8 * 64];
    __shared__ float sb1[64];
    __shared__ int sre[64], sce[64];
    __shared__ float z1[64 * 68];
    int t = threadIdx.x;
    for (int i = t; i < 64 * 32; i += 256) sw2[i] = Wm2[i];
    for (int i = t; i < 512; i += 256) sW1e[i] = Wm1[128 * 64 + i];
    if (t < 64) sb1[t] = bm1[t];
    int e0 = blockIdx.x * 64;
    if (t < 64) {
        int e = e0 + t;
        if (e < E) { sre[t] = ei[e]; sce[t] = ei[E + e]; }
        else { sre[t] = 0; sce[t] = 0; }
    }
    __syncthreads();
    // stage z1 = gelu(u[r] + v[c] + (ea[e]@W1e + b1)) : 64 edges x 8 q-chunks of 8 cols
    for (int i = t; i < 512; i += 256) {
        int el = i >> 3, q = i & 7;
        int r = sre[el], c = sce[el];
        uint4 ru = *(const uint4*)(uh + (size_t)r * 64 + q * 8);
        uint4 rv = *(const uint4*)(vh + (size_t)c * 64 + q * 8);
        float4 a0 = *(const float4*)(ea + (size_t)(e0 + el) * 8);
        float4 a1 = *(const float4*)(ea + (size_t)(e0 + el) * 8 + 4);
        float av[8] = { a0.x, a0.y, a0.z, a0.w, a1.x, a1.y, a1.z, a1.w };
        float wv[8];
#pragma unroll
        for (int j = 0; j < 8; j++) wv[j] = sb1[q * 8 + j];
#pragma unroll
        for (int k = 0; k < 8; k++) {
            float a = av[k];
#pragma unroll
            for (int j = 0; j < 8; j++) wv[j] += a * sW1e[k * 64 + q * 8 + j];
        }
        float4 uhi, vhi;
        float4 ulo = half8_lo_hi(ru, &uhi);
        float4 vlo = half8_lo_hi(rv, &vhi);
        float4 zlo, zhi;
        zlo.x = gelu_f(ulo.x + vlo.x + wv[0]);
        zlo.y = gelu_f(ulo.y + vlo.y + wv[1]);
        zlo.z = gelu_f(ulo.z + vlo.z + wv[2]);
        zlo.w = gelu_f(ulo.w + vlo.w + wv[3]);
        zhi.x = gelu_f(uhi.x + vhi.x + wv[4]);
        zhi.y = gelu_f(uhi.y + vhi.y + wv[5]);
        zhi.z = gelu_f(uhi.z + vhi.z + wv[6]);
        zhi.w = gelu_f(uhi.w + vhi.w + wv[7]);
        *(float4*)(z1 + el * 68 + q * 8)     = zlo;
        *(float4*)(z1 + el * 68 + q * 8 + 4) = zhi;
    }
    __syncthreads();
    // layer 2: per thread 2 edges x 4 cols; layer 3 via 8-lane shuffle reduce
    int tr = t >> 3;
    int tc = t & 7;
    float b2[4], w3[4];
#pragma unroll
    for (int j = 0; j < 4; j++) { b2[j] = bm2[tc * 4 + j]; w3[j] = Wm3[tc * 4 + j]; }
    float b3 = bm3[0];
    float acc0[4], acc1[4];
#pragma unroll
    for (int j = 0; j < 4; j++) { acc0[j] = 0.f; acc1[j] = 0.f; }
    const float* z0p = z1 + (tr * 2 + 0) * 68;
    const float* z1p = z1 + (tr * 2 + 1) * 68;
#pragma unroll 8
    for (int k = 0; k < 64; k++) {
        float4 wv = *(const float4*)(sw2 + k * 32 + tc * 4);
        float a0 = z0p[k];
        float a1 = z1p[k];
        acc0[0] += a0 * wv.x; acc0[1] += a0 * wv.y; acc0[2] += a0 * wv.z; acc0[3] += a0 * wv.w;
        acc1[0] += a1 * wv.x; acc1[1] += a1 * wv.y; acc1[2] += a1 * wv.z; acc1[3] += a1 * wv.w;
    }
    float p0 = 0.f, p1 = 0.f;
#pragma unroll
    for (int j = 0; j < 4; j++) {
        p0 += gelu_f(acc0[j] + b2[j]) * w3[j];
        p1 += gelu_f(acc1[j] + b2[j]) * w3[j];
    }
    p0 += __shfl_xor(p0, 1, 64); p0 += __shfl_xor(p0, 2, 64); p0 += __shfl_xor(p0, 4, 64);
    p1 += __shfl_xor(p1, 1, 64); p1 += __shfl_xor(p1, 2, 64); p1 += __shfl_xor(p1, 4, 64);
    if (tc == 0) {
        int e = e0 + tr * 2;
        if (e < E)     out[e]     = 1.f / (1.f + expf(-(p0 + b3)));
        if (e + 1 < E) out[e + 1] = 1.f / (1.f + expf(-(p1 + b3)));
    }
}

extern "C" void kernel_launch(void* const* d_in, const int* in_sizes, int n_in,
                              void* d_out, int out_size, void* d_ws, size_t ws_size,
                              hipStream_t stream) {
    const float* x    = (const float*)d_in[0];
    const int*   ei   = (const int*)d_in[1];
    const float* ea   = (const float*)d_in[2];
    const float* Wl1  = (const float*)d_in[3];
    const float* bl1  = (const float*)d_in[4];
    const float* Wr1  = (const float*)d_in[5];
    const float* br1  = (const float*)d_in[6];
    const float* We1  = (const float*)d_in[7];
    const float* att1 = (const float*)d_in[8];
    const float* bias1= (const float*)d_in[9];
    const float* Wl2  = (const float*)d_in[10];
    const float* bl2  = (const float*)d_in[11];
    const float* Wr2  = (const float*)d_in[12];
    const float* br2  = (const float*)d_in[13];
    const float* We2  = (const float*)d_in[14];
    const float* att2 = (const float*)d_in[15];
    const float* bias2= (const float*)d_in[16];
    const float* bn1g = (const float*)d_in[17];
    const float* bn1b = (const float*)d_in[18];
    const float* bn1m = (const float*)d_in[19];
    const float* bn1v = (const float*)d_in[20];
    const float* bn2g = (const float*)d_in[21];
    const float* bn2b = (const float*)d_in[22];
    const float* bn2m = (const float*)d_in[23];
    const float* bn2v = (const float*)d_in[24];
    const float* Wres = (const float*)d_in[25];
    const float* Wm1  = (const float*)d_in[26];
    const float* bm1  = (const float*)d_in[27];
    const float* Wm2  = (const float*)d_in[28];
    const float* bm2  = (const float*)d_in[29];
    const float* Wm3  = (const float*)d_in[30];
    const float* bm3  = (const float*)d_in[31];
    float* out = (float*)d_out;
    float* ws = (float*)d_ws;

    const int N = NN, E = EE, Etot = ETOT;

    // workspace layout (floats)
    float* ea_sum   = ws;                                     // 16
    int*   counts   = (int*)(ws + 16);                        // N
    int*   off      = (int*)(ws + 16 + (size_t)N);            // N+16
    int*   cursor   = (int*)(ws + 32 + (size_t)2 * N);        // N
    int*   csr_src  = (int*)(ws + 32 + (size_t)3 * N);        // Etot
    int*   csr_eid  = (int*)(ws + 32 + (size_t)3 * N + Etot); // Etot
    size_t base     = 32 + (size_t)3 * N + (size_t)2 * Etot;
    __half* xl1h    = (__half*)(ws + base);                   // 256N halfs = 128N floats
    __half* xl2h    = xl1h;                                   // reuses (xl1h dead after k_fagg1)
    __half* h2h     = (__half*)(ws + base + (size_t)128 * N); // 64N halfs = 32N floats
    float* xr1      = ws + base + (size_t)160 * N;            // 256N floats
    float* h1       = xr1;                                    // in-place (row read before write)
    float* xr2      = xr1 + (size_t)256 * N;                  // 64N floats
    __half* uh      = (__half*)xr2;                           // 64N halfs
    __half* vh      = uh + (size_t)64 * N;                    // 64N halfs (xr2 dead after k_fagg2)

    hipMemsetAsync(ea_sum, 0, 16 * sizeof(float), stream);
    hipMemsetAsync(counts, 0, (size_t)N * sizeof(int), stream);

    int S = (Etot + 255) / 256;
    k_init<<<256 + S, 256, 0, stream>>>(ea, ea_sum, ei, counts, E, N);
    k_scan<<<1, 1024, 0, stream>>>(counts, off, cursor, N);
    k_scat_nt1<<<S + (N + 31) / 32, 256, 0, stream>>>(ei, cursor, csr_src, csr_eid,
                                                      x, Wl1, bl1, Wr1, br1, xl1h, xr1, E, N);
    k_fagg1<<<(N + 3) / 4, 256, 0, stream>>>(xl1h, xr1, off, csr_src, csr_eid, ea, ea_sum,
                                             We1, att1, bias1, x, Wres,
                                             bn1g, bn1b, bn1m, bn1v, h1, E, N);
    k_xlr2<<<(N + 31) / 32, 256, 0, stream>>>(h1, Wl2, bl2, Wr2, br2, xl2h, xr2, N);
    k_fagg2<<<(N + 3) / 4, 256, 0, stream>>>(xl2h, xr2, off, csr_src, csr_eid, ea, ea_sum,
                                             We2, att2, bias2,
                                             bn2g, bn2b, bn2m, bn2v, h2h, E, N);
    k_uv<<<(N + 31) / 32, 256, 0, stream>>>(h2h, Wm1, uh, vh, N);
    k_mlp2<<<(E + 63) / 64, 256, 0, stream>>>(uh, vh, ea, ei, Wm1, bm1, Wm2, bm2, Wm3, bm3, out, E);
}

// Round 12
// 467.874 us; speedup vs baseline: 1.2725x; 1.0307x over previous
//
#include <hip/hip_runtime.h>
#include <hip/hip_bf16.h>
#include <hip/hip_fp16.h>
#include <math.h>

#define NN 50000
#define EE 400000
#define ETOT (NN + EE)

// ---------- helpers ----------
__device__ __forceinline__ float gelu_f(float x) {
    return 0.5f * x * (1.f + erff(x * 0.7071067811865476f));
}
__device__ __forceinline__ float elu_f(float x) {
    return x > 0.f ? x : expm1f(x);
}
__device__ __forceinline__ float4 half8_lo_hi(uint4 raw, float4* hi) {
    __half2 h0 = *(__half2*)&raw.x, h1 = *(__half2*)&raw.y;
    __half2 h2 = *(__half2*)&raw.z, h3 = *(__half2*)&raw.w;
    float2 f0 = __half22float2(h0), f1 = __half22float2(h1);
    float2 f2 = __half22float2(h2), f3 = __half22float2(h3);
    *hi = make_float4(f2.x, f2.y, f3.x, f3.y);
    return make_float4(f0.x, f0.y, f1.x, f1.y);
}

// ---------- combined: ea mean (sum) [blocks 0..255] + degree count [blocks 256..] ----------
__global__ __launch_bounds__(256) void k_init(const float* __restrict__ ea, float* __restrict__ ea_sum,
                                              const int* __restrict__ ei, int* __restrict__ counts,
                                              int E, int N) {
    int t = threadIdx.x;
    if (blockIdx.x < 256) {
        float s[8];
#pragma unroll
        for (int i = 0; i < 8; i++) s[i] = 0.f;
        for (int e = blockIdx.x * 256 + t; e < E; e += 256 * 256) {
            const float4* p = (const float4*)(ea + (size_t)e * 8);
            float4 a = p[0], b = p[1];
            s[0] += a.x; s[1] += a.y; s[2] += a.z; s[3] += a.w;
            s[4] += b.x; s[5] += b.y; s[6] += b.z; s[7] += b.w;
        }
#pragma unroll
        for (int o = 32; o; o >>= 1)
#pragma unroll
            for (int i = 0; i < 8; i++) s[i] += __shfl_xor(s[i], o, 64);
        __shared__ float sh[4][8];
        int lane = t & 63, w = t >> 6;
        if (lane == 0)
#pragma unroll
            for (int i = 0; i < 8; i++) sh[w][i] = s[i];
        __syncthreads();
        if (t < 8) {
            float v = sh[0][t] + sh[1][t] + sh[2][t] + sh[3][t];
            atomicAdd(ea_sum + t, v);
        }
    } else {
        int e = (blockIdx.x - 256) * 256 + t;
        if (e >= E + N) return;
        int d = (e < E) ? ei[E + e] : (e - E);
        atomicAdd(counts + d, 1);
    }
}

// ---------- scan (4 elems/thread) ----------
__global__ __launch_bounds__(1024) void k_scan(const int* __restrict__ counts, int* __restrict__ off,
                                               int* __restrict__ cursor, int N) {
    __shared__ int buf[1024];
    int t = threadIdx.x;
    int carry = 0;
    if (t == 0) off[0] = 0;
    for (int base = 0; base < N; base += 4096) {
        int i0 = base + t * 4;
        int v0 = 0, v1 = 0, v2 = 0, v3 = 0;
        if (i0 + 3 < N) {
            int4 vv = *(const int4*)(counts + i0);
            v0 = vv.x; v1 = vv.y; v2 = vv.z; v3 = vv.w;
        } else {
            if (i0 < N)     v0 = counts[i0];
            if (i0 + 1 < N) v1 = counts[i0 + 1];
            if (i0 + 2 < N) v2 = counts[i0 + 2];
            if (i0 + 3 < N) v3 = counts[i0 + 3];
        }
        int s01 = v0 + v1, s012 = s01 + v2, tot4 = s012 + v3;
        buf[t] = tot4;
        __syncthreads();
        for (int o = 1; o < 1024; o <<= 1) {
            int add = (t >= o) ? buf[t - o] : 0;
            __syncthreads();
            buf[t] += add;
            __syncthreads();
        }
        int incl4 = buf[t] + carry;
        int excl = incl4 - tot4;
        if (i0 < N)     { off[i0 + 1] = excl + v0;   cursor[i0]     = excl; }
        if (i0 + 1 < N) { off[i0 + 2] = excl + s01;  cursor[i0 + 1] = excl + v0; }
        if (i0 + 2 < N) { off[i0 + 3] = excl + s012; cursor[i0 + 2] = excl + s01; }
        if (i0 + 3 < N) { off[i0 + 4] = excl + tot4; cursor[i0 + 3] = excl + s012; }
        int tot = buf[1023];
        __syncthreads();
        carry += tot;
    }
}

// ---------- combined: scatter [blocks 0..S) + ntrans1 [blocks S..) ----------
__global__ __launch_bounds__(256) void k_scat_nt1(const int* __restrict__ ei, int* __restrict__ cursor,
                                                  int* __restrict__ csr_src, int* __restrict__ csr_eid,
                                                  const float* __restrict__ x,
                                                  const float* __restrict__ Wl, const float* __restrict__ bl,
                                                  const float* __restrict__ Wr, const float* __restrict__ br,
                                                  __half* __restrict__ xl1h, float* __restrict__ xr1,
                                                  int E, int N) {
    __shared__ float swl[16 * 256];
    __shared__ float swr[16 * 256];
    __shared__ float sx[32 * 16];
    int t = threadIdx.x;
    int S = (E + N + 255) >> 8;
    if ((int)blockIdx.x < S) {
        int e = blockIdx.x * 256 + t;
        if (e >= E + N) return;
        int s, d;
        if (e < E) { s = ei[e]; d = ei[E + e]; }
        else { s = d = e - E; }
        int pos = atomicAdd(cursor + d, 1);
        csr_src[pos] = s;
        csr_eid[pos] = e;
        return;
    }
    int bid = blockIdx.x - S;
#pragma unroll
    for (int k = 0; k < 16; k++) { swl[k * 256 + t] = Wl[k * 256 + t]; swr[k * 256 + t] = Wr[k * 256 + t]; }
    int n0 = bid * 32;
    for (int i = t; i < 32 * 16; i += 256) {
        int n = n0 + (i >> 4);
        sx[i] = (n < N) ? x[(size_t)n * 16 + (i & 15)] : 0.f;
    }
    __syncthreads();
    float bL = bl[t], bR = br[t];
    for (int ni = 0; ni < 32; ni++) {
        int n = n0 + ni;
        if (n >= N) break;
        float al = bL, ar = bR;
#pragma unroll
        for (int k = 0; k < 16; k++) {
            float xv = sx[ni * 16 + k];
            al += xv * swl[k * 256 + t];
            ar += xv * swr[k * 256 + t];
        }
        xl1h[(size_t)n * 256 + t] = __float2half(al);
        xr1[(size_t)n * 256 + t] = ar;
    }
}

// ---------- fused conv1: zero-LDS, chunked broadcast, depth-3 prefetch, no-shift softmax ----------
__global__ __launch_bounds__(256) void k_fagg1(const __half* __restrict__ xl1h, const float* __restrict__ xr1,
                                               const int* __restrict__ off, const int* __restrict__ csr_src,
                                               const int* __restrict__ csr_eid,
                                               const float* __restrict__ ea, const float* __restrict__ ea_sum,
                                               const float* __restrict__ We1, const float* __restrict__ att1,
                                               const float* __restrict__ bias1,
                                               const float* __restrict__ x, const float* __restrict__ Wres,
                                               const float* __restrict__ g, const float* __restrict__ bb_,
                                               const float* __restrict__ mm_, const float* __restrict__ vv_,
                                               float* __restrict__ h1,
                                               int E, int N) {
    int t = threadIdx.x;
    int lane = t & 63, w = t >> 6;
    int node = blockIdx.x * 4 + w;
    if (node >= N) return;
    int c4 = lane * 4;
    float4 we[8];
#pragma unroll
    for (int k = 0; k < 8; k++) we[k] = *(const float4*)(We1 + k * 256 + c4);
    float4 xr4 = *(const float4*)(xr1 + (size_t)node * 256 + c4);
    float4 at4 = *(const float4*)(att1 + c4);
    float invE = 1.f / (float)E;
    float4 eam0, eam1;
    eam0.x = ea_sum[0] * invE; eam0.y = ea_sum[1] * invE;
    eam0.z = ea_sum[2] * invE; eam0.w = ea_sum[3] * invE;
    eam1.x = ea_sum[4] * invE; eam1.y = ea_sum[5] * invE;
    eam1.z = ea_sum[6] * invE; eam1.w = ea_sum[7] * invE;

    int beg = off[node], end = off[node + 1];
    float sumw = 0.f;
    float4 acc = make_float4(0.f, 0.f, 0.f, 0.f);

    int cb = beg;
    while (cb < end) {
        int cnt = end - cb; if (cnt > 64) cnt = 64;
        int sl = 0;
        float4 ba = eam0, bb4 = eam1;
        if (lane < cnt) {
            sl = csr_src[cb + lane];
            int el = csr_eid[cb + lane];
            if (el < E) {
                ba  = *(const float4*)(ea + (size_t)el * 8);
                bb4 = *(const float4*)(ea + (size_t)el * 8 + 4);
            }
        }
        float2 r0 = make_float2(0.f, 0.f), r1 = r0, r2 = r0;
        {
            int s0 = __shfl(sl, 0, 64);
            r0 = *(const float2*)(xl1h + (size_t)s0 * 256 + c4);
            if (cnt > 1) { int s1 = __shfl(sl, 1, 64); r1 = *(const float2*)(xl1h + (size_t)s1 * 256 + c4); }
            if (cnt > 2) { int s2 = __shfl(sl, 2, 64); r2 = *(const float2*)(xl1h + (size_t)s2 * 256 + c4); }
        }
        for (int j = 0; j < cnt; j++) {
            float2 cur = r0;
            r0 = r1; r1 = r2;
            if (j + 3 < cnt) {
                int s3 = __shfl(sl, j + 3, 64);
                r2 = *(const float2*)(xl1h + (size_t)s3 * 256 + c4);
            }
            float eav[8];
            eav[0] = __shfl(ba.x, j, 64);  eav[1] = __shfl(ba.y, j, 64);
            eav[2] = __shfl(ba.z, j, 64);  eav[3] = __shfl(ba.w, j, 64);
            eav[4] = __shfl(bb4.x, j, 64); eav[5] = __shfl(bb4.y, j, 64);
            eav[6] = __shfl(bb4.z, j, 64); eav[7] = __shfl(bb4.w, j, 64);
            const __half2* hp = (const __half2*)&cur;
            float2 lo = __half22float2(hp[0]);
            float2 hi = __half22float2(hp[1]);
            float4 xs = make_float4(lo.x, lo.y, hi.x, hi.y);
            float4 ee = make_float4(0.f, 0.f, 0.f, 0.f);
#pragma unroll
            for (int k = 0; k < 8; k++) {
                ee.x += eav[k] * we[k].x; ee.y += eav[k] * we[k].y;
                ee.z += eav[k] * we[k].z; ee.w += eav[k] * we[k].w;
            }
            float4 v;
            v.x = xs.x + xr4.x + ee.x; v.y = xs.y + xr4.y + ee.y;
            v.z = xs.z + xr4.z + ee.z; v.w = xs.w + xr4.w + ee.w;
            v.x = v.x > 0.f ? v.x : 0.2f * v.x;
            v.y = v.y > 0.f ? v.y : 0.2f * v.y;
            v.z = v.z > 0.f ? v.z : 0.2f * v.z;
            v.w = v.w > 0.f ? v.w : 0.2f * v.w;
            float p = v.x * at4.x + v.y * at4.y + v.z * at4.z + v.w * at4.w;
            p += __shfl_xor(p, 1, 64);
            p += __shfl_xor(p, 2, 64);
            p += __shfl_xor(p, 4, 64);
            p += __shfl_xor(p, 8, 64);
            // no-shift softmax accumulate (logits are O(1); exact algebra)
            float wgt = expf(p);
            acc.x += wgt * xs.x;
            acc.y += wgt * xs.y;
            acc.z += wgt * xs.z;
            acc.w += wgt * xs.w;
            sumw += wgt;
        }
        cb += cnt;
    }
    float inv = 1.f / (sumw + 1e-16f);
    float4 r = make_float4(0.f, 0.f, 0.f, 0.f);
#pragma unroll
    for (int q = 0; q < 4; q++) {
        float4 xq = *(const float4*)(x + (size_t)node * 16 + q * 4);
        float xa[4] = { xq.x, xq.y, xq.z, xq.w };
#pragma unroll
        for (int kk = 0; kk < 4; kk++) {
            float4 wv = *(const float4*)(Wres + (size_t)(q * 4 + kk) * 256 + c4);
            r.x += xa[kk] * wv.x; r.y += xa[kk] * wv.y;
            r.z += xa[kk] * wv.z; r.w += xa[kk] * wv.w;
        }
    }
    float4 bi = *(const float4*)(bias1 + c4);
    float4 g4 = *(const float4*)(g + c4);
    float4 b4 = *(const float4*)(bb_ + c4);
    float4 m4 = *(const float4*)(mm_ + c4);
    float4 v4 = *(const float4*)(vv_ + c4);
    float4 o;
    o.x = acc.x * inv + bi.x; o.y = acc.y * inv + bi.y;
    o.z = acc.z * inv + bi.z; o.w = acc.w * inv + bi.w;
    o.x = (o.x - m4.x) * rsqrtf(v4.x + 1e-5f) * g4.x + b4.x + r.x;
    o.y = (o.y - m4.y) * rsqrtf(v4.y + 1e-5f) * g4.y + b4.y + r.y;
    o.z = (o.z - m4.z) * rsqrtf(v4.z + 1e-5f) * g4.z + b4.z + r.z;
    o.w = (o.w - m4.w) * rsqrtf(v4.w + 1e-5f) * g4.w + b4.w + r.w;
    o.x = elu_f(o.x); o.y = elu_f(o.y); o.z = elu_f(o.z); o.w = elu_f(o.w);
    *(float4*)(h1 + (size_t)node * 256 + c4) = o;
}

// ---------- xl2(fp16) = h1@Wl2+bl2, xr2(fp32) = h1@Wr2+br2 ----------
__global__ __launch_bounds__(256) void k_xlr2(const float* __restrict__ h1,
                                              const float* __restrict__ Wl2, const float* __restrict__ bl2,
                                              const float* __restrict__ Wr2, const float* __restrict__ br2,
                                              __half* __restrict__ xl2h, float* __restrict__ xr2, int N) {
    __shared__ float sh[32][32];    // [kk][node]
    __shared__ float sw[32][128];   // [kk][col]
    int t = threadIdx.x;
    int tr = t >> 5, tc = t & 31;
    int n0 = blockIdx.x * 32;
    float acc[4][4];
#pragma unroll
    for (int i = 0; i < 4; i++)
#pragma unroll
        for (int j = 0; j < 4; j++) acc[i][j] = 0.f;
    for (int k0 = 0; k0 < 256; k0 += 32) {
        {
            int n = t >> 3, kk0 = (t & 7) * 4;
            int gn = n0 + n;
            float4 hv = make_float4(0.f, 0.f, 0.f, 0.f);
            if (gn < N) hv = *(const float4*)(h1 + (size_t)gn * 256 + k0 + kk0);
            sh[kk0 + 0][n] = hv.x; sh[kk0 + 1][n] = hv.y; sh[kk0 + 2][n] = hv.z; sh[kk0 + 3][n] = hv.w;
        }
        for (int i = t; i < 32 * 128; i += 256) {
            int kk = i >> 7, c = i & 127;
            sw[kk][c] = (c < 64) ? Wl2[(size_t)(k0 + kk) * 64 + c] : Wr2[(size_t)(k0 + kk) * 64 + (c - 64)];
        }
        __syncthreads();
#pragma unroll
        for (int kk = 0; kk < 32; kk++) {
            float4 hv = *(const float4*)&sh[kk][tr * 4];
            float4 wv = *(const float4*)&sw[kk][tc * 4];
            float hh[4] = { hv.x, hv.y, hv.z, hv.w };
            float wwv[4] = { wv.x, wv.y, wv.z, wv.w };
#pragma unroll
            for (int i = 0; i < 4; i++)
#pragma unroll
                for (int j = 0; j < 4; j++) acc[i][j] += hh[i] * wwv[j];
        }
        __syncthreads();
    }
#pragma unroll
    for (int i = 0; i < 4; i++) {
        int gn = n0 + tr * 4 + i;
        if (gn >= N) continue;
#pragma unroll
        for (int j = 0; j < 4; j++) {
            int c = tc * 4 + j;
            float vv = acc[i][j];
            if (c < 64) xl2h[(size_t)gn * 64 + c] = __float2half(vv + bl2[c]);
            else        xr2[(size_t)gn * 64 + (c - 64)] = vv + br2[c - 64];
        }
    }
}

// ---------- fused conv2 v3: 4 edges/wave, no-shift softmax, plain-sum merge ----------
__global__ __launch_bounds__(256) void k_fagg2(const __half* __restrict__ xl2h, const float* __restrict__ xr2,
                                               const int* __restrict__ off, const int* __restrict__ csr_src,
                                               const int* __restrict__ csr_eid,
                                               const float* __restrict__ ea, const float* __restrict__ ea_sum,
                                               const float* __restrict__ We2, const float* __restrict__ att2,
                                               const float* __restrict__ bias2,
                                               const float* __restrict__ g, const float* __restrict__ bb_,
                                               const float* __restrict__ mm_, const float* __restrict__ vv_,
                                               __half* __restrict__ h2h,
                                               int E, int N) {
    int t = threadIdx.x;
    int lane = t & 63, w = t >> 6;
    int node = blockIdx.x * 4 + w;
    if (node >= N) return;
    int seg = lane >> 4;          // edge slot 0..3
    int c4 = (lane & 15) * 4;     // 4 channels owned
    float4 we[8];
#pragma unroll
    for (int k = 0; k < 8; k++) we[k] = *(const float4*)(We2 + k * 64 + c4);
    float4 xr4 = *(const float4*)(xr2 + (size_t)node * 64 + c4);
    float4 at4 = *(const float4*)(att2 + c4);
    float invE = 1.f / (float)E;
    float4 eam0, eam1;
    eam0.x = ea_sum[0] * invE; eam0.y = ea_sum[1] * invE;
    eam0.z = ea_sum[2] * invE; eam0.w = ea_sum[3] * invE;
    eam1.x = ea_sum[4] * invE; eam1.y = ea_sum[5] * invE;
    eam1.z = ea_sum[6] * invE; eam1.w = ea_sum[7] * invE;

    int beg = off[node], end = off[node + 1];
    float sumw = 0.f;
    float4 acc = make_float4(0.f, 0.f, 0.f, 0.f);

    int cb = beg;
    while (cb < end) {
        int cnt = end - cb; if (cnt > 64) cnt = 64;
        int sl = 0;
        float4 ba = eam0, bb4 = eam1;
        if (lane < cnt) {
            sl = csr_src[cb + lane];
            int el = csr_eid[cb + lane];
            if (el < E) {
                ba  = *(const float4*)(ea + (size_t)el * 8);
                bb4 = *(const float4*)(ea + (size_t)el * 8 + 4);
            }
        }
        int nit = (cnt + 3) >> 2;
        float2 r0, r1;
        {
            int s0 = __shfl(sl, seg, 64);
            r0 = *(const float2*)(xl2h + (size_t)s0 * 64 + c4);
            int s1 = __shfl(sl, (seg + 4) & 63, 64);
            r1 = *(const float2*)(xl2h + (size_t)s1 * 64 + c4);
        }
        for (int it = 0; it < nit; ++it) {
            int jj = it * 4 + seg;
            float2 cur = r0;
            r0 = r1;
            {
                int sn = __shfl(sl, (jj + 8) & 63, 64);
                r1 = *(const float2*)(xl2h + (size_t)sn * 64 + c4);
            }
            float eav[8];
            eav[0] = __shfl(ba.x, jj, 64);  eav[1] = __shfl(ba.y, jj, 64);
            eav[2] = __shfl(ba.z, jj, 64);  eav[3] = __shfl(ba.w, jj, 64);
            eav[4] = __shfl(bb4.x, jj, 64); eav[5] = __shfl(bb4.y, jj, 64);
            eav[6] = __shfl(bb4.z, jj, 64); eav[7] = __shfl(bb4.w, jj, 64);
            const __half2* hp = (const __half2*)&cur;
            float2 lo = __half22float2(hp[0]);
            float2 hi = __half22float2(hp[1]);
            float4 xs = make_float4(lo.x, lo.y, hi.x, hi.y);
            float4 ee = make_float4(0.f, 0.f, 0.f, 0.f);
#pragma unroll
            for (int k = 0; k < 8; k++) {
                ee.x += eav[k] * we[k].x; ee.y += eav[k] * we[k].y;
                ee.z += eav[k] * we[k].z; ee.w += eav[k] * we[k].w;
            }
            float4 v;
            v.x = xs.x + xr4.x + ee.x; v.y = xs.y + xr4.y + ee.y;
            v.z = xs.z + xr4.z + ee.z; v.w = xs.w + xr4.w + ee.w;
            v.x = v.x > 0.f ? v.x : 0.2f * v.x;
            v.y = v.y > 0.f ? v.y : 0.2f * v.y;
            v.z = v.z > 0.f ? v.z : 0.2f * v.z;
            v.w = v.w > 0.f ? v.w : 0.2f * v.w;
            float p = v.x * at4.x + v.y * at4.y + v.z * at4.z + v.w * at4.w;
            p += __shfl_xor(p, 1, 64);
            p += __shfl_xor(p, 2, 64);
            p += __shfl_xor(p, 4, 64);
            p += __shfl_xor(p, 8, 64);        // 16-lane segment reduce
            bool valid = jj < cnt;
            float wgt = valid ? expf(p) : 0.f;
            acc.x += wgt * xs.x;
            acc.y += wgt * xs.y;
            acc.z += wgt * xs.z;
            acc.w += wgt * xs.w;
            sumw += wgt;
        }
        cb += cnt;
    }
    // merge the 4 segment states: plain sums (no-shift softmax)
#pragma unroll
    for (int d = 16; d <= 32; d <<= 1) {
        acc.x += __shfl_xor(acc.x, d, 64);
        acc.y += __shfl_xor(acc.y, d, 64);
        acc.z += __shfl_xor(acc.z, d, 64);
        acc.w += __shfl_xor(acc.w, d, 64);
        sumw  += __shfl_xor(sumw, d, 64);
    }
    float inv = 1.f / (sumw + 1e-16f);
    float4 bi = *(const float4*)(bias2 + c4);
    float4 g4 = *(const float4*)(g + c4);
    float4 b4 = *(const float4*)(bb_ + c4);
    float4 m4 = *(const float4*)(mm_ + c4);
    float4 v4 = *(const float4*)(vv_ + c4);
    float4 o;
    o.x = acc.x * inv + bi.x; o.y = acc.y * inv + bi.y;
    o.z = acc.z * inv + bi.z; o.w = acc.w * inv + bi.w;
    o.x = (o.x - m4.x) * rsqrtf(v4.x + 1e-5f) * g4.x + b4.x;
    o.y = (o.y - m4.y) * rsqrtf(v4.y + 1e-5f) * g4.y + b4.y;
    o.z = (o.z - m4.z) * rsqrtf(v4.z + 1e-5f) * g4.z + b4.z;
    o.w = (o.w - m4.w) * rsqrtf(v4.w + 1e-5f) * g4.w + b4.w;
    if (seg == 0) {
        __half2 h0 = __floats2half2_rn(elu_f(o.x), elu_f(o.y));
        __half2 h1 = __floats2half2_rn(elu_f(o.z), elu_f(o.w));
        uint2 pk;
        pk.x = *(unsigned*)&h0;
        pk.y = *(unsigned*)&h1;
        *(uint2*)(h2h + (size_t)node * 64 + c4) = pk;
    }
}

// ---------- u = h2@Wm1[0:64], v = h2@Wm1[64:128]  (fp16 out, no bias) ----------
__global__ __launch_bounds__(256) void k_uv(const __half* __restrict__ h2h, const float* __restrict__ Wm1,
                                            __half* __restrict__ uh, __half* __restrict__ vh, int N) {
    __shared__ float sh[32][32];    // [kk][node]
    __shared__ float sw[32][128];   // [kk][col]  (u cols 0..63, v cols 64..127)
    int t = threadIdx.x;
    int tr = t >> 5, tc = t & 31;
    int n0 = blockIdx.x * 32;
    float acc[4][4];
#pragma unroll
    for (int i = 0; i < 4; i++)
#pragma unroll
        for (int j = 0; j < 4; j++) acc[i][j] = 0.f;
    for (int k0 = 0; k0 < 64; k0 += 32) {
        {
            int n = t >> 3, kk0 = (t & 7) * 4;
            int gn = n0 + n;
            float4 hv = make_float4(0.f, 0.f, 0.f, 0.f);
            if (gn < N) {
                uint2 raw = *(const uint2*)(h2h + (size_t)gn * 64 + k0 + kk0);
                __half2 a = *(__half2*)&raw.x, b = *(__half2*)&raw.y;
                float2 fa = __half22float2(a), fb = __half22float2(b);
                hv = make_float4(fa.x, fa.y, fb.x, fb.y);
            }
            sh[kk0 + 0][n] = hv.x; sh[kk0 + 1][n] = hv.y; sh[kk0 + 2][n] = hv.z; sh[kk0 + 3][n] = hv.w;
        }
        for (int i = t; i < 32 * 128; i += 256) {
            int kk = i >> 7, c = i & 127;
            sw[kk][c] = (c < 64) ? Wm1[(size_t)(k0 + kk) * 64 + c]
                                 : Wm1[(size_t)(64 + k0 + kk) * 64 + (c - 64)];
        }
        __syncthreads();
#pragma unroll
        for (int kk = 0; kk < 32; kk++) {
            float4 hv = *(const float4*)&sh[kk][tr * 4];
            float4 wv = *(const float4*)&sw[kk][tc * 4];
            float hh[4] = { hv.x, hv.y, hv.z, hv.w };
            float wwv[4] = { wv.x, wv.y, wv.z, wv.w };
#pragma unroll
            for (int i = 0; i < 4; i++)
#pragma unroll
                for (int j = 0; j < 4; j++) acc[i][j] += hh[i] * wwv[j];
        }
        __syncthreads();
    }
#pragma unroll
    for (int i = 0; i < 4; i++) {
        int gn = n0 + tr * 4 + i;
        if (gn >= N) continue;
#pragma unroll
        for (int j = 0; j < 4; j++) {
            int c = tc * 4 + j;
            if (c < 64) uh[(size_t)gn * 64 + c] = __float2half(acc[i][j]);
            else        vh[(size_t)gn * 64 + (c - 64)] = __float2half(acc[i][j]);
        }
    }
}

// ---------- edge MLP head v3: inline weA = ea@Wm1[128:136]+bm1; z1 = gelu(u[r]+v[c]+weA); layer2+3 fused ----------
__global__ __launch_bounds__(256) void k_mlp2(const __half* __restrict__ uh, const __half* __restrict__ vh,
                                              const float* __restrict__ ea, const int* __restrict__ ei,
                                              const float* __restrict__ Wm1, const float* __restrict__ bm1,
                                              const float* __restrict__ Wm2, const float* __restrict__ bm2,
                                              const float* __restrict__ Wm3, const float* __restrict__ bm3,
                                              float* __restrict__ out, int E) {
    __shared__ float sw2[64 * 32];
    __shared__ float sW1e[8 * 64];
    __shared__ float sb1[64];
    __shared__ int sre[64], sce[64];
    __shared__ float z1[64 * 68];
    int t = threadIdx.x;
    for (int i = t; i < 64 * 32; i += 256) sw2[i] = Wm2[i];
    for (int i = t; i < 512; i += 256) sW1e[i] = Wm1[128 * 64 + i];
    if (t < 64) sb1[t] = bm1[t];
    int e0 = blockIdx.x * 64;
    if (t < 64) {
        int e = e0 + t;
        if (e < E) { sre[t] = ei[e]; sce[t] = ei[E + e]; }
        else { sre[t] = 0; sce[t] = 0; }
    }
    __syncthreads();
    for (int i = t; i < 512; i += 256) {
        int el = i >> 3, q = i & 7;
        int r = sre[el], c = sce[el];
        uint4 ru = *(const uint4*)(uh + (size_t)r * 64 + q * 8);
        uint4 rv = *(const uint4*)(vh + (size_t)c * 64 + q * 8);
        float4 a0 = *(const float4*)(ea + (size_t)(e0 + el) * 8);
        float4 a1 = *(const float4*)(ea + (size_t)(e0 + el) * 8 + 4);
        float av[8] = { a0.x, a0.y, a0.z, a0.w, a1.x, a1.y, a1.z, a1.w };
        float wv[8];
#pragma unroll
        for (int j = 0; j < 8; j++) wv[j] = sb1[q * 8 + j];
#pragma unroll
        for (int k = 0; k < 8; k++) {
            float a = av[k];
#pragma unroll
            for (int j = 0; j < 8; j++) wv[j] += a * sW1e[k * 64 + q * 8 + j];
        }
        float4 uhi, vhi;
        float4 ulo = half8_lo_hi(ru, &uhi);
        float4 vlo = half8_lo_hi(rv, &vhi);
        float4 zlo, zhi;
        zlo.x = gelu_f(ulo.x + vlo.x + wv[0]);
        zlo.y = gelu_f(ulo.y + vlo.y + wv[1]);
        zlo.z = gelu_f(ulo.z + vlo.z + wv[2]);
        zlo.w = gelu_f(ulo.w + vlo.w + wv[3]);
        zhi.x = gelu_f(uhi.x + vhi.x + wv[4]);
        zhi.y = gelu_f(uhi.y + vhi.y + wv[5]);
        zhi.z = gelu_f(uhi.z + vhi.z + wv[6]);
        zhi.w = gelu_f(uhi.w + vhi.w + wv[7]);
        *(float4*)(z1 + el * 68 + q * 8)     = zlo;
        *(float4*)(z1 + el * 68 + q * 8 + 4) = zhi;
    }
    __syncthreads();
    int tr = t >> 3;
    int tc = t & 7;
    float b2[4], w3[4];
#pragma unroll
    for (int j = 0; j < 4; j++) { b2[j] = bm2[tc * 4 + j]; w3[j] = Wm3[tc * 4 + j]; }
    float b3 = bm3[0];
    float acc0[4], acc1[4];
#pragma unroll
    for (int j = 0; j < 4; j++) { acc0[j] = 0.f; acc1[j] = 0.f; }
    const float* z0p = z1 + (tr * 2 + 0) * 68;
    const float* z1p = z1 + (tr * 2 + 1) * 68;
#pragma unroll 8
    for (int k = 0; k < 64; k++) {
        float4 wv = *(const float4*)(sw2 + k * 32 + tc * 4);
        float a0 = z0p[k];
        float a1 = z1p[k];
        acc0[0] += a0 * wv.x; acc0[1] += a0 * wv.y; acc0[2] += a0 * wv.z; acc0[3] += a0 * wv.w;
        acc1[0] += a1 * wv.x; acc1[1] += a1 * wv.y; acc1[2] += a1 * wv.z; acc1[3] += a1 * wv.w;
    }
    float p0 = 0.f, p1 = 0.f;
#pragma unroll
    for (int j = 0; j < 4; j++) {
        p0 += gelu_f(acc0[j] + b2[j]) * w3[j];
        p1 += gelu_f(acc1[j] + b2[j]) * w3[j];
    }
    p0 += __shfl_xor(p0, 1, 64); p0 += __shfl_xor(p0, 2, 64); p0 += __shfl_xor(p0, 4, 64);
    p1 += __shfl_xor(p1, 1, 64); p1 += __shfl_xor(p1, 2, 64); p1 += __shfl_xor(p1, 4, 64);
    if (tc == 0) {
        int e = e0 + tr * 2;
        if (e < E)     out[e]     = 1.f / (1.f + expf(-(p0 + b3)));
        if (e + 1 < E) out[e + 1] = 1.f / (1.f + expf(-(p1 + b3)));
    }
}

extern "C" void kernel_launch(void* const* d_in, const int* in_sizes, int n_in,
                              void* d_out, int out_size, void* d_ws, size_t ws_size,
                              hipStream_t stream) {
    const float* x    = (const float*)d_in[0];
    const int*   ei   = (const int*)d_in[1];
    const float* ea   = (const float*)d_in[2];
    const float* Wl1  = (const float*)d_in[3];
    const float* bl1  = (const float*)d_in[4];
    const float* Wr1  = (const float*)d_in[5];
    const float* br1  = (const float*)d_in[6];
    const float* We1  = (const float*)d_in[7];
    const float* att1 = (const float*)d_in[8];
    const float* bias1= (const float*)d_in[9];
    const float* Wl2  = (const float*)d_in[10];
    const float* bl2  = (const float*)d_in[11];
    const float* Wr2  = (const float*)d_in[12];
    const float* br2  = (const float*)d_in[13];
    const float* We2  = (const float*)d_in[14];
    const float* att2 = (const float*)d_in[15];
    const float* bias2= (const float*)d_in[16];
    const float* bn1g = (const float*)d_in[17];
    const float* bn1b = (const float*)d_in[18];
    const float* bn1m = (const float*)d_in[19];
    const float* bn1v = (const float*)d_in[20];
    const float* bn2g = (const float*)d_in[21];
    const float* bn2b = (const float*)d_in[22];
    const float* bn2m = (const float*)d_in[23];
    const float* bn2v = (const float*)d_in[24];
    const float* Wres = (const float*)d_in[25];
    const float* Wm1  = (const float*)d_in[26];
    const float* bm1  = (const float*)d_in[27];
    const float* Wm2  = (const float*)d_in[28];
    const float* bm2  = (const float*)d_in[29];
    const float* Wm3  = (const float*)d_in[30];
    const float* bm3  = (const float*)d_in[31];
    float* out = (float*)d_out;
    float* ws = (float*)d_ws;

    const int N = NN, E = EE, Etot = ETOT;

    // workspace layout (floats)
    float* ea_sum   = ws;                                     // 16
    int*   counts   = (int*)(ws + 16);                        // N
    int*   off      = (int*)(ws + 16 + (size_t)N);            // N+16
    int*   cursor   = (int*)(ws + 32 + (size_t)2 * N);        // N
    int*   csr_src  = (int*)(ws + 32 + (size_t)3 * N);        // Etot
    int*   csr_eid  = (int*)(ws + 32 + (size_t)3 * N + Etot); // Etot
    size_t base     = 32 + (size_t)3 * N + (size_t)2 * Etot;
    __half* xl1h    = (__half*)(ws + base);                   // 256N halfs = 128N floats
    __half* xl2h    = xl1h;                                   // reuses (xl1h dead after k_fagg1)
    __half* h2h     = (__half*)(ws + base + (size_t)128 * N); // 64N halfs = 32N floats
    float* xr1      = ws + base + (size_t)160 * N;            // 256N floats
    float* h1       = xr1;                                    // in-place (row read before write)
    float* xr2      = xr1 + (size_t)256 * N;                  // 64N floats
    __half* uh      = (__half*)xr2;                           // 64N halfs
    __half* vh      = uh + (size_t)64 * N;                    // 64N halfs (xr2 dead after k_fagg2)

    hipMemsetAsync(ea_sum, 0, 16 * sizeof(float), stream);
    hipMemsetAsync(counts, 0, (size_t)N * sizeof(int), stream);

    int S = (Etot + 255) / 256;
    k_init<<<256 + S, 256, 0, stream>>>(ea, ea_sum, ei, counts, E, N);
    k_scan<<<1, 1024, 0, stream>>>(counts, off, cursor, N);
    k_scat_nt1<<<S + (N + 31) / 32, 256, 0, stream>>>(ei, cursor, csr_src, csr_eid,
                                                      x, Wl1, bl1, Wr1, br1, xl1h, xr1, E, N);
    k_fagg1<<<(N + 3) / 4, 256, 0, stream>>>(xl1h, xr1, off, csr_src, csr_eid, ea, ea_sum,
                                             We1, att1, bias1, x, Wres,
                                             bn1g, bn1b, bn1m, bn1v, h1, E, N);
    k_xlr2<<<(N + 31) / 32, 256, 0, stream>>>(h1, Wl2, bl2, Wr2, br2, xl2h, xr2, N);
    k_fagg2<<<(N + 3) / 4, 256, 0, stream>>>(xl2h, xr2, off, csr_src, csr_eid, ea, ea_sum,
                                             We2, att2, bias2,
                                             bn2g, bn2b, bn2m, bn2v, h2h, E, N);
    k_uv<<<(N + 31) / 32, 256, 0, stream>>>(h2h, Wm1, uh, vh, N);
    k_mlp2<<<(E + 63) / 64, 256, 0, stream>>>(uh, vh, ea, ei, Wm1, bm1, Wm2, bm2, Wm3, bm3, out, E);
}

// Round 13
// 453.075 us; speedup vs baseline: 1.3141x; 1.0327x over previous
//
#include <hip/hip_runtime.h>
#include <hip/hip_bf16.h>
#include <hip/hip_fp16.h>
#include <math.h>

#define NN 50000
#define EE 400000
#define ETOT (NN + EE)

// ---------- helpers ----------
__device__ __forceinline__ float gelu_f(float x) {
    return 0.5f * x * (1.f + erff(x * 0.7071067811865476f));
}
__device__ __forceinline__ float elu_f(float x) {
    return x > 0.f ? x : expm1f(x);
}
__device__ __forceinline__ float4 half8_lo_hi(uint4 raw, float4* hi) {
    __half2 h0 = *(__half2*)&raw.x, h1 = *(__half2*)&raw.y;
    __half2 h2 = *(__half2*)&raw.z, h3 = *(__half2*)&raw.w;
    float2 f0 = __half22float2(h0), f1 = __half22float2(h1);
    float2 f2 = __half22float2(h2), f3 = __half22float2(h3);
    *hi = make_float4(f2.x, f2.y, f3.x, f3.y);
    return make_float4(f0.x, f0.y, f1.x, f1.y);
}
__device__ __forceinline__ float4 half4_to_f4(uint2 raw) {
    __half2 a = *(__half2*)&raw.x, b = *(__half2*)&raw.y;
    float2 fa = __half22float2(a), fb = __half22float2(b);
    return make_float4(fa.x, fa.y, fb.x, fb.y);
}
__device__ __forceinline__ uint2 f4_to_half4(float4 v) {
    __half2 h0 = __floats2half2_rn(v.x, v.y);
    __half2 h1 = __floats2half2_rn(v.z, v.w);
    uint2 pk;
    pk.x = *(unsigned*)&h0;
    pk.y = *(unsigned*)&h1;
    return pk;
}

// ---------- combined: ea mean (sum) [blocks 0..255] + degree count [blocks 256..] ----------
__global__ __launch_bounds__(256) void k_init(const float* __restrict__ ea, float* __restrict__ ea_sum,
                                              const int* __restrict__ ei, int* __restrict__ counts,
                                              int E, int N) {
    int t = threadIdx.x;
    if (blockIdx.x < 256) {
        float s[8];
#pragma unroll
        for (int i = 0; i < 8; i++) s[i] = 0.f;
        for (int e = blockIdx.x * 256 + t; e < E; e += 256 * 256) {
            const float4* p = (const float4*)(ea + (size_t)e * 8);
            float4 a = p[0], b = p[1];
            s[0] += a.x; s[1] += a.y; s[2] += a.z; s[3] += a.w;
            s[4] += b.x; s[5] += b.y; s[6] += b.z; s[7] += b.w;
        }
#pragma unroll
        for (int o = 32; o; o >>= 1)
#pragma unroll
            for (int i = 0; i < 8; i++) s[i] += __shfl_xor(s[i], o, 64);
        __shared__ float sh[4][8];
        int lane = t & 63, w = t >> 6;
        if (lane == 0)
#pragma unroll
            for (int i = 0; i < 8; i++) sh[w][i] = s[i];
        __syncthreads();
        if (t < 8) {
            float v = sh[0][t] + sh[1][t] + sh[2][t] + sh[3][t];
            atomicAdd(ea_sum + t, v);
        }
    } else {
        int e = (blockIdx.x - 256) * 256 + t;
        if (e >= E + N) return;
        int d = (e < E) ? ei[E + e] : (e - E);
        atomicAdd(counts + d, 1);
    }
}

// ---------- scan (4 elems/thread) ----------
__global__ __launch_bounds__(1024) void k_scan(const int* __restrict__ counts, int* __restrict__ off,
                                               int* __restrict__ cursor, int N) {
    __shared__ int buf[1024];
    int t = threadIdx.x;
    int carry = 0;
    if (t == 0) off[0] = 0;
    for (int base = 0; base < N; base += 4096) {
        int i0 = base + t * 4;
        int v0 = 0, v1 = 0, v2 = 0, v3 = 0;
        if (i0 + 3 < N) {
            int4 vv = *(const int4*)(counts + i0);
            v0 = vv.x; v1 = vv.y; v2 = vv.z; v3 = vv.w;
        } else {
            if (i0 < N)     v0 = counts[i0];
            if (i0 + 1 < N) v1 = counts[i0 + 1];
            if (i0 + 2 < N) v2 = counts[i0 + 2];
            if (i0 + 3 < N) v3 = counts[i0 + 3];
        }
        int s01 = v0 + v1, s012 = s01 + v2, tot4 = s012 + v3;
        buf[t] = tot4;
        __syncthreads();
        for (int o = 1; o < 1024; o <<= 1) {
            int add = (t >= o) ? buf[t - o] : 0;
            __syncthreads();
            buf[t] += add;
            __syncthreads();
        }
        int incl4 = buf[t] + carry;
        int excl = incl4 - tot4;
        if (i0 < N)     { off[i0 + 1] = excl + v0;   cursor[i0]     = excl; }
        if (i0 + 1 < N) { off[i0 + 2] = excl + s01;  cursor[i0 + 1] = excl + v0; }
        if (i0 + 2 < N) { off[i0 + 3] = excl + s012; cursor[i0 + 2] = excl + s01; }
        if (i0 + 3 < N) { off[i0 + 4] = excl + tot4; cursor[i0 + 3] = excl + s012; }
        int tot = buf[1023];
        __syncthreads();
        carry += tot;
    }
}

// ---------- combined: scatter [blocks 0..S) + ntrans1 [blocks S..) ----------
__global__ __launch_bounds__(256) void k_scat_nt1(const int* __restrict__ ei, int* __restrict__ cursor,
                                                  int* __restrict__ csr_src, int* __restrict__ csr_eid,
                                                  const float* __restrict__ x,
                                                  const float* __restrict__ Wl, const float* __restrict__ bl,
                                                  const float* __restrict__ Wr, const float* __restrict__ br,
                                                  __half* __restrict__ xl1h, __half* __restrict__ xr1h,
                                                  int E, int N) {
    __shared__ float swl[16 * 256];
    __shared__ float swr[16 * 256];
    __shared__ float sx[32 * 16];
    int t = threadIdx.x;
    int S = (E + N + 255) >> 8;
    if ((int)blockIdx.x < S) {
        int e = blockIdx.x * 256 + t;
        if (e >= E + N) return;
        int s, d;
        if (e < E) { s = ei[e]; d = ei[E + e]; }
        else { s = d = e - E; }
        int pos = atomicAdd(cursor + d, 1);
        csr_src[pos] = s;
        csr_eid[pos] = e;
        return;
    }
    int bid = blockIdx.x - S;
#pragma unroll
    for (int k = 0; k < 16; k++) { swl[k * 256 + t] = Wl[k * 256 + t]; swr[k * 256 + t] = Wr[k * 256 + t]; }
    int n0 = bid * 32;
    for (int i = t; i < 32 * 16; i += 256) {
        int n = n0 + (i >> 4);
        sx[i] = (n < N) ? x[(size_t)n * 16 + (i & 15)] : 0.f;
    }
    __syncthreads();
    float bL = bl[t], bR = br[t];
    for (int ni = 0; ni < 32; ni++) {
        int n = n0 + ni;
        if (n >= N) break;
        float al = bL, ar = bR;
#pragma unroll
        for (int k = 0; k < 16; k++) {
            float xv = sx[ni * 16 + k];
            al += xv * swl[k * 256 + t];
            ar += xv * swr[k * 256 + t];
        }
        xl1h[(size_t)n * 256 + t] = __float2half(al);
        xr1h[(size_t)n * 256 + t] = __float2half(ar);
    }
}

// ---------- fused conv1: zero-LDS, chunked broadcast, depth-3 prefetch, no-shift softmax, fp16 IO ----------
__global__ __launch_bounds__(256) void k_fagg1(const __half* __restrict__ xl1h, const __half* __restrict__ xr1h,
                                               const int* __restrict__ off, const int* __restrict__ csr_src,
                                               const int* __restrict__ csr_eid,
                                               const float* __restrict__ ea, const float* __restrict__ ea_sum,
                                               const float* __restrict__ We1, const float* __restrict__ att1,
                                               const float* __restrict__ bias1,
                                               const float* __restrict__ x, const float* __restrict__ Wres,
                                               const float* __restrict__ g, const float* __restrict__ bb_,
                                               const float* __restrict__ mm_, const float* __restrict__ vv_,
                                               __half* __restrict__ h1h,
                                               int E, int N) {
    int t = threadIdx.x;
    int lane = t & 63, w = t >> 6;
    int node = blockIdx.x * 4 + w;
    if (node >= N) return;
    int c4 = lane * 4;
    float4 we[8];
#pragma unroll
    for (int k = 0; k < 8; k++) we[k] = *(const float4*)(We1 + k * 256 + c4);
    float4 xr4 = half4_to_f4(*(const uint2*)(xr1h + (size_t)node * 256 + c4));
    float4 at4 = *(const float4*)(att1 + c4);
    float invE = 1.f / (float)E;
    float4 eam0, eam1;
    eam0.x = ea_sum[0] * invE; eam0.y = ea_sum[1] * invE;
    eam0.z = ea_sum[2] * invE; eam0.w = ea_sum[3] * invE;
    eam1.x = ea_sum[4] * invE; eam1.y = ea_sum[5] * invE;
    eam1.z = ea_sum[6] * invE; eam1.w = ea_sum[7] * invE;

    int beg = off[node], end = off[node + 1];
    float sumw = 0.f;
    float4 acc = make_float4(0.f, 0.f, 0.f, 0.f);

    int cb = beg;
    while (cb < end) {
        int cnt = end - cb; if (cnt > 64) cnt = 64;
        int sl = 0;
        float4 ba = eam0, bb4 = eam1;
        if (lane < cnt) {
            sl = csr_src[cb + lane];
            int el = csr_eid[cb + lane];
            if (el < E) {
                ba  = *(const float4*)(ea + (size_t)el * 8);
                bb4 = *(const float4*)(ea + (size_t)el * 8 + 4);
            }
        }
        float2 r0 = make_float2(0.f, 0.f), r1 = r0, r2 = r0;
        {
            int s0 = __shfl(sl, 0, 64);
            r0 = *(const float2*)(xl1h + (size_t)s0 * 256 + c4);
            if (cnt > 1) { int s1 = __shfl(sl, 1, 64); r1 = *(const float2*)(xl1h + (size_t)s1 * 256 + c4); }
            if (cnt > 2) { int s2 = __shfl(sl, 2, 64); r2 = *(const float2*)(xl1h + (size_t)s2 * 256 + c4); }
        }
        for (int j = 0; j < cnt; j++) {
            float2 cur = r0;
            r0 = r1; r1 = r2;
            if (j + 3 < cnt) {
                int s3 = __shfl(sl, j + 3, 64);
                r2 = *(const float2*)(xl1h + (size_t)s3 * 256 + c4);
            }
            float eav[8];
            eav[0] = __shfl(ba.x, j, 64);  eav[1] = __shfl(ba.y, j, 64);
            eav[2] = __shfl(ba.z, j, 64);  eav[3] = __shfl(ba.w, j, 64);
            eav[4] = __shfl(bb4.x, j, 64); eav[5] = __shfl(bb4.y, j, 64);
            eav[6] = __shfl(bb4.z, j, 64); eav[7] = __shfl(bb4.w, j, 64);
            const __half2* hp = (const __half2*)&cur;
            float2 lo = __half22float2(hp[0]);
            float2 hi = __half22float2(hp[1]);
            float4 xs = make_float4(lo.x, lo.y, hi.x, hi.y);
            float4 ee = make_float4(0.f, 0.f, 0.f, 0.f);
#pragma unroll
            for (int k = 0; k < 8; k++) {
                ee.x += eav[k] * we[k].x; ee.y += eav[k] * we[k].y;
                ee.z += eav[k] * we[k].z; ee.w += eav[k] * we[k].w;
            }
            float4 v;
            v.x = xs.x + xr4.x + ee.x; v.y = xs.y + xr4.y + ee.y;
            v.z = xs.z + xr4.z + ee.z; v.w = xs.w + xr4.w + ee.w;
            v.x = v.x > 0.f ? v.x : 0.2f * v.x;
            v.y = v.y > 0.f ? v.y : 0.2f * v.y;
            v.z = v.z > 0.f ? v.z : 0.2f * v.z;
            v.w = v.w > 0.f ? v.w : 0.2f * v.w;
            float p = v.x * at4.x + v.y * at4.y + v.z * at4.z + v.w * at4.w;
            p += __shfl_xor(p, 1, 64);
            p += __shfl_xor(p, 2, 64);
            p += __shfl_xor(p, 4, 64);
            p += __shfl_xor(p, 8, 64);
            float wgt = expf(p);
            acc.x += wgt * xs.x;
            acc.y += wgt * xs.y;
            acc.z += wgt * xs.z;
            acc.w += wgt * xs.w;
            sumw += wgt;
        }
        cb += cnt;
    }
    float inv = 1.f / (sumw + 1e-16f);
    float4 r = make_float4(0.f, 0.f, 0.f, 0.f);
#pragma unroll
    for (int q = 0; q < 4; q++) {
        float4 xq = *(const float4*)(x + (size_t)node * 16 + q * 4);
        float xa[4] = { xq.x, xq.y, xq.z, xq.w };
#pragma unroll
        for (int kk = 0; kk < 4; kk++) {
            float4 wv = *(const float4*)(Wres + (size_t)(q * 4 + kk) * 256 + c4);
            r.x += xa[kk] * wv.x; r.y += xa[kk] * wv.y;
            r.z += xa[kk] * wv.z; r.w += xa[kk] * wv.w;
        }
    }
    float4 bi = *(const float4*)(bias1 + c4);
    float4 g4 = *(const float4*)(g + c4);
    float4 b4 = *(const float4*)(bb_ + c4);
    float4 m4 = *(const float4*)(mm_ + c4);
    float4 v4 = *(const float4*)(vv_ + c4);
    float4 o;
    o.x = acc.x * inv + bi.x; o.y = acc.y * inv + bi.y;
    o.z = acc.z * inv + bi.z; o.w = acc.w * inv + bi.w;
    o.x = (o.x - m4.x) * rsqrtf(v4.x + 1e-5f) * g4.x + b4.x + r.x;
    o.y = (o.y - m4.y) * rsqrtf(v4.y + 1e-5f) * g4.y + b4.y + r.y;
    o.z = (o.z - m4.z) * rsqrtf(v4.z + 1e-5f) * g4.z + b4.z + r.z;
    o.w = (o.w - m4.w) * rsqrtf(v4.w + 1e-5f) * g4.w + b4.w + r.w;
    o.x = elu_f(o.x); o.y = elu_f(o.y); o.z = elu_f(o.z); o.w = elu_f(o.w);
    *(uint2*)(h1h + (size_t)node * 256 + c4) = f4_to_half4(o);
}

// ---------- xl2(fp16) = h1@Wl2+bl2, xr2(fp16) = h1@Wr2+br2 (h1 fp16 in) ----------
__global__ __launch_bounds__(256) void k_xlr2(const __half* __restrict__ h1h,
                                              const float* __restrict__ Wl2, const float* __restrict__ bl2,
                                              const float* __restrict__ Wr2, const float* __restrict__ br2,
                                              __half* __restrict__ xl2h, __half* __restrict__ xr2h, int N) {
    __shared__ float sh[32][32];    // [kk][node]
    __shared__ float sw[32][128];   // [kk][col]
    int t = threadIdx.x;
    int tr = t >> 5, tc = t & 31;
    int n0 = blockIdx.x * 32;
    float acc[4][4];
#pragma unroll
    for (int i = 0; i < 4; i++)
#pragma unroll
        for (int j = 0; j < 4; j++) acc[i][j] = 0.f;
    for (int k0 = 0; k0 < 256; k0 += 32) {
        {
            int n = t >> 3, kk0 = (t & 7) * 4;
            int gn = n0 + n;
            float4 hv = make_float4(0.f, 0.f, 0.f, 0.f);
            if (gn < N) hv = half4_to_f4(*(const uint2*)(h1h + (size_t)gn * 256 + k0 + kk0));
            sh[kk0 + 0][n] = hv.x; sh[kk0 + 1][n] = hv.y; sh[kk0 + 2][n] = hv.z; sh[kk0 + 3][n] = hv.w;
        }
        for (int i = t; i < 32 * 128; i += 256) {
            int kk = i >> 7, c = i & 127;
            sw[kk][c] = (c < 64) ? Wl2[(size_t)(k0 + kk) * 64 + c] : Wr2[(size_t)(k0 + kk) * 64 + (c - 64)];
        }
        __syncthreads();
#pragma unroll
        for (int kk = 0; kk < 32; kk++) {
            float4 hv = *(const float4*)&sh[kk][tr * 4];
            float4 wv = *(const float4*)&sw[kk][tc * 4];
            float hh[4] = { hv.x, hv.y, hv.z, hv.w };
            float wwv[4] = { wv.x, wv.y, wv.z, wv.w };
#pragma unroll
            for (int i = 0; i < 4; i++)
#pragma unroll
                for (int j = 0; j < 4; j++) acc[i][j] += hh[i] * wwv[j];
        }
        __syncthreads();
    }
#pragma unroll
    for (int i = 0; i < 4; i++) {
        int gn = n0 + tr * 4 + i;
        if (gn >= N) continue;
#pragma unroll
        for (int j = 0; j < 4; j++) {
            int c = tc * 4 + j;
            float vv = acc[i][j];
            if (c < 64) xl2h[(size_t)gn * 64 + c] = __float2half(vv + bl2[c]);
            else        xr2h[(size_t)gn * 64 + (c - 64)] = __float2half(vv + br2[c - 64]);
        }
    }
}

// ---------- fused conv2 v3: 4 edges/wave, no-shift softmax, plain-sum merge, fp16 xr2 ----------
__global__ __launch_bounds__(256) void k_fagg2(const __half* __restrict__ xl2h, const __half* __restrict__ xr2h,
                                               const int* __restrict__ off, const int* __restrict__ csr_src,
                                               const int* __restrict__ csr_eid,
                                               const float* __restrict__ ea, const float* __restrict__ ea_sum,
                                               const float* __restrict__ We2, const float* __restrict__ att2,
                                               const float* __restrict__ bias2,
                                               const float* __restrict__ g, const float* __restrict__ bb_,
                                               const float* __restrict__ mm_, const float* __restrict__ vv_,
                                               __half* __restrict__ h2h,
                                               int E, int N) {
    int t = threadIdx.x;
    int lane = t & 63, w = t >> 6;
    int node = blockIdx.x * 4 + w;
    if (node >= N) return;
    int seg = lane >> 4;          // edge slot 0..3
    int c4 = (lane & 15) * 4;     // 4 channels owned
    float4 we[8];
#pragma unroll
    for (int k = 0; k < 8; k++) we[k] = *(const float4*)(We2 + k * 64 + c4);
    float4 xr4 = half4_to_f4(*(const uint2*)(xr2h + (size_t)node * 64 + c4));
    float4 at4 = *(const float4*)(att2 + c4);
    float invE = 1.f / (float)E;
    float4 eam0, eam1;
    eam0.x = ea_sum[0] * invE; eam0.y = ea_sum[1] * invE;
    eam0.z = ea_sum[2] * invE; eam0.w = ea_sum[3] * invE;
    eam1.x = ea_sum[4] * invE; eam1.y = ea_sum[5] * invE;
    eam1.z = ea_sum[6] * invE; eam1.w = ea_sum[7] * invE;

    int beg = off[node], end = off[node + 1];
    float sumw = 0.f;
    float4 acc = make_float4(0.f, 0.f, 0.f, 0.f);

    int cb = beg;
    while (cb < end) {
        int cnt = end - cb; if (cnt > 64) cnt = 64;
        int sl = 0;
        float4 ba = eam0, bb4 = eam1;
        if (lane < cnt) {
            sl = csr_src[cb + lane];
            int el = csr_eid[cb + lane];
            if (el < E) {
                ba  = *(const float4*)(ea + (size_t)el * 8);
                bb4 = *(const float4*)(ea + (size_t)el * 8 + 4);
            }
        }
        int nit = (cnt + 3) >> 2;
        float2 r0, r1;
        {
            int s0 = __shfl(sl, seg, 64);
            r0 = *(const float2*)(xl2h + (size_t)s0 * 64 + c4);
            int s1 = __shfl(sl, (seg + 4) & 63, 64);
            r1 = *(const float2*)(xl2h + (size_t)s1 * 64 + c4);
        }
        for (int it = 0; it < nit; ++it) {
            int jj = it * 4 + seg;
            float2 cur = r0;
            r0 = r1;
            {
                int sn = __shfl(sl, (jj + 8) & 63, 64);
                r1 = *(const float2*)(xl2h + (size_t)sn * 64 + c4);
            }
            float eav[8];
            eav[0] = __shfl(ba.x, jj, 64);  eav[1] = __shfl(ba.y, jj, 64);
            eav[2] = __shfl(ba.z, jj, 64);  eav[3] = __shfl(ba.w, jj, 64);
            eav[4] = __shfl(bb4.x, jj, 64); eav[5] = __shfl(bb4.y, jj, 64);
            eav[6] = __shfl(bb4.z, jj, 64); eav[7] = __shfl(bb4.w, jj, 64);
            const __half2* hp = (const __half2*)&cur;
            float2 lo = __half22float2(hp[0]);
            float2 hi = __half22float2(hp[1]);
            float4 xs = make_float4(lo.x, lo.y, hi.x, hi.y);
            float4 ee = make_float4(0.f, 0.f, 0.f, 0.f);
#pragma unroll
            for (int k = 0; k < 8; k++) {
                ee.x += eav[k] * we[k].x; ee.y += eav[k] * we[k].y;
                ee.z += eav[k] * we[k].z; ee.w += eav[k] * we[k].w;
            }
            float4 v;
            v.x = xs.x + xr4.x + ee.x; v.y = xs.y + xr4.y + ee.y;
            v.z = xs.z + xr4.z + ee.z; v.w = xs.w + xr4.w + ee.w;
            v.x = v.x > 0.f ? v.x : 0.2f * v.x;
            v.y = v.y > 0.f ? v.y : 0.2f * v.y;
            v.z = v.z > 0.f ? v.z : 0.2f * v.z;
            v.w = v.w > 0.f ? v.w : 0.2f * v.w;
            float p = v.x * at4.x + v.y * at4.y + v.z * at4.z + v.w * at4.w;
            p += __shfl_xor(p, 1, 64);
            p += __shfl_xor(p, 2, 64);
            p += __shfl_xor(p, 4, 64);
            p += __shfl_xor(p, 8, 64);        // 16-lane segment reduce
            bool valid = jj < cnt;
            float wgt = valid ? expf(p) : 0.f;
            acc.x += wgt * xs.x;
            acc.y += wgt * xs.y;
            acc.z += wgt * xs.z;
            acc.w += wgt * xs.w;
            sumw += wgt;
        }
        cb += cnt;
    }
    // merge the 4 segment states: plain sums (no-shift softmax)
#pragma unroll
    for (int d = 16; d <= 32; d <<= 1) {
        acc.x += __shfl_xor(acc.x, d, 64);
        acc.y += __shfl_xor(acc.y, d, 64);
        acc.z += __shfl_xor(acc.z, d, 64);
        acc.w += __shfl_xor(acc.w, d, 64);
        sumw  += __shfl_xor(sumw, d, 64);
    }
    float inv = 1.f / (sumw + 1e-16f);
    float4 bi = *(const float4*)(bias2 + c4);
    float4 g4 = *(const float4*)(g + c4);
    float4 b4 = *(const float4*)(bb_ + c4);
    float4 m4 = *(const float4*)(mm_ + c4);
    float4 v4 = *(const float4*)(vv_ + c4);
    float4 o;
    o.x = acc.x * inv + bi.x; o.y = acc.y * inv + bi.y;
    o.z = acc.z * inv + bi.z; o.w = acc.w * inv + bi.w;
    o.x = (o.x - m4.x) * rsqrtf(v4.x + 1e-5f) * g4.x + b4.x;
    o.y = (o.y - m4.y) * rsqrtf(v4.y + 1e-5f) * g4.y + b4.y;
    o.z = (o.z - m4.z) * rsqrtf(v4.z + 1e-5f) * g4.z + b4.z;
    o.w = (o.w - m4.w) * rsqrtf(v4.w + 1e-5f) * g4.w + b4.w;
    if (seg == 0) {
        o.x = elu_f(o.x); o.y = elu_f(o.y); o.z = elu_f(o.z); o.w = elu_f(o.w);
        *(uint2*)(h2h + (size_t)node * 64 + c4) = f4_to_half4(o);
    }
}

// ---------- u = h2@Wm1[0:64], v = h2@Wm1[64:128]  (fp16 out, no bias) ----------
__global__ __launch_bounds__(256) void k_uv(const __half* __restrict__ h2h, const float* __restrict__ Wm1,
                                            __half* __restrict__ uh, __half* __restrict__ vh, int N) {
    __shared__ float sh[32][32];    // [kk][node]
    __shared__ float sw[32][128];   // [kk][col]  (u cols 0..63, v cols 64..127)
    int t = threadIdx.x;
    int tr = t >> 5, tc = t & 31;
    int n0 = blockIdx.x * 32;
    float acc[4][4];
#pragma unroll
    for (int i = 0; i < 4; i++)
#pragma unroll
        for (int j = 0; j < 4; j++) acc[i][j] = 0.f;
    for (int k0 = 0; k0 < 64; k0 += 32) {
        {
            int n = t >> 3, kk0 = (t & 7) * 4;
            int gn = n0 + n;
            float4 hv = make_float4(0.f, 0.f, 0.f, 0.f);
            if (gn < N) hv = half4_to_f4(*(const uint2*)(h2h + (size_t)gn * 64 + k0 + kk0));
            sh[kk0 + 0][n] = hv.x; sh[kk0 + 1][n] = hv.y; sh[kk0 + 2][n] = hv.z; sh[kk0 + 3][n] = hv.w;
        }
        for (int i = t; i < 32 * 128; i += 256) {
            int kk = i >> 7, c = i & 127;
            sw[kk][c] = (c < 64) ? Wm1[(size_t)(k0 + kk) * 64 + c]
                                 : Wm1[(size_t)(64 + k0 + kk) * 64 + (c - 64)];
        }
        __syncthreads();
#pragma unroll
        for (int kk = 0; kk < 32; kk++) {
            float4 hv = *(const float4*)&sh[kk][tr * 4];
            float4 wv = *(const float4*)&sw[kk][tc * 4];
            float hh[4] = { hv.x, hv.y, hv.z, hv.w };
            float wwv[4] = { wv.x, wv.y, wv.z, wv.w };
#pragma unroll
            for (int i = 0; i < 4; i++)
#pragma unroll
                for (int j = 0; j < 4; j++) acc[i][j] += hh[i] * wwv[j];
        }
        __syncthreads();
    }
#pragma unroll
    for (int i = 0; i < 4; i++) {
        int gn = n0 + tr * 4 + i;
        if (gn >= N) continue;
#pragma unroll
        for (int j = 0; j < 4; j++) {
            int c = tc * 4 + j;
            if (c < 64) uh[(size_t)gn * 64 + c] = __float2half(acc[i][j]);
            else        vh[(size_t)gn * 64 + (c - 64)] = __float2half(acc[i][j]);
        }
    }
}

// ---------- edge MLP head v3: inline weA = ea@Wm1[128:136]+bm1; z1 = gelu(u[r]+v[c]+weA); layer2+3 fused ----------
__global__ __launch_bounds__(256) void k_mlp2(const __half* __restrict__ uh, const __half* __restrict__ vh,
                                              const float* __restrict__ ea, const int* __restrict__ ei,
                                              const float* __restrict__ Wm1, const float* __restrict__ bm1,
                                              const float* __restrict__ Wm2, const float* __restrict__ bm2,
                                              const float* __restrict__ Wm3, const float* __restrict__ bm3,
                                              float* __restrict__ out, int E) {
    __shared__ float sw2[64 * 32];
    __shared__ float sW1e[8 * 64];
    __shared__ float sb1[64];
    __shared__ int sre[64], sce[64];
    __shared__ float z1[64 * 68];
    int t = threadIdx.x;
    for (int i = t; i < 64 * 32; i += 256) sw2[i] = Wm2[i];
    for (int i = t; i < 512; i += 256) sW1e[i] = Wm1[128 * 64 + i];
    if (t < 64) sb1[t] = bm1[t];
    int e0 = blockIdx.x * 64;
    if (t < 64) {
        int e = e0 + t;
        if (e < E) { sre[t] = ei[e]; sce[t] = ei[E + e]; }
        else { sre[t] = 0; sce[t] = 0; }
    }
    __syncthreads();
    for (int i = t; i < 512; i += 256) {
        int el = i >> 3, q = i & 7;
        int r = sre[el], c = sce[el];
        uint4 ru = *(const uint4*)(uh + (size_t)r * 64 + q * 8);
        uint4 rv = *(const uint4*)(vh + (size_t)c * 64 + q * 8);
        float4 a0 = *(const float4*)(ea + (size_t)(e0 + el) * 8);
        float4 a1 = *(const float4*)(ea + (size_t)(e0 + el) * 8 + 4);
        float av[8] = { a0.x, a0.y, a0.z, a0.w, a1.x, a1.y, a1.z, a1.w };
        float wv[8];
#pragma unroll
        for (int j = 0; j < 8; j++) wv[j] = sb1[q * 8 + j];
#pragma unroll
        for (int k = 0; k < 8; k++) {
            float a = av[k];
#pragma unroll
            for (int j = 0; j < 8; j++) wv[j] += a * sW1e[k * 64 + q * 8 + j];
        }
        float4 uhi, vhi;
        float4 ulo = half8_lo_hi(ru, &uhi);
        float4 vlo = half8_lo_hi(rv, &vhi);
        float4 zlo, zhi;
        zlo.x = gelu_f(ulo.x + vlo.x + wv[0]);
        zlo.y = gelu_f(ulo.y + vlo.y + wv[1]);
        zlo.z = gelu_f(ulo.z + vlo.z + wv[2]);
        zlo.w = gelu_f(ulo.w + vlo.w + wv[3]);
        zhi.x = gelu_f(uhi.x + vhi.x + wv[4]);
        zhi.y = gelu_f(uhi.y + vhi.y + wv[5]);
        zhi.z = gelu_f(uhi.z + vhi.z + wv[6]);
        zhi.w = gelu_f(uhi.w + vhi.w + wv[7]);
        *(float4*)(z1 + el * 68 + q * 8)     = zlo;
        *(float4*)(z1 + el * 68 + q * 8 + 4) = zhi;
    }
    __syncthreads();
    int tr = t >> 3;
    int tc = t & 7;
    float b2[4], w3[4];
#pragma unroll
    for (int j = 0; j < 4; j++) { b2[j] = bm2[tc * 4 + j]; w3[j] = Wm3[tc * 4 + j]; }
    float b3 = bm3[0];
    float acc0[4], acc1[4];
#pragma unroll
    for (int j = 0; j < 4; j++) { acc0[j] = 0.f; acc1[j] = 0.f; }
    const float* z0p = z1 + (tr * 2 + 0) * 68;
    const float* z1p = z1 + (tr * 2 + 1) * 68;
#pragma unroll 8
    for (int k = 0; k < 64; k++) {
        float4 wv = *(const float4*)(sw2 + k * 32 + tc * 4);
        float a0 = z0p[k];
        float a1 = z1p[k];
        acc0[0] += a0 * wv.x; acc0[1] += a0 * wv.y; acc0[2] += a0 * wv.z; acc0[3] += a0 * wv.w;
        acc1[0] += a1 * wv.x; acc1[1] += a1 * wv.y; acc1[2] += a1 * wv.z; acc1[3] += a1 * wv.w;
    }
    float p0 = 0.f, p1 = 0.f;
#pragma unroll
    for (int j = 0; j < 4; j++) {
        p0 += gelu_f(acc0[j] + b2[j]) * w3[j];
        p1 += gelu_f(acc1[j] + b2[j]) * w3[j];
    }
    p0 += __shfl_xor(p0, 1, 64); p0 += __shfl_xor(p0, 2, 64); p0 += __shfl_xor(p0, 4, 64);
    p1 += __shfl_xor(p1, 1, 64); p1 += __shfl_xor(p1, 2, 64); p1 += __shfl_xor(p1, 4, 64);
    if (tc == 0) {
        int e = e0 + tr * 2;
        if (e < E)     out[e]     = 1.f / (1.f + expf(-(p0 + b3)));
        if (e + 1 < E) out[e + 1] = 1.f / (1.f + expf(-(p1 + b3)));
    }
}

extern "C" void kernel_launch(void* const* d_in, const int* in_sizes, int n_in,
                              void* d_out, int out_size, void* d_ws, size_t ws_size,
                              hipStream_t stream) {
    const float* x    = (const float*)d_in[0];
    const int*   ei   = (const int*)d_in[1];
    const float* ea   = (const float*)d_in[2];
    const float* Wl1  = (const float*)d_in[3];
    const float* bl1  = (const float*)d_in[4];
    const float* Wr1  = (const float*)d_in[5];
    const float* br1  = (const float*)d_in[6];
    const float* We1  = (const float*)d_in[7];
    const float* att1 = (const float*)d_in[8];
    const float* bias1= (const float*)d_in[9];
    const float* Wl2  = (const float*)d_in[10];
    const float* bl2  = (const float*)d_in[11];
    const float* Wr2  = (const float*)d_in[12];
    const float* br2  = (const float*)d_in[13];
    const float* We2  = (const float*)d_in[14];
    const float* att2 = (const float*)d_in[15];
    const float* bias2= (const float*)d_in[16];
    const float* bn1g = (const float*)d_in[17];
    const float* bn1b = (const float*)d_in[18];
    const float* bn1m = (const float*)d_in[19];
    const float* bn1v = (const float*)d_in[20];
    const float* bn2g = (const float*)d_in[21];
    const float* bn2b = (const float*)d_in[22];
    const float* bn2m = (const float*)d_in[23];
    const float* bn2v = (const float*)d_in[24];
    const float* Wres = (const float*)d_in[25];
    const float* Wm1  = (const float*)d_in[26];
    const float* bm1  = (const float*)d_in[27];
    const float* Wm2  = (const float*)d_in[28];
    const float* bm2  = (const float*)d_in[29];
    const float* Wm3  = (const float*)d_in[30];
    const float* bm3  = (const float*)d_in[31];
    float* out = (float*)d_out;
    float* ws = (float*)d_ws;

    const int N = NN, E = EE, Etot = ETOT;

    // workspace layout (floats)
    float* ea_sum   = ws;                                     // 16
    int*   counts   = (int*)(ws + 16);                        // N
    int*   off      = (int*)(ws + 16 + (size_t)N);            // N+16
    int*   cursor   = (int*)(ws + 32 + (size_t)2 * N);        // N
    int*   csr_src  = (int*)(ws + 32 + (size_t)3 * N);        // Etot
    int*   csr_eid  = (int*)(ws + 32 + (size_t)3 * N + Etot); // Etot
    size_t base     = 32 + (size_t)3 * N + (size_t)2 * Etot;
    __half* xl1h    = (__half*)(ws + base);                   // 256N halfs = 128N floats
    __half* xl2h    = xl1h;                                   // reuses (xl1h dead after k_fagg1)
    __half* h2h     = (__half*)(ws + base + (size_t)128 * N); // 64N halfs = 32N floats
    __half* xr1h    = (__half*)(ws + base + (size_t)160 * N); // 256N halfs = 128N floats
    __half* h1h     = xr1h;                                   // in-place (own row read before write)
    __half* xr2h    = (__half*)(ws + base + (size_t)288 * N); // 64N halfs = 32N floats
    __half* uh      = xr2h;                                   // overlays xr2h (dead after k_fagg2)
    __half* vh      = uh + (size_t)64 * N;                    // next 32N floats

    hipMemsetAsync(ea_sum, 0, 16 * sizeof(float), stream);
    hipMemsetAsync(counts, 0, (size_t)N * sizeof(int), stream);

    int S = (Etot + 255) / 256;
    k_init<<<256 + S, 256, 0, stream>>>(ea, ea_sum, ei, counts, E, N);
    k_scan<<<1, 1024, 0, stream>>>(counts, off, cursor, N);
    k_scat_nt1<<<S + (N + 31) / 32, 256, 0, stream>>>(ei, cursor, csr_src, csr_eid,
                                                      x, Wl1, bl1, Wr1, br1, xl1h, xr1h, E, N);
    k_fagg1<<<(N + 3) / 4, 256, 0, stream>>>(xl1h, xr1h, off, csr_src, csr_eid, ea, ea_sum,
                                             We1, att1, bias1, x, Wres,
                                             bn1g, bn1b, bn1m, bn1v, h1h, E, N);
    k_xlr2<<<(N + 31) / 32, 256, 0, stream>>>(h1h, Wl2, bl2, Wr2, br2, xl2h, xr2h, N);
    k_fagg2<<<(N + 3) / 4, 256, 0, stream>>>(xl2h, xr2h, off, csr_src, csr_eid, ea, ea_sum,
                                             We2, att2, bias2,
                                             bn2g, bn2b, bn2m, bn2v, h2h, E, N);
    k_uv<<<(N + 31) / 32, 256, 0, stream>>>(h2h, Wm1, uh, vh, N);
    k_mlp2<<<(E + 63) / 64, 256, 0, stream>>>(uh, vh, ea, ei, Wm1, bm1, Wm2, bm2, Wm3, bm3, out, E);
}

// Round 14
// 451.280 us; speedup vs baseline: 1.3193x; 1.0040x over previous
//
#include <hip/hip_runtime.h>
#include <hip/hip_bf16.h>
#include <hip/hip_fp16.h>
#include <math.h>

#define NN 50000
#define EE 400000
#define ETOT (NN + EE)

// ---------- helpers ----------
__device__ __forceinline__ float gelu_f(float x) {
    return 0.5f * x * (1.f + erff(x * 0.7071067811865476f));
}
__device__ __forceinline__ float elu_f(float x) {
    return x > 0.f ? x : expm1f(x);
}
__device__ __forceinline__ float4 half8_lo_hi(uint4 raw, float4* hi) {
    __half2 h0 = *(__half2*)&raw.x, h1 = *(__half2*)&raw.y;
    __half2 h2 = *(__half2*)&raw.z, h3 = *(__half2*)&raw.w;
    float2 f0 = __half22float2(h0), f1 = __half22float2(h1);
    float2 f2 = __half22float2(h2), f3 = __half22float2(h3);
    *hi = make_float4(f2.x, f2.y, f3.x, f3.y);
    return make_float4(f0.x, f0.y, f1.x, f1.y);
}
__device__ __forceinline__ float4 half4_to_f4(uint2 raw) {
    __half2 a = *(__half2*)&raw.x, b = *(__half2*)&raw.y;
    float2 fa = __half22float2(a), fb = __half22float2(b);
    return make_float4(fa.x, fa.y, fb.x, fb.y);
}
__device__ __forceinline__ uint2 f4_to_half4(float4 v) {
    __half2 h0 = __floats2half2_rn(v.x, v.y);
    __half2 h1 = __floats2half2_rn(v.z, v.w);
    uint2 pk;
    pk.x = *(unsigned*)&h0;
    pk.y = *(unsigned*)&h1;
    return pk;
}
__device__ __forceinline__ uint4 pack8_half(float4 a, float4 b) {
    __half2 q0 = __floats2half2_rn(a.x, a.y), q1 = __floats2half2_rn(a.z, a.w);
    __half2 q2 = __floats2half2_rn(b.x, b.y), q3 = __floats2half2_rn(b.z, b.w);
    uint4 pk;
    pk.x = *(unsigned*)&q0; pk.y = *(unsigned*)&q1;
    pk.z = *(unsigned*)&q2; pk.w = *(unsigned*)&q3;
    return pk;
}
__device__ __forceinline__ void unpack8_half(int x, int y, int z, int w, float* ev) {
    float2 f0 = __half22float2(*(__half2*)&x);
    float2 f1 = __half22float2(*(__half2*)&y);
    float2 f2 = __half22float2(*(__half2*)&z);
    float2 f3 = __half22float2(*(__half2*)&w);
    ev[0] = f0.x; ev[1] = f0.y; ev[2] = f1.x; ev[3] = f1.y;
    ev[4] = f2.x; ev[5] = f2.y; ev[6] = f3.x; ev[7] = f3.y;
}

// ---------- combined: ea mean (sum) + ea->fp16 copy [blocks 0..255] + degree count [blocks 256..] ----------
__global__ __launch_bounds__(256) void k_init(const float* __restrict__ ea, float* __restrict__ ea_sum,
                                              __half* __restrict__ eah,
                                              const int* __restrict__ ei, int* __restrict__ counts,
                                              int E, int N) {
    int t = threadIdx.x;
    if (blockIdx.x < 256) {
        float s[8];
#pragma unroll
        for (int i = 0; i < 8; i++) s[i] = 0.f;
        for (int e = blockIdx.x * 256 + t; e < E; e += 256 * 256) {
            const float4* p = (const float4*)(ea + (size_t)e * 8);
            float4 a = p[0], b = p[1];
            s[0] += a.x; s[1] += a.y; s[2] += a.z; s[3] += a.w;
            s[4] += b.x; s[5] += b.y; s[6] += b.z; s[7] += b.w;
            *(uint4*)(eah + (size_t)e * 8) = pack8_half(a, b);
        }
#pragma unroll
        for (int o = 32; o; o >>= 1)
#pragma unroll
            for (int i = 0; i < 8; i++) s[i] += __shfl_xor(s[i], o, 64);
        __shared__ float sh[4][8];
        int lane = t & 63, w = t >> 6;
        if (lane == 0)
#pragma unroll
            for (int i = 0; i < 8; i++) sh[w][i] = s[i];
        __syncthreads();
        if (t < 8) {
            float v = sh[0][t] + sh[1][t] + sh[2][t] + sh[3][t];
            atomicAdd(ea_sum + t, v);
        }
    } else {
        int e = (blockIdx.x - 256) * 256 + t;
        if (e >= E + N) return;
        int d = (e < E) ? ei[E + e] : (e - E);
        atomicAdd(counts + d, 1);
    }
}

// ---------- scan (4 elems/thread) ----------
__global__ __launch_bounds__(1024) void k_scan(const int* __restrict__ counts, int* __restrict__ off,
                                               int* __restrict__ cursor, int N) {
    __shared__ int buf[1024];
    int t = threadIdx.x;
    int carry = 0;
    if (t == 0) off[0] = 0;
    for (int base = 0; base < N; base += 4096) {
        int i0 = base + t * 4;
        int v0 = 0, v1 = 0, v2 = 0, v3 = 0;
        if (i0 + 3 < N) {
            int4 vv = *(const int4*)(counts + i0);
            v0 = vv.x; v1 = vv.y; v2 = vv.z; v3 = vv.w;
        } else {
            if (i0 < N)     v0 = counts[i0];
            if (i0 + 1 < N) v1 = counts[i0 + 1];
            if (i0 + 2 < N) v2 = counts[i0 + 2];
            if (i0 + 3 < N) v3 = counts[i0 + 3];
        }
        int s01 = v0 + v1, s012 = s01 + v2, tot4 = s012 + v3;
        buf[t] = tot4;
        __syncthreads();
        for (int o = 1; o < 1024; o <<= 1) {
            int add = (t >= o) ? buf[t - o] : 0;
            __syncthreads();
            buf[t] += add;
            __syncthreads();
        }
        int incl4 = buf[t] + carry;
        int excl = incl4 - tot4;
        if (i0 < N)     { off[i0 + 1] = excl + v0;   cursor[i0]     = excl; }
        if (i0 + 1 < N) { off[i0 + 2] = excl + s01;  cursor[i0 + 1] = excl + v0; }
        if (i0 + 2 < N) { off[i0 + 3] = excl + s012; cursor[i0 + 2] = excl + s01; }
        if (i0 + 3 < N) { off[i0 + 4] = excl + tot4; cursor[i0 + 3] = excl + s012; }
        int tot = buf[1023];
        __syncthreads();
        carry += tot;
    }
}

// ---------- combined: scatter [blocks 0..S) + ntrans1 [blocks S..) ----------
__global__ __launch_bounds__(256) void k_scat_nt1(const int* __restrict__ ei, int* __restrict__ cursor,
                                                  int* __restrict__ csr_src, int* __restrict__ csr_eid,
                                                  const float* __restrict__ x,
                                                  const float* __restrict__ Wl, const float* __restrict__ bl,
                                                  const float* __restrict__ Wr, const float* __restrict__ br,
                                                  __half* __restrict__ xl1h, __half* __restrict__ xr1h,
                                                  int E, int N) {
    __shared__ float swl[16 * 256];
    __shared__ float swr[16 * 256];
    __shared__ float sx[32 * 16];
    int t = threadIdx.x;
    int S = (E + N + 255) >> 8;
    if ((int)blockIdx.x < S) {
        int e = blockIdx.x * 256 + t;
        if (e >= E + N) return;
        int s, d;
        if (e < E) { s = ei[e]; d = ei[E + e]; }
        else { s = d = e - E; }
        int pos = atomicAdd(cursor + d, 1);
        csr_src[pos] = s;
        csr_eid[pos] = e;
        return;
    }
    int bid = blockIdx.x - S;
#pragma unroll
    for (int k = 0; k < 16; k++) { swl[k * 256 + t] = Wl[k * 256 + t]; swr[k * 256 + t] = Wr[k * 256 + t]; }
    int n0 = bid * 32;
    for (int i = t; i < 32 * 16; i += 256) {
        int n = n0 + (i >> 4);
        sx[i] = (n < N) ? x[(size_t)n * 16 + (i & 15)] : 0.f;
    }
    __syncthreads();
    float bL = bl[t], bR = br[t];
    for (int ni = 0; ni < 32; ni++) {
        int n = n0 + ni;
        if (n >= N) break;
        float al = bL, ar = bR;
#pragma unroll
        for (int k = 0; k < 16; k++) {
            float xv = sx[ni * 16 + k];
            al += xv * swl[k * 256 + t];
            ar += xv * swr[k * 256 + t];
        }
        xl1h[(size_t)n * 256 + t] = __float2half(al);
        xr1h[(size_t)n * 256 + t] = __float2half(ar);
    }
}

// ---------- fused conv1: zero-LDS, packed-ea broadcast (4 shfl), depth-3 prefetch, no-shift softmax ----------
__global__ __launch_bounds__(256) void k_fagg1(const __half* __restrict__ xl1h, const __half* __restrict__ xr1h,
                                               const int* __restrict__ off, const int* __restrict__ csr_src,
                                               const int* __restrict__ csr_eid,
                                               const __half* __restrict__ eah, const float* __restrict__ ea_sum,
                                               const float* __restrict__ We1, const float* __restrict__ att1,
                                               const float* __restrict__ bias1,
                                               const float* __restrict__ x, const float* __restrict__ Wres,
                                               const float* __restrict__ g, const float* __restrict__ bb_,
                                               const float* __restrict__ mm_, const float* __restrict__ vv_,
                                               __half* __restrict__ h1h,
                                               int E, int N) {
    int t = threadIdx.x;
    int lane = t & 63, w = t >> 6;
    int node = blockIdx.x * 4 + w;
    if (node >= N) return;
    int c4 = lane * 4;
    float4 we[8];
#pragma unroll
    for (int k = 0; k < 8; k++) we[k] = *(const float4*)(We1 + k * 256 + c4);
    float4 xr4 = half4_to_f4(*(const uint2*)(xr1h + (size_t)node * 256 + c4));
    float4 at4 = *(const float4*)(att1 + c4);
    float invE = 1.f / (float)E;
    float4 eam0, eam1;
    eam0.x = ea_sum[0] * invE; eam0.y = ea_sum[1] * invE;
    eam0.z = ea_sum[2] * invE; eam0.w = ea_sum[3] * invE;
    eam1.x = ea_sum[4] * invE; eam1.y = ea_sum[5] * invE;
    eam1.z = ea_sum[6] * invE; eam1.w = ea_sum[7] * invE;
    uint4 eamp = pack8_half(eam0, eam1);

    int beg = off[node], end = off[node + 1];
    float sumw = 0.f;
    float4 acc = make_float4(0.f, 0.f, 0.f, 0.f);

    int cb = beg;
    while (cb < end) {
        int cnt = end - cb; if (cnt > 64) cnt = 64;
        int sl = 0;
        uint4 pea = eamp;
        if (lane < cnt) {
            sl = csr_src[cb + lane];
            int el = csr_eid[cb + lane];
            if (el < E) pea = *(const uint4*)(eah + (size_t)el * 8);
        }
        float2 r0 = make_float2(0.f, 0.f), r1 = r0, r2 = r0;
        {
            int s0 = __shfl(sl, 0, 64);
            r0 = *(const float2*)(xl1h + (size_t)s0 * 256 + c4);
            if (cnt > 1) { int s1 = __shfl(sl, 1, 64); r1 = *(const float2*)(xl1h + (size_t)s1 * 256 + c4); }
            if (cnt > 2) { int s2 = __shfl(sl, 2, 64); r2 = *(const float2*)(xl1h + (size_t)s2 * 256 + c4); }
        }
        for (int j = 0; j < cnt; j++) {
            float2 cur = r0;
            r0 = r1; r1 = r2;
            if (j + 3 < cnt) {
                int s3 = __shfl(sl, j + 3, 64);
                r2 = *(const float2*)(xl1h + (size_t)s3 * 256 + c4);
            }
            int ex = __shfl((int)pea.x, j, 64);
            int ey = __shfl((int)pea.y, j, 64);
            int ez = __shfl((int)pea.z, j, 64);
            int ew = __shfl((int)pea.w, j, 64);
            float eav[8];
            unpack8_half(ex, ey, ez, ew, eav);
            const __half2* hp = (const __half2*)&cur;
            float2 lo = __half22float2(hp[0]);
            float2 hi = __half22float2(hp[1]);
            float4 xs = make_float4(lo.x, lo.y, hi.x, hi.y);
            float4 ee = make_float4(0.f, 0.f, 0.f, 0.f);
#pragma unroll
            for (int k = 0; k < 8; k++) {
                ee.x += eav[k] * we[k].x; ee.y += eav[k] * we[k].y;
                ee.z += eav[k] * we[k].z; ee.w += eav[k] * we[k].w;
            }
            float4 v;
            v.x = xs.x + xr4.x + ee.x; v.y = xs.y + xr4.y + ee.y;
            v.z = xs.z + xr4.z + ee.z; v.w = xs.w + xr4.w + ee.w;
            v.x = v.x > 0.f ? v.x : 0.2f * v.x;
            v.y = v.y > 0.f ? v.y : 0.2f * v.y;
            v.z = v.z > 0.f ? v.z : 0.2f * v.z;
            v.w = v.w > 0.f ? v.w : 0.2f * v.w;
            float p = v.x * at4.x + v.y * at4.y + v.z * at4.z + v.w * at4.w;
            p += __shfl_xor(p, 1, 64);
            p += __shfl_xor(p, 2, 64);
            p += __shfl_xor(p, 4, 64);
            p += __shfl_xor(p, 8, 64);
            float wgt = expf(p);
            acc.x += wgt * xs.x;
            acc.y += wgt * xs.y;
            acc.z += wgt * xs.z;
            acc.w += wgt * xs.w;
            sumw += wgt;
        }
        cb += cnt;
    }
    float inv = 1.f / (sumw + 1e-16f);
    float4 r = make_float4(0.f, 0.f, 0.f, 0.f);
#pragma unroll
    for (int q = 0; q < 4; q++) {
        float4 xq = *(const float4*)(x + (size_t)node * 16 + q * 4);
        float xa[4] = { xq.x, xq.y, xq.z, xq.w };
#pragma unroll
        for (int kk = 0; kk < 4; kk++) {
            float4 wv = *(const float4*)(Wres + (size_t)(q * 4 + kk) * 256 + c4);
            r.x += xa[kk] * wv.x; r.y += xa[kk] * wv.y;
            r.z += xa[kk] * wv.z; r.w += xa[kk] * wv.w;
        }
    }
    float4 bi = *(const float4*)(bias1 + c4);
    float4 g4 = *(const float4*)(g + c4);
    float4 b4 = *(const float4*)(bb_ + c4);
    float4 m4 = *(const float4*)(mm_ + c4);
    float4 v4 = *(const float4*)(vv_ + c4);
    float4 o;
    o.x = acc.x * inv + bi.x; o.y = acc.y * inv + bi.y;
    o.z = acc.z * inv + bi.z; o.w = acc.w * inv + bi.w;
    o.x = (o.x - m4.x) * rsqrtf(v4.x + 1e-5f) * g4.x + b4.x + r.x;
    o.y = (o.y - m4.y) * rsqrtf(v4.y + 1e-5f) * g4.y + b4.y + r.y;
    o.z = (o.z - m4.z) * rsqrtf(v4.z + 1e-5f) * g4.z + b4.z + r.z;
    o.w = (o.w - m4.w) * rsqrtf(v4.w + 1e-5f) * g4.w + b4.w + r.w;
    o.x = elu_f(o.x); o.y = elu_f(o.y); o.z = elu_f(o.z); o.w = elu_f(o.w);
    *(uint2*)(h1h + (size_t)node * 256 + c4) = f4_to_half4(o);
}

// ---------- xl2(fp16) = h1@Wl2+bl2, xr2(fp16) = h1@Wr2+br2 (h1 fp16 in) ----------
__global__ __launch_bounds__(256) void k_xlr2(const __half* __restrict__ h1h,
                                              const float* __restrict__ Wl2, const float* __restrict__ bl2,
                                              const float* __restrict__ Wr2, const float* __restrict__ br2,
                                              __half* __restrict__ xl2h, __half* __restrict__ xr2h, int N) {
    __shared__ float sh[32][32];    // [kk][node]
    __shared__ float sw[32][128];   // [kk][col]
    int t = threadIdx.x;
    int tr = t >> 5, tc = t & 31;
    int n0 = blockIdx.x * 32;
    float acc[4][4];
#pragma unroll
    for (int i = 0; i < 4; i++)
#pragma unroll
        for (int j = 0; j < 4; j++) acc[i][j] = 0.f;
    for (int k0 = 0; k0 < 256; k0 += 32) {
        {
            int n = t >> 3, kk0 = (t & 7) * 4;
            int gn = n0 + n;
            float4 hv = make_float4(0.f, 0.f, 0.f, 0.f);
            if (gn < N) hv = half4_to_f4(*(const uint2*)(h1h + (size_t)gn * 256 + k0 + kk0));
            sh[kk0 + 0][n] = hv.x; sh[kk0 + 1][n] = hv.y; sh[kk0 + 2][n] = hv.z; sh[kk0 + 3][n] = hv.w;
        }
        for (int i = t; i < 32 * 128; i += 256) {
            int kk = i >> 7, c = i & 127;
            sw[kk][c] = (c < 64) ? Wl2[(size_t)(k0 + kk) * 64 + c] : Wr2[(size_t)(k0 + kk) * 64 + (c - 64)];
        }
        __syncthreads();
#pragma unroll
        for (int kk = 0; kk < 32; kk++) {
            float4 hv = *(const float4*)&sh[kk][tr * 4];
            float4 wv = *(const float4*)&sw[kk][tc * 4];
            float hh[4] = { hv.x, hv.y, hv.z, hv.w };
            float wwv[4] = { wv.x, wv.y, wv.z, wv.w };
#pragma unroll
            for (int i = 0; i < 4; i++)
#pragma unroll
                for (int j = 0; j < 4; j++) acc[i][j] += hh[i] * wwv[j];
        }
        __syncthreads();
    }
#pragma unroll
    for (int i = 0; i < 4; i++) {
        int gn = n0 + tr * 4 + i;
        if (gn >= N) continue;
#pragma unroll
        for (int j = 0; j < 4; j++) {
            int c = tc * 4 + j;
            float vv = acc[i][j];
            if (c < 64) xl2h[(size_t)gn * 64 + c] = __float2half(vv + bl2[c]);
            else        xr2h[(size_t)gn * 64 + (c - 64)] = __float2half(vv + br2[c - 64]);
        }
    }
}

// ---------- fused conv2 v3: 4 edges/wave, packed-ea broadcast, no-shift softmax ----------
__global__ __launch_bounds__(256) void k_fagg2(const __half* __restrict__ xl2h, const __half* __restrict__ xr2h,
                                               const int* __restrict__ off, const int* __restrict__ csr_src,
                                               const int* __restrict__ csr_eid,
                                               const __half* __restrict__ eah, const float* __restrict__ ea_sum,
                                               const float* __restrict__ We2, const float* __restrict__ att2,
                                               const float* __restrict__ bias2,
                                               const float* __restrict__ g, const float* __restrict__ bb_,
                                               const float* __restrict__ mm_, const float* __restrict__ vv_,
                                               __half* __restrict__ h2h,
                                               int E, int N) {
    int t = threadIdx.x;
    int lane = t & 63, w = t >> 6;
    int node = blockIdx.x * 4 + w;
    if (node >= N) return;
    int seg = lane >> 4;          // edge slot 0..3
    int c4 = (lane & 15) * 4;     // 4 channels owned
    float4 we[8];
#pragma unroll
    for (int k = 0; k < 8; k++) we[k] = *(const float4*)(We2 + k * 64 + c4);
    float4 xr4 = half4_to_f4(*(const uint2*)(xr2h + (size_t)node * 64 + c4));
    float4 at4 = *(const float4*)(att2 + c4);
    float invE = 1.f / (float)E;
    float4 eam0, eam1;
    eam0.x = ea_sum[0] * invE; eam0.y = ea_sum[1] * invE;
    eam0.z = ea_sum[2] * invE; eam0.w = ea_sum[3] * invE;
    eam1.x = ea_sum[4] * invE; eam1.y = ea_sum[5] * invE;
    eam1.z = ea_sum[6] * invE; eam1.w = ea_sum[7] * invE;
    uint4 eamp = pack8_half(eam0, eam1);

    int beg = off[node], end = off[node + 1];
    float sumw = 0.f;
    float4 acc = make_float4(0.f, 0.f, 0.f, 0.f);

    int cb = beg;
    while (cb < end) {
        int cnt = end - cb; if (cnt > 64) cnt = 64;
        int sl = 0;
        uint4 pea = eamp;
        if (lane < cnt) {
            sl = csr_src[cb + lane];
            int el = csr_eid[cb + lane];
            if (el < E) pea = *(const uint4*)(eah + (size_t)el * 8);
        }
        int nit = (cnt + 3) >> 2;
        float2 r0, r1;
        {
            int s0 = __shfl(sl, seg, 64);
            r0 = *(const float2*)(xl2h + (size_t)s0 * 64 + c4);
            int s1 = __shfl(sl, (seg + 4) & 63, 64);
            r1 = *(const float2*)(xl2h + (size_t)s1 * 64 + c4);
        }
        for (int it = 0; it < nit; ++it) {
            int jj = it * 4 + seg;
            float2 cur = r0;
            r0 = r1;
            {
                int sn = __shfl(sl, (jj + 8) & 63, 64);
                r1 = *(const float2*)(xl2h + (size_t)sn * 64 + c4);
            }
            int ex = __shfl((int)pea.x, jj, 64);
            int ey = __shfl((int)pea.y, jj, 64);
            int ez = __shfl((int)pea.z, jj, 64);
            int ew = __shfl((int)pea.w, jj, 64);
            float eav[8];
            unpack8_half(ex, ey, ez, ew, eav);
            const __half2* hp = (const __half2*)&cur;
            float2 lo = __half22float2(hp[0]);
            float2 hi = __half22float2(hp[1]);
            float4 xs = make_float4(lo.x, lo.y, hi.x, hi.y);
            float4 ee = make_float4(0.f, 0.f, 0.f, 0.f);
#pragma unroll
            for (int k = 0; k < 8; k++) {
                ee.x += eav[k] * we[k].x; ee.y += eav[k] * we[k].y;
                ee.z += eav[k] * we[k].z; ee.w += eav[k] * we[k].w;
            }
            float4 v;
            v.x = xs.x + xr4.x + ee.x; v.y = xs.y + xr4.y + ee.y;
            v.z = xs.z + xr4.z + ee.z; v.w = xs.w + xr4.w + ee.w;
            v.x = v.x > 0.f ? v.x : 0.2f * v.x;
            v.y = v.y > 0.f ? v.y : 0.2f * v.y;
            v.z = v.z > 0.f ? v.z : 0.2f * v.z;
            v.w = v.w > 0.f ? v.w : 0.2f * v.w;
            float p = v.x * at4.x + v.y * at4.y + v.z * at4.z + v.w * at4.w;
            p += __shfl_xor(p, 1, 64);
            p += __shfl_xor(p, 2, 64);
            p += __shfl_xor(p, 4, 64);
            p += __shfl_xor(p, 8, 64);        // 16-lane segment reduce
            bool valid = jj < cnt;
            float wgt = valid ? expf(p) : 0.f;
            acc.x += wgt * xs.x;
            acc.y += wgt * xs.y;
            acc.z += wgt * xs.z;
            acc.w += wgt * xs.w;
            sumw += wgt;
        }
        cb += cnt;
    }
#pragma unroll
    for (int d = 16; d <= 32; d <<= 1) {
        acc.x += __shfl_xor(acc.x, d, 64);
        acc.y += __shfl_xor(acc.y, d, 64);
        acc.z += __shfl_xor(acc.z, d, 64);
        acc.w += __shfl_xor(acc.w, d, 64);
        sumw  += __shfl_xor(sumw, d, 64);
    }
    float inv = 1.f / (sumw + 1e-16f);
    float4 bi = *(const float4*)(bias2 + c4);
    float4 g4 = *(const float4*)(g + c4);
    float4 b4 = *(const float4*)(bb_ + c4);
    float4 m4 = *(const float4*)(mm_ + c4);
    float4 v4 = *(const float4*)(vv_ + c4);
    float4 o;
    o.x = acc.x * inv + bi.x; o.y = acc.y * inv + bi.y;
    o.z = acc.z * inv + bi.z; o.w = acc.w * inv + bi.w;
    o.x = (o.x - m4.x) * rsqrtf(v4.x + 1e-5f) * g4.x + b4.x;
    o.y = (o.y - m4.y) * rsqrtf(v4.y + 1e-5f) * g4.y + b4.y;
    o.z = (o.z - m4.z) * rsqrtf(v4.z + 1e-5f) * g4.z + b4.z;
    o.w = (o.w - m4.w) * rsqrtf(v4.w + 1e-5f) * g4.w + b4.w;
    if (seg == 0) {
        o.x = elu_f(o.x); o.y = elu_f(o.y); o.z = elu_f(o.z); o.w = elu_f(o.w);
        *(uint2*)(h2h + (size_t)node * 64 + c4) = f4_to_half4(o);
    }
}

// ---------- u = h2@Wm1[0:64], v = h2@Wm1[64:128]  (fp16 out, no bias) ----------
__global__ __launch_bounds__(256) void k_uv(const __half* __restrict__ h2h, const float* __restrict__ Wm1,
                                            __half* __restrict__ uh, __half* __restrict__ vh, int N) {
    __shared__ float sh[32][32];    // [kk][node]
    __shared__ float sw[32][128];   // [kk][col]  (u cols 0..63, v cols 64..127)
    int t = threadIdx.x;
    int tr = t >> 5, tc = t & 31;
    int n0 = blockIdx.x * 32;
    float acc[4][4];
#pragma unroll
    for (int i = 0; i < 4; i++)
#pragma unroll
        for (int j = 0; j < 4; j++) acc[i][j] = 0.f;
    for (int k0 = 0; k0 < 64; k0 += 32) {
        {
            int n = t >> 3, kk0 = (t & 7) * 4;
            int gn = n0 + n;
            float4 hv = make_float4(0.f, 0.f, 0.f, 0.f);
            if (gn < N) hv = half4_to_f4(*(const uint2*)(h2h + (size_t)gn * 64 + k0 + kk0));
            sh[kk0 + 0][n] = hv.x; sh[kk0 + 1][n] = hv.y; sh[kk0 + 2][n] = hv.z; sh[kk0 + 3][n] = hv.w;
        }
        for (int i = t; i < 32 * 128; i += 256) {
            int kk = i >> 7, c = i & 127;
            sw[kk][c] = (c < 64) ? Wm1[(size_t)(k0 + kk) * 64 + c]
                                 : Wm1[(size_t)(64 + k0 + kk) * 64 + (c - 64)];
        }
        __syncthreads();
#pragma unroll
        for (int kk = 0; kk < 32; kk++) {
            float4 hv = *(const float4*)&sh[kk][tr * 4];
            float4 wv = *(const float4*)&sw[kk][tc * 4];
            float hh[4] = { hv.x, hv.y, hv.z, hv.w };
            float wwv[4] = { wv.x, wv.y, wv.z, wv.w };
#pragma unroll
            for (int i = 0; i < 4; i++)
#pragma unroll
                for (int j = 0; j < 4; j++) acc[i][j] += hh[i] * wwv[j];
        }
        __syncthreads();
    }
#pragma unroll
    for (int i = 0; i < 4; i++) {
        int gn = n0 + tr * 4 + i;
        if (gn >= N) continue;
#pragma unroll
        for (int j = 0; j < 4; j++) {
            int c = tc * 4 + j;
            if (c < 64) uh[(size_t)gn * 64 + c] = __float2half(acc[i][j]);
            else        vh[(size_t)gn * 64 + (c - 64)] = __float2half(acc[i][j]);
        }
    }
}

// ---------- edge MLP head v3: inline weA (fp16 ea); z1 = gelu(u[r]+v[c]+weA); layer2+3 fused ----------
__global__ __launch_bounds__(256) void k_mlp2(const __half* __restrict__ uh, const __half* __restrict__ vh,
                                              const __half* __restrict__ eah, const int* __restrict__ ei,
                                              const float* __restrict__ Wm1, const float* __restrict__ bm1,
                                              const float* __restrict__ Wm2, const float* __restrict__ bm2,
                                              const float* __restrict__ Wm3, const float* __restrict__ bm3,
                                              float* __restrict__ out, int E) {
    __shared__ float sw2[64 * 32];
    __shared__ float sW1e[8 * 64];
    __shared__ float sb1[64];
    __shared__ int sre[64], sce[64];
    __shared__ float z1[64 * 68];
    int t = threadIdx.x;
    for (int i = t; i < 64 * 32; i += 256) sw2[i] = Wm2[i];
    for (int i = t; i < 512; i += 256) sW1e[i] = Wm1[128 * 64 + i];
    if (t < 64) sb1[t] = bm1[t];
    int e0 = blockIdx.x * 64;
    if (t < 64) {
        int e = e0 + t;
        if (e < E) { sre[t] = ei[e]; sce[t] = ei[E + e]; }
        else { sre[t] = 0; sce[t] = 0; }
    }
    __syncthreads();
    for (int i = t; i < 512; i += 256) {
        int el = i >> 3, q = i & 7;
        int r = sre[el], c = sce[el];
        uint4 ru = *(const uint4*)(uh + (size_t)r * 64 + q * 8);
        uint4 rv = *(const uint4*)(vh + (size_t)c * 64 + q * 8);
        uint4 rea = *(const uint4*)(eah + (size_t)(e0 + el) * 8);
        float av[8];
        unpack8_half((int)rea.x, (int)rea.y, (int)rea.z, (int)rea.w, av);
        float wv[8];
#pragma unroll
        for (int j = 0; j < 8; j++) wv[j] = sb1[q * 8 + j];
#pragma unroll
        for (int k = 0; k < 8; k++) {
            float a = av[k];
#pragma unroll
            for (int j = 0; j < 8; j++) wv[j] += a * sW1e[k * 64 + q * 8 + j];
        }
        float4 uhi, vhi;
        float4 ulo = half8_lo_hi(ru, &uhi);
        float4 vlo = half8_lo_hi(rv, &vhi);
        float4 zlo, zhi;
        zlo.x = gelu_f(ulo.x + vlo.x + wv[0]);
        zlo.y = gelu_f(ulo.y + vlo.y + wv[1]);
        zlo.z = gelu_f(ulo.z + vlo.z + wv[2]);
        zlo.w = gelu_f(ulo.w + vlo.w + wv[3]);
        zhi.x = gelu_f(uhi.x + vhi.x + wv[4]);
        zhi.y = gelu_f(uhi.y + vhi.y + wv[5]);
        zhi.z = gelu_f(uhi.z + vhi.z + wv[6]);
        zhi.w = gelu_f(uhi.w + vhi.w + wv[7]);
        *(float4*)(z1 + el * 68 + q * 8)     = zlo;
        *(float4*)(z1 + el * 68 + q * 8 + 4) = zhi;
    }
    __syncthreads();
    int tr = t >> 3;
    int tc = t & 7;
    float b2[4], w3[4];
#pragma unroll
    for (int j = 0; j < 4; j++) { b2[j] = bm2[tc * 4 + j]; w3[j] = Wm3[tc * 4 + j]; }
    float b3 = bm3[0];
    float acc0[4], acc1[4];
#pragma unroll
    for (int j = 0; j < 4; j++) { acc0[j] = 0.f; acc1[j] = 0.f; }
    const float* z0p = z1 + (tr * 2 + 0) * 68;
    const float* z1p = z1 + (tr * 2 + 1) * 68;
#pragma unroll 8
    for (int k = 0; k < 64; k++) {
        float4 wv = *(const float4*)(sw2 + k * 32 + tc * 4);
        float a0 = z0p[k];
        float a1 = z1p[k];
        acc0[0] += a0 * wv.x; acc0[1] += a0 * wv.y; acc0[2] += a0 * wv.z; acc0[3] += a0 * wv.w;
        acc1[0] += a1 * wv.x; acc1[1] += a1 * wv.y; acc1[2] += a1 * wv.z; acc1[3] += a1 * wv.w;
    }
    float p0 = 0.f, p1 = 0.f;
#pragma unroll
    for (int j = 0; j < 4; j++) {
        p0 += gelu_f(acc0[j] + b2[j]) * w3[j];
        p1 += gelu_f(acc1[j] + b2[j]) * w3[j];
    }
    p0 += __shfl_xor(p0, 1, 64); p0 += __shfl_xor(p0, 2, 64); p0 += __shfl_xor(p0, 4, 64);
    p1 += __shfl_xor(p1, 1, 64); p1 += __shfl_xor(p1, 2, 64); p1 += __shfl_xor(p1, 4, 64);
    if (tc == 0) {
        int e = e0 + tr * 2;
        if (e < E)     out[e]     = 1.f / (1.f + expf(-(p0 + b3)));
        if (e + 1 < E) out[e + 1] = 1.f / (1.f + expf(-(p1 + b3)));
    }
}

extern "C" void kernel_launch(void* const* d_in, const int* in_sizes, int n_in,
                              void* d_out, int out_size, void* d_ws, size_t ws_size,
                              hipStream_t stream) {
    const float* x    = (const float*)d_in[0];
    const int*   ei   = (const int*)d_in[1];
    const float* ea   = (const float*)d_in[2];
    const float* Wl1  = (const float*)d_in[3];
    const float* bl1  = (const float*)d_in[4];
    const float* Wr1  = (const float*)d_in[5];
    const float* br1  = (const float*)d_in[6];
    const float* We1  = (const float*)d_in[7];
    const float* att1 = (const float*)d_in[8];
    const float* bias1= (const float*)d_in[9];
    const float* Wl2  = (const float*)d_in[10];
    const float* bl2  = (const float*)d_in[11];
    const float* Wr2  = (const float*)d_in[12];
    const float* br2  = (const float*)d_in[13];
    const float* We2  = (const float*)d_in[14];
    const float* att2 = (const float*)d_in[15];
    const float* bias2= (const float*)d_in[16];
    const float* bn1g = (const float*)d_in[17];
    const float* bn1b = (const float*)d_in[18];
    const float* bn1m = (const float*)d_in[19];
    const float* bn1v = (const float*)d_in[20];
    const float* bn2g = (const float*)d_in[21];
    const float* bn2b = (const float*)d_in[22];
    const float* bn2m = (const float*)d_in[23];
    const float* bn2v = (const float*)d_in[24];
    const float* Wres = (const float*)d_in[25];
    const float* Wm1  = (const float*)d_in[26];
    const float* bm1  = (const float*)d_in[27];
    const float* Wm2  = (const float*)d_in[28];
    const float* bm2  = (const float*)d_in[29];
    const float* Wm3  = (const float*)d_in[30];
    const float* bm3  = (const float*)d_in[31];
    float* out = (float*)d_out;
    float* ws = (float*)d_ws;

    const int N = NN, E = EE, Etot = ETOT;

    // workspace layout (floats)
    float* ea_sum   = ws;                                     // 16
    int*   counts   = (int*)(ws + 16);                        // N
    int*   off      = (int*)(ws + 16 + (size_t)N);            // N+16
    int*   cursor   = (int*)(ws + 32 + (size_t)2 * N);        // N
    int*   csr_src  = (int*)(ws + 32 + (size_t)3 * N);        // Etot
    int*   csr_eid  = (int*)(ws + 32 + (size_t)3 * N + Etot); // Etot
    size_t base     = 32 + (size_t)3 * N + (size_t)2 * Etot;
    __half* xl1h    = (__half*)(ws + base);                   // 256N halfs = 128N floats
    __half* xl2h    = xl1h;                                   // reuses (xl1h dead after k_fagg1)
    __half* h2h     = (__half*)(ws + base + (size_t)128 * N); // 64N halfs = 32N floats
    __half* xr1h    = (__half*)(ws + base + (size_t)160 * N); // 256N halfs = 128N floats
    __half* h1h     = xr1h;                                   // in-place (own row read before write)
    __half* xr2h    = (__half*)(ws + base + (size_t)288 * N); // 64N halfs = 32N floats
    __half* uh      = xr2h;                                   // overlays xr2h (dead after k_fagg2)
    __half* vh      = uh + (size_t)64 * N;                    // next 32N floats
    __half* eah     = (__half*)(ws + base + (size_t)352 * N); // 8E halfs = 4E floats

    hipMemsetAsync(ea_sum, 0, 16 * sizeof(float), stream);
    hipMemsetAsync(counts, 0, (size_t)N * sizeof(int), stream);

    int S = (Etot + 255) / 256;
    k_init<<<256 + S, 256, 0, stream>>>(ea, ea_sum, eah, ei, counts, E, N);
    k_scan<<<1, 1024, 0, stream>>>(counts, off, cursor, N);
    k_scat_nt1<<<S + (N + 31) / 32, 256, 0, stream>>>(ei, cursor, csr_src, csr_eid,
                                                      x, Wl1, bl1, Wr1, br1, xl1h, xr1h, E, N);
    k_fagg1<<<(N + 3) / 4, 256, 0, stream>>>(xl1h, xr1h, off, csr_src, csr_eid, eah, ea_sum,
                                             We1, att1, bias1, x, Wres,
                                             bn1g, bn1b, bn1m, bn1v, h1h, E, N);
    k_xlr2<<<(N + 31) / 32, 256, 0, stream>>>(h1h, Wl2, bl2, Wr2, br2, xl2h, xr2h, N);
    k_fagg2<<<(N + 3) / 4, 256, 0, stream>>>(xl2h, xr2h, off, csr_src, csr_eid, eah, ea_sum,
                                             We2, att2, bias2,
                                             bn2g, bn2b, bn2m, bn2v, h2h, E, N);
    k_uv<<<(N + 31) / 32, 256, 0, stream>>>(h2h, Wm1, uh, vh, N);
    k_mlp2<<<(E + 63) / 64, 256, 0, stream>>>(uh, vh, eah, ei, Wm1, bm1, Wm2, bm2, Wm3, bm3, out, E);
}